// Round 1
// baseline (913.005 us; speedup 1.0000x reference)
//
#include <hip/hip_runtime.h>
#include <hip/hip_bf16.h>

typedef __attribute__((ext_vector_type(8))) short bf16x8;
typedef __attribute__((ext_vector_type(4))) float f32x4;

#define S_LEN 2048
#define NHEAD 16
#define HDIM 64
#define DMODEL 1024
#define NORM_F 0.125f

__device__ __forceinline__ short f2b(float x) {
  union { float f; unsigned u; } c; c.f = x;
  unsigned r = (c.u + 0x7FFFu + ((c.u >> 16) & 1u)) >> 16;
  return (short)r;
}

// ---------------------------------------------------------------------------
// Segment-bit extraction with dtype detection (int32 / float32 / uint8 bool).
// segbits[b*S + i] = seg_mat[b, 0, i]  (two segment classes -> row 0 suffices)
// ---------------------------------------------------------------------------
__global__ void seg_extract_kernel(const unsigned int* __restrict__ seg_raw,
                                   int* __restrict__ segbits) {
  __shared__ int bad_int, bad_flt;
  int tid = threadIdx.x;
  if (tid == 0) { bad_int = 0; bad_flt = 0; }
  __syncthreads();
  for (int i = tid; i < 2048; i += blockDim.x) {
    unsigned v = seg_raw[i];
    if (v > 1u) atomicOr(&bad_int, 1);
    if (v != 0u && v != 0x3F800000u) atomicOr(&bad_flt, 1);
  }
  __syncthreads();
  int mode = bad_int ? (bad_flt ? 2 : 1) : 0;  // 0=int32, 1=float32, 2=uint8
  const unsigned char* u8 = (const unsigned char*)seg_raw;
  for (int idx = tid; idx < 2 * S_LEN; idx += blockDim.x) {
    int b = idx / S_LEN, i = idx % S_LEN;
    size_t base = (size_t)b * S_LEN * S_LEN + i;
    int bit;
    if (mode == 0)      bit = (int)seg_raw[base];
    else if (mode == 1) bit = (seg_raw[base] != 0u) ? 1 : 0;
    else                bit = (int)u8[base];
    segbits[idx] = bit;
  }
}

// ---------------------------------------------------------------------------
// GEMM: C[4096][1024] = scale * (A[4096][1024] x W[1024][1024]) + bias[1024]
// bf16 MFMA 16x16x32, 64x64 tile, 4 waves, BK=32.
// ---------------------------------------------------------------------------
__global__ __launch_bounds__(256) void gemm_kernel(
    const float* __restrict__ A, const float* __restrict__ W,
    const float* __restrict__ bias, float* __restrict__ C, float scale) {
  __shared__ short As[64][40];   // [row][k], pad row stride 80B (16B aligned)
  __shared__ short BsT[64][40];  // [col][k]
  const int tid = threadIdx.x;
  const int wave = tid >> 6, lane = tid & 63;
  const int r16 = lane & 15, g = lane >> 4;
  const int m0 = blockIdx.x * 64;
  const int n0 = blockIdx.y * 64;
  f32x4 acc[4] = {};
  for (int k0 = 0; k0 < 1024; k0 += 32) {
    for (int idx = tid; idx < 64 * 32; idx += 256) {
      int r = idx >> 5, kk = idx & 31;
      As[r][kk] = f2b(A[(size_t)(m0 + r) * 1024 + k0 + kk]);
    }
    for (int idx = tid; idx < 64 * 32; idx += 256) {
      int kk = idx >> 6, c = idx & 63;
      BsT[c][kk] = f2b(W[(size_t)(k0 + kk) * 1024 + n0 + c]);
    }
    __syncthreads();
    bf16x8 a = *(const bf16x8*)&As[wave * 16 + r16][g * 8];
#pragma unroll
    for (int s = 0; s < 4; ++s) {
      bf16x8 bfr = *(const bf16x8*)&BsT[s * 16 + r16][g * 8];
      acc[s] = __builtin_amdgcn_mfma_f32_16x16x32_bf16(a, bfr, acc[s], 0, 0, 0);
    }
    __syncthreads();
  }
  const int lrow = wave * 16 + g * 4;
#pragma unroll
  for (int s = 0; s < 4; ++s) {
    int col = n0 + s * 16 + r16;
    float bv = bias ? bias[col] : 0.f;
#pragma unroll
    for (int r = 0; r < 4; ++r) {
      C[(size_t)(m0 + lrow + r) * 1024 + col] = acc[s][r] * scale + bv;
    }
  }
}

// ---------------------------------------------------------------------------
// Fused causal relative attention. One block = (b, n, 64 q-rows).
// ---------------------------------------------------------------------------
__global__ __launch_bounds__(256) void attn_kernel(
    const float* __restrict__ qh_g, const float* __restrict__ kh_g,
    const float* __restrict__ vh_g, const float* __restrict__ rh_g,
    const float* __restrict__ rwb, const float* __restrict__ rrb,
    const float* __restrict__ rsb, const float* __restrict__ seg_embed,
    const int* __restrict__ segbits, float* __restrict__ attn_vec) {
  __shared__ short Ks[64][72];    // [j][h]
  __shared__ short VsT[64][72];   // [h][j]
  __shared__ short Rs[128][72];   // [u][h], t = t0 + u
  __shared__ short Ps[64][72];    // [i][j] probs bf16
  __shared__ float sc[64][65];    // score tile fp32
  __shared__ float m_s[64], l_s[64], rs_s[64], sb0_s[64], sb1_s[64];
  __shared__ int ai_s[64], aj_s[64];

  const int tid = threadIdx.x;
  const int wave = tid >> 6, lane = tid & 63;
  const int r16 = lane & 15, g = lane >> 4;
  const int i0 = blockIdx.x * 64;
  const int n = blockIdx.y;
  const int b = blockIdx.z;

  // prologue: Q fragments (content/pos variants) + segment projections
  const int qrow = i0 + wave * 16 + r16;
  bf16x8 qw[2], qr[2];
  float p0 = 0.f, p1 = 0.f;
#pragma unroll
  for (int hg = 0; hg < 2; ++hg) {
    const int hb = hg * 32 + g * 8;
    const float* qp = qh_g + (size_t)(b * S_LEN + qrow) * DMODEL + n * HDIM + hb;
#pragma unroll
    for (int e = 0; e < 8; ++e) {
      float qv = qp[e];
      int hh = n * HDIM + hb + e;
      qw[hg][e] = f2b(qv + rwb[hh] * NORM_F);
      qr[hg][e] = f2b(qv + rrb[hh] * NORM_F);
      float qs = qv + rsb[hh] * NORM_F;
      p0 += qs * seg_embed[hh];
      p1 += qs * seg_embed[DMODEL + hh];
    }
  }
  p0 += __shfl_xor(p0, 16); p0 += __shfl_xor(p0, 32);
  p1 += __shfl_xor(p1, 16); p1 += __shfl_xor(p1, 32);
  sb0_s[wave * 16 + r16] = p0;
  sb1_s[wave * 16 + r16] = p1;
  ai_s[wave * 16 + r16] = segbits[b * S_LEN + qrow];
  if (tid < 64) { m_s[tid] = -1e30f; l_s[tid] = 0.f; }
  f32x4 o[4] = {};
  __syncthreads();

  for (int j0 = 0; j0 <= i0; j0 += 64) {
    // stage K, V tiles (bf16), V transposed
    for (int idx = tid; idx < 64 * 16; idx += 256) {
      int j = idx >> 4, h4 = (idx & 15) * 4;
      size_t goff = (size_t)(b * S_LEN + j0 + j) * DMODEL + n * HDIM + h4;
      float4 kv = *(const float4*)(kh_g + goff);
      Ks[j][h4 + 0] = f2b(kv.x); Ks[j][h4 + 1] = f2b(kv.y);
      Ks[j][h4 + 2] = f2b(kv.z); Ks[j][h4 + 3] = f2b(kv.w);
      float4 vv = *(const float4*)(vh_g + goff);
      VsT[h4 + 0][j] = f2b(vv.x); VsT[h4 + 1][j] = f2b(vv.y);
      VsT[h4 + 2][j] = f2b(vv.z); VsT[h4 + 3][j] = f2b(vv.w);
    }
    // stage R tile: rows t0..t0+127 (always within [1, 2112) ⊂ [0,4096))
    const int t0 = S_LEN + j0 - i0 - 63;
    for (int idx = tid; idx < 128 * 16; idx += 256) {
      int u = idx >> 4, h4 = (idx & 15) * 4;
      float4 rv = *(const float4*)(rh_g + (size_t)(t0 + u) * DMODEL + n * HDIM + h4);
      Rs[u][h4 + 0] = f2b(rv.x); Rs[u][h4 + 1] = f2b(rv.y);
      Rs[u][h4 + 2] = f2b(rv.z); Rs[u][h4 + 3] = f2b(rv.w);
    }
    if (tid < 64) aj_s[tid] = segbits[b * S_LEN + j0 + tid];
    __syncthreads();

    // content: (q + rwb*NORM) . K^T  -> sc
    f32x4 cf[4] = {};
#pragma unroll
    for (int hg = 0; hg < 2; ++hg)
#pragma unroll
      for (int s = 0; s < 4; ++s) {
        bf16x8 bk = *(const bf16x8*)&Ks[s * 16 + r16][hg * 32 + g * 8];
        cf[s] = __builtin_amdgcn_mfma_f32_16x16x32_bf16(qw[hg], bk, cf[s], 0, 0, 0);
      }
#pragma unroll
    for (int s = 0; s < 4; ++s)
#pragma unroll
      for (int r = 0; r < 4; ++r)
        sc[wave * 16 + g * 4 + r][s * 16 + r16] = cf[s][r];
    __syncthreads();

    // position: (q + rrb*NORM) . R^T, add at shifted (i, j = u - 63 + i)
    f32x4 pf[8] = {};
#pragma unroll
    for (int hg = 0; hg < 2; ++hg)
#pragma unroll
      for (int s = 0; s < 8; ++s) {
        bf16x8 br = *(const bf16x8*)&Rs[s * 16 + r16][hg * 32 + g * 8];
        pf[s] = __builtin_amdgcn_mfma_f32_16x16x32_bf16(qr[hg], br, pf[s], 0, 0, 0);
      }
#pragma unroll
    for (int s = 0; s < 8; ++s)
#pragma unroll
      for (int r = 0; r < 4; ++r) {
        int il = wave * 16 + g * 4 + r;
        int jl = s * 16 + r16 - 63 + il;
        if (jl >= 0 && jl < 64) sc[il][jl] += pf[s][r];
      }
    __syncthreads();

    // online softmax (seg bias + causal mask applied here)
    {
      int row = tid >> 2, q4 = tid & 3;
      int i_abs = i0 + row;
      float sb0v = sb0_s[row], sb1v = sb1_s[row];
      int aiv = ai_s[row];
      float vals[16];
      float tmax = -1e30f;
#pragma unroll
      for (int jj = 0; jj < 16; ++jj) {
        int jl = q4 * 16 + jj;
        float sv = sc[row][jl];
        sv += (aj_s[jl] == aiv) ? sb1v : sb0v;
        if (j0 + jl > i_abs) sv -= 1e6f;  // matches ref: score - INF*mask
        vals[jj] = sv;
        tmax = fmaxf(tmax, sv);
      }
      tmax = fmaxf(tmax, __shfl_xor(tmax, 1));
      tmax = fmaxf(tmax, __shfl_xor(tmax, 2));
      float mold = m_s[row];
      float mnew = fmaxf(mold, tmax);
      float psum = 0.f;
#pragma unroll
      for (int jj = 0; jj < 16; ++jj) {
        float p = __expf(vals[jj] - mnew);
        psum += p;
        Ps[row][q4 * 16 + jj] = f2b(p);
      }
      psum += __shfl_xor(psum, 1);
      psum += __shfl_xor(psum, 2);
      if (q4 == 0) {
        m_s[row] = mnew;
        l_s[row] = l_s[row] * __expf(mold - mnew) + psum;
        rs_s[row] = __expf(mold - mnew);
      }
    }
    __syncthreads();

    // rescale O, then O += P x V
#pragma unroll
    for (int s = 0; s < 4; ++s)
#pragma unroll
      for (int r = 0; r < 4; ++r)
        o[s][r] *= rs_s[wave * 16 + g * 4 + r];
#pragma unroll
    for (int jg = 0; jg < 2; ++jg) {
      bf16x8 pa = *(const bf16x8*)&Ps[wave * 16 + r16][jg * 32 + g * 8];
#pragma unroll
      for (int s = 0; s < 4; ++s) {
        bf16x8 bv = *(const bf16x8*)&VsT[s * 16 + r16][jg * 32 + g * 8];
        o[s] = __builtin_amdgcn_mfma_f32_16x16x32_bf16(pa, bv, o[s], 0, 0, 0);
      }
    }
    __syncthreads();
  }

  // epilogue: normalize and store attn_vec
#pragma unroll
  for (int s = 0; s < 4; ++s)
#pragma unroll
    for (int r = 0; r < 4; ++r) {
      int il = wave * 16 + g * 4 + r;
      float ov = o[s][r] / l_s[il];
      attn_vec[(size_t)(b * S_LEN + i0 + il) * DMODEL + n * HDIM + s * 16 + r16] = ov;
    }
}

// ---------------------------------------------------------------------------
// Residual + LayerNorm: out = LN(q + attn_out) * g + b
// ---------------------------------------------------------------------------
__global__ __launch_bounds__(256) void ln_kernel(
    const float* __restrict__ q, const float* __restrict__ ao,
    const float* __restrict__ ln_g, const float* __restrict__ ln_b,
    float* __restrict__ out) {
  int row = blockIdx.x;
  const float* xq = q + (size_t)row * 1024;
  const float* xa = ao + (size_t)row * 1024;
  float x[4], lsum = 0.f, lsq = 0.f;
#pragma unroll
  for (int e = 0; e < 4; ++e) {
    int d = threadIdx.x + e * 256;
    x[e] = xq[d] + xa[d];
    lsum += x[e]; lsq += x[e] * x[e];
  }
  for (int off = 1; off < 64; off <<= 1) {
    lsum += __shfl_xor(lsum, off);
    lsq += __shfl_xor(lsq, off);
  }
  __shared__ float red[8];
  int wv = threadIdx.x >> 6, ln = threadIdx.x & 63;
  if (ln == 0) { red[wv] = lsum; red[4 + wv] = lsq; }
  __syncthreads();
  lsum = red[0] + red[1] + red[2] + red[3];
  lsq = red[4] + red[5] + red[6] + red[7];
  float mu = lsum * (1.f / 1024.f);
  float var = lsq * (1.f / 1024.f) - mu * mu;
  float inv = rsqrtf(var + 1e-5f);
#pragma unroll
  for (int e = 0; e < 4; ++e) {
    int d = threadIdx.x + e * 256;
    out[(size_t)row * 1024 + d] = (x[e] - mu) * inv * ln_g[d] + ln_b[d];
  }
}

// ---------------------------------------------------------------------------
extern "C" void kernel_launch(void* const* d_in, const int* in_sizes, int n_in,
                              void* d_out, int out_size, void* d_ws, size_t ws_size,
                              hipStream_t stream) {
  const float* q   = (const float*)d_in[0];
  const float* k   = (const float*)d_in[1];
  const float* v   = (const float*)d_in[2];
  const float* pe  = (const float*)d_in[3];
  const void*  seg = d_in[4];
  const float* qW  = (const float*)d_in[6];
  const float* kW  = (const float*)d_in[7];
  const float* kb  = (const float*)d_in[8];
  const float* vW  = (const float*)d_in[9];
  const float* vb  = (const float*)d_in[10];
  const float* rwb = (const float*)d_in[11];
  const float* rrb = (const float*)d_in[12];
  const float* rK  = (const float*)d_in[13];
  const float* rsb = (const float*)d_in[14];
  const float* sem = (const float*)d_in[15];
  const float* pW  = (const float*)d_in[16];
  const float* pb  = (const float*)d_in[17];
  const float* lng = (const float*)d_in[18];
  const float* lnb = (const float*)d_in[19];
  float* out = (float*)d_out;

  const size_t PLANE = (size_t)4096 * 1024;
  float* ws = (float*)d_ws;
  float* qh = ws;
  float* kh = qh + PLANE;
  float* vh = kh + PLANE;
  float* rh = vh + PLANE;
  float* av = rh + PLANE;
  int* segbits = (int*)(av + PLANE);
  float* ao = qh;  // qh no longer needed after attention -> reuse

  seg_extract_kernel<<<dim3(1), dim3(256), 0, stream>>>((const unsigned int*)seg, segbits);

  dim3 gg(64, 16), bb(256);
  gemm_kernel<<<gg, bb, 0, stream>>>(q,  qW, (const float*)nullptr, qh, NORM_F);
  gemm_kernel<<<gg, bb, 0, stream>>>(k,  kW, kb, kh, 1.0f);
  gemm_kernel<<<gg, bb, 0, stream>>>(v,  vW, vb, vh, 1.0f);
  gemm_kernel<<<gg, bb, 0, stream>>>(pe, rK, (const float*)nullptr, rh, 1.0f);

  attn_kernel<<<dim3(32, 16, 2), dim3(256), 0, stream>>>(qh, kh, vh, rh, rwb, rrb,
                                                         rsb, sem, segbits, av);

  gemm_kernel<<<gg, bb, 0, stream>>>(av, pW, pb, ao, 1.0f);
  ln_kernel<<<dim3(4096), dim3(256), 0, stream>>>(q, ao, lng, lnb, out);
}

// Round 2
// 448.938 us; speedup vs baseline: 2.0337x; 2.0337x over previous
//
#include <hip/hip_runtime.h>
#include <hip/hip_bf16.h>

typedef __attribute__((ext_vector_type(8))) short bf16x8;
typedef __attribute__((ext_vector_type(4))) float f32x4;
typedef unsigned short ushort_t;

#define S_LEN 2048
#define DMODEL 1024
#define NORM_F 0.125f

__device__ __forceinline__ short f2b(float x) {
  union { float f; unsigned u; } c; c.f = x;
  unsigned r = (c.u + 0x7FFFu + ((c.u >> 16) & 1u)) >> 16;
  return (short)r;
}
__device__ __forceinline__ float b2f(ushort_t u) {
  union { unsigned u; float f; } c; c.u = ((unsigned)u) << 16; return c.f;
}

// ---------------------------------------------------------------------------
// Segment-bit extraction with dtype detection (int32 / float32 / uint8 bool).
// ---------------------------------------------------------------------------
__global__ void seg_extract_kernel(const unsigned int* __restrict__ seg_raw,
                                   int* __restrict__ segbits) {
  __shared__ int bad_int, bad_flt;
  int tid = threadIdx.x;
  if (tid == 0) { bad_int = 0; bad_flt = 0; }
  __syncthreads();
  for (int i = tid; i < 2048; i += blockDim.x) {
    unsigned v = seg_raw[i];
    if (v > 1u) atomicOr(&bad_int, 1);
    if (v != 0u && v != 0x3F800000u) atomicOr(&bad_flt, 1);
  }
  __syncthreads();
  int mode = bad_int ? (bad_flt ? 2 : 1) : 0;
  const unsigned char* u8 = (const unsigned char*)seg_raw;
  for (int idx = tid; idx < 2 * S_LEN; idx += blockDim.x) {
    int b = idx / S_LEN, i = idx % S_LEN;
    size_t base = (size_t)b * S_LEN * S_LEN + i;
    int bit;
    if (mode == 0)      bit = (int)seg_raw[base];
    else if (mode == 1) bit = (seg_raw[base] != 0u) ? 1 : 0;
    else                bit = (int)u8[base];
    segbits[idx] = bit;
  }
}

// ---------------------------------------------------------------------------
// fp32 -> bf16 plane conversion (4 planes of 4096x1024, z picks plane)
// ---------------------------------------------------------------------------
__global__ __launch_bounds__(256) void conv4_kernel(
    const float* __restrict__ s0, const float* __restrict__ s1,
    const float* __restrict__ s2, const float* __restrict__ s3,
    ushort_t* __restrict__ d0, ushort_t* __restrict__ d1,
    ushort_t* __restrict__ d2, ushort_t* __restrict__ d3) {
  int z = blockIdx.y;
  const float* src = z == 0 ? s0 : z == 1 ? s1 : z == 2 ? s2 : s3;
  ushort_t* dst = z == 0 ? d0 : z == 1 ? d1 : z == 2 ? d2 : d3;
  size_t base = ((size_t)blockIdx.x * 256 + threadIdx.x) * 8;
  float4 a = *(const float4*)(src + base);
  float4 b = *(const float4*)(src + base + 4);
  union { ushort_t us[8]; uint4 v; } o;
  o.us[0] = (ushort_t)f2b(a.x); o.us[1] = (ushort_t)f2b(a.y);
  o.us[2] = (ushort_t)f2b(a.z); o.us[3] = (ushort_t)f2b(a.w);
  o.us[4] = (ushort_t)f2b(b.x); o.us[5] = (ushort_t)f2b(b.y);
  o.us[6] = (ushort_t)f2b(b.z); o.us[7] = (ushort_t)f2b(b.w);
  *(uint4*)(dst + base) = o.v;
}

// ---------------------------------------------------------------------------
// Weight transpose+convert: W fp32 [1024 k][1024 n] -> Wt bf16 [n][k]
// ---------------------------------------------------------------------------
__global__ __launch_bounds__(256) void convT_kernel(
    const float* __restrict__ s0, const float* __restrict__ s1,
    const float* __restrict__ s2, const float* __restrict__ s3,
    const float* __restrict__ s4,
    ushort_t* __restrict__ d0, ushort_t* __restrict__ d1,
    ushort_t* __restrict__ d2, ushort_t* __restrict__ d3,
    ushort_t* __restrict__ d4) {
  int z = blockIdx.z;
  const float* src = z == 0 ? s0 : z == 1 ? s1 : z == 2 ? s2 : z == 3 ? s3 : s4;
  ushort_t* dst = z == 0 ? d0 : z == 1 ? d1 : z == 2 ? d2 : z == 3 ? d3 : d4;
  __shared__ float Tl[64][68];
  int tid = threadIdx.x;
  int k0 = blockIdx.x * 64, n0 = blockIdx.y * 64;
#pragma unroll
  for (int it = 0; it < 4; ++it) {
    int idx = tid + it * 256;
    int r = idx >> 4, c4 = (idx & 15) * 4;
    *(float4*)&Tl[r][c4] = *(const float4*)(src + (size_t)(k0 + r) * 1024 + n0 + c4);
  }
  __syncthreads();
#pragma unroll
  for (int it = 0; it < 2; ++it) {
    int idx = tid + it * 256;
    int nn = idx >> 3, kc = idx & 7;
    union { ushort_t us[8]; uint4 v; } o;
#pragma unroll
    for (int e = 0; e < 8; ++e) o.us[e] = (ushort_t)f2b(Tl[kc * 8 + e][nn]);
    *(uint4*)(dst + (size_t)(n0 + nn) * 1024 + k0 + kc * 8) = o.v;
  }
}

// ---------------------------------------------------------------------------
// bf16 GEMM: C[4096][1024] = scale*(A[4096][1024] x Wt[n][k]^T) + bias
// 128x64 tile, 4 waves (each 64x32), BK=32, reg-prefetched staging.
// ---------------------------------------------------------------------------
template <bool OUTBF>
__global__ __launch_bounds__(256) void gemm_bf_kernel(
    const ushort_t* __restrict__ A, const ushort_t* __restrict__ Wt,
    const float* __restrict__ bias, void* __restrict__ Cv, float scale) {
  __shared__ short A_lds[128][40];
  __shared__ short B_lds[64][40];
  const int tid = threadIdx.x;
  const int wave = tid >> 6, lane = tid & 63;
  const int r16 = lane & 15, g = lane >> 4;
  const int wm = wave >> 1, wn = wave & 1;
  const int m0 = blockIdx.x * 128, n0 = blockIdx.y * 64;
  const int sr = tid >> 2, sseg = (tid & 3) * 8;
  f32x4 acc[4][2] = {};
  uint4 ra0 = *(const uint4*)(A + (size_t)(m0 + sr) * 1024 + sseg);
  uint4 ra1 = *(const uint4*)(A + (size_t)(m0 + 64 + sr) * 1024 + sseg);
  uint4 rb  = *(const uint4*)(Wt + (size_t)(n0 + sr) * 1024 + sseg);
  for (int k0 = 0; k0 < 1024; k0 += 32) {
    *(uint4*)&A_lds[sr][sseg] = ra0;
    *(uint4*)&A_lds[64 + sr][sseg] = ra1;
    *(uint4*)&B_lds[sr][sseg] = rb;
    __syncthreads();
    if (k0 + 32 < 1024) {
      ra0 = *(const uint4*)(A + (size_t)(m0 + sr) * 1024 + k0 + 32 + sseg);
      ra1 = *(const uint4*)(A + (size_t)(m0 + 64 + sr) * 1024 + k0 + 32 + sseg);
      rb  = *(const uint4*)(Wt + (size_t)(n0 + sr) * 1024 + k0 + 32 + sseg);
    }
    bf16x8 af[4], bfr[2];
#pragma unroll
    for (int fm = 0; fm < 4; ++fm)
      af[fm] = *(const bf16x8*)&A_lds[wm * 64 + fm * 16 + r16][g * 8];
#pragma unroll
    for (int fn = 0; fn < 2; ++fn)
      bfr[fn] = *(const bf16x8*)&B_lds[wn * 32 + fn * 16 + r16][g * 8];
#pragma unroll
    for (int fm = 0; fm < 4; ++fm)
#pragma unroll
      for (int fn = 0; fn < 2; ++fn)
        acc[fm][fn] = __builtin_amdgcn_mfma_f32_16x16x32_bf16(af[fm], bfr[fn], acc[fm][fn], 0, 0, 0);
    __syncthreads();
  }
  float bv[2];
#pragma unroll
  for (int fn = 0; fn < 2; ++fn)
    bv[fn] = bias ? bias[n0 + wn * 32 + fn * 16 + r16] : 0.f;
#pragma unroll
  for (int fm = 0; fm < 4; ++fm)
#pragma unroll
    for (int fn = 0; fn < 2; ++fn)
#pragma unroll
      for (int rr = 0; rr < 4; ++rr) {
        float vv = acc[fm][fn][rr] * scale + bv[fn];
        size_t off = (size_t)(m0 + wm * 64 + fm * 16 + g * 4 + rr) * 1024 +
                     n0 + wn * 32 + fn * 16 + r16;
        if (OUTBF) ((ushort_t*)Cv)[off] = (ushort_t)f2b(vv);
        else       ((float*)Cv)[off] = vv;
      }
}

// ---------------------------------------------------------------------------
// Fused causal relative attention v2: in-register online softmax,
// circular R buffer, reg-prefetched staging, 3 barriers/tile.
// ---------------------------------------------------------------------------
__global__ __launch_bounds__(256) void attn_kernel(
    const ushort_t* __restrict__ qhb, const ushort_t* __restrict__ khb,
    const ushort_t* __restrict__ vhb, const ushort_t* __restrict__ rhb,
    const float* __restrict__ rwb, const float* __restrict__ rrb,
    const float* __restrict__ rsb, const float* __restrict__ sem,
    const int* __restrict__ segbits, ushort_t* __restrict__ av) {
  __shared__ short Ks[64][72];
  __shared__ short VsT[64][72];
  __shared__ short Rs[128][72];
  __shared__ short Ps[64][72];
  __shared__ short PosL[64][132];
  __shared__ float sb0_s[64], sb1_s[64];
  __shared__ int aj_s[2][64];

  const int tid = threadIdx.x;
  const int w = tid >> 6, lane = tid & 63;
  const int r16 = lane & 15, g = lane >> 4;
  const int i0 = ((int)gridDim.x - 1 - (int)blockIdx.x) * 64;  // big blocks first
  const int n = blockIdx.y, b = blockIdx.z;
  const int t0 = S_LEN - i0 - 63;  // tile-0 R base; tile t base = t0 + 64*t

  // prologue: Q fragments + segment projections
  const int qrow = i0 + w * 16 + r16;
  bf16x8 qw[2], qr[2];
  float p0 = 0.f, p1 = 0.f;
#pragma unroll
  for (int hg = 0; hg < 2; ++hg) {
    const ushort_t* qp = qhb + (size_t)(b * S_LEN + qrow) * DMODEL + n * 64 + hg * 32 + g * 8;
    union { uint4 v; ushort_t us[8]; } qv; qv.v = *(const uint4*)qp;
#pragma unroll
    for (int e = 0; e < 8; ++e) {
      float q = b2f(qv.us[e]);
      int hh = n * 64 + hg * 32 + g * 8 + e;
      qw[hg][e] = f2b(q + rwb[hh] * NORM_F);
      qr[hg][e] = f2b(q + rrb[hh] * NORM_F);
      float qs = q + rsb[hh] * NORM_F;
      p0 += qs * sem[hh];
      p1 += qs * sem[DMODEL + hh];
    }
  }
  p0 += __shfl_xor(p0, 16); p0 += __shfl_xor(p0, 32);
  p1 += __shfl_xor(p1, 16); p1 += __shfl_xor(p1, 32);
  sb0_s[w * 16 + r16] = p0;
  sb1_s[w * 16 + r16] = p1;
  int ai_r[4];
#pragma unroll
  for (int rr = 0; rr < 4; ++rr)
    ai_r[rr] = segbits[b * S_LEN + i0 + w * 16 + g * 4 + rr];

  // stage tile 0: K, V (transposed), R rows 0..127
  const int srow = tid >> 3, sseg = (tid & 7) * 8;
#pragma unroll
  for (int it = 0; it < 2; ++it) {
    int j = srow + it * 32;
    size_t go = (size_t)(b * S_LEN + j) * DMODEL + n * 64 + sseg;
    *(uint4*)&Ks[j][sseg] = *(const uint4*)(khb + go);
    union { uint4 v; ushort_t us[8]; } vv; vv.v = *(const uint4*)(vhb + go);
#pragma unroll
    for (int e = 0; e < 8; ++e) VsT[sseg + e][j] = (short)vv.us[e];
  }
#pragma unroll
  for (int it = 0; it < 4; ++it) {
    int u = srow + it * 32;
    *(uint4*)&Rs[u][sseg] = *(const uint4*)(rhb + (size_t)(t0 + u) * DMODEL + n * 64 + sseg);
  }
  if (tid < 64) aj_s[0][tid] = segbits[b * S_LEN + tid];
  __syncthreads();

  float sb0[4], sb1[4];
#pragma unroll
  for (int rr = 0; rr < 4; ++rr) {
    sb0[rr] = sb0_s[w * 16 + g * 4 + rr];
    sb1[rr] = sb1_s[w * 16 + g * 4 + rr];
  }
  float m_r[4], l_r[4];
#pragma unroll
  for (int rr = 0; rr < 4; ++rr) { m_r[rr] = -1e30f; l_r[rr] = 0.f; }
  f32x4 o[4] = {};

  const int ntiles = i0 / 64 + 1;
  for (int t = 0; t < ntiles; ++t) {
    const int j0 = t * 64;
    const bool hasn = (t + 1 < ntiles);
    const int xm = (t & 1) ? 64 : 0;
    // phase 0: issue next-tile global loads (latency hidden under MFMAs)
    uint4 kpf[2], vpf[2], rpf[2]; int ajpf = 0;
    if (hasn) {
#pragma unroll
      for (int it = 0; it < 2; ++it) {
        int j = srow + it * 32;
        size_t go = (size_t)(b * S_LEN + j0 + 64 + j) * DMODEL + n * 64 + sseg;
        kpf[it] = *(const uint4*)(khb + go);
        vpf[it] = *(const uint4*)(vhb + go);
        rpf[it] = *(const uint4*)(rhb + (size_t)(t0 + j0 + 128 + j) * DMODEL + n * 64 + sseg);
      }
      if (tid < 64) ajpf = segbits[b * S_LEN + j0 + 64 + tid];
    }
    // phase 1: content MFMAs
    f32x4 cf[4] = {};
#pragma unroll
    for (int hg = 0; hg < 2; ++hg)
#pragma unroll
      for (int s = 0; s < 4; ++s) {
        bf16x8 bk = *(const bf16x8*)&Ks[s * 16 + r16][hg * 32 + g * 8];
        cf[s] = __builtin_amdgcn_mfma_f32_16x16x32_bf16(qw[hg], bk, cf[s], 0, 0, 0);
      }
    // phase 2: pos MFMAs (circular R rows)
    f32x4 pf[8] = {};
#pragma unroll
    for (int hg = 0; hg < 2; ++hg)
#pragma unroll
      for (int s = 0; s < 8; ++s) {
        int rrow = (s * 16 + r16) ^ xm;
        bf16x8 br = *(const bf16x8*)&Rs[rrow][hg * 32 + g * 8];
        pf[s] = __builtin_amdgcn_mfma_f32_16x16x32_bf16(qr[hg], br, pf[s], 0, 0, 0);
      }
    // phase 3: pos -> PosL (bf16)
#pragma unroll
    for (int s = 0; s < 8; ++s)
#pragma unroll
      for (int rr = 0; rr < 4; ++rr)
        PosL[w * 16 + g * 4 + rr][s * 16 + r16] = f2b(pf[s][rr]);
    __syncthreads();  // B: PosL readable; Ks/Rs free
    // phase 6: commit next K, R, aj
    if (hasn) {
#pragma unroll
      for (int it = 0; it < 2; ++it) {
        *(uint4*)&Ks[srow + it * 32][sseg] = kpf[it];
        *(uint4*)&Rs[srow + it * 32 + xm][sseg] = rpf[it];
      }
      if (tid < 64) aj_s[(t + 1) & 1][tid] = ajpf;
    }
    // phase 7: in-register online softmax
    int ajv[4];
#pragma unroll
    for (int s = 0; s < 4; ++s) ajv[s] = aj_s[t & 1][s * 16 + r16];
    float scl[4];
#pragma unroll
    for (int rr = 0; rr < 4; ++rr) {
      const int il = w * 16 + g * 4 + rr;
      float vals[4];
      float vmax = -1e30f;
#pragma unroll
      for (int s = 0; s < 4; ++s) {
        float pos = b2f((ushort_t)PosL[il][s * 16 + r16 + 63 - il]);
        float sv = cf[s][rr] + pos + ((ajv[s] == ai_r[rr]) ? sb1[rr] : sb0[rr]);
        if (j0 + s * 16 + r16 > i0 + il) sv -= 1e6f;
        vals[s] = sv;
        vmax = fmaxf(vmax, sv);
      }
      vmax = fmaxf(vmax, __shfl_xor(vmax, 1));
      vmax = fmaxf(vmax, __shfl_xor(vmax, 2));
      vmax = fmaxf(vmax, __shfl_xor(vmax, 4));
      vmax = fmaxf(vmax, __shfl_xor(vmax, 8));
      float mnew = fmaxf(m_r[rr], vmax);
      float sc_ = __expf(m_r[rr] - mnew);
      float psum = 0.f;
      float pex[4];
#pragma unroll
      for (int s = 0; s < 4; ++s) {
        pex[s] = __expf(vals[s] - mnew);
        psum += pex[s];
      }
      psum += __shfl_xor(psum, 1);
      psum += __shfl_xor(psum, 2);
      psum += __shfl_xor(psum, 4);
      psum += __shfl_xor(psum, 8);
      l_r[rr] = l_r[rr] * sc_ + psum;
      m_r[rr] = mnew;
      scl[rr] = sc_;
#pragma unroll
      for (int s = 0; s < 4; ++s)
        Ps[il][s * 16 + r16] = f2b(pex[s]);
    }
    __syncthreads();  // C: Ps ready
    // phase 9: rescale + PV
#pragma unroll
    for (int s = 0; s < 4; ++s)
#pragma unroll
      for (int rr = 0; rr < 4; ++rr) o[s][rr] *= scl[rr];
#pragma unroll
    for (int jg = 0; jg < 2; ++jg) {
      bf16x8 pa = *(const bf16x8*)&Ps[w * 16 + r16][jg * 32 + g * 8];
#pragma unroll
      for (int s = 0; s < 4; ++s) {
        bf16x8 bv2 = *(const bf16x8*)&VsT[s * 16 + r16][jg * 32 + g * 8];
        o[s] = __builtin_amdgcn_mfma_f32_16x16x32_bf16(pa, bv2, o[s], 0, 0, 0);
      }
    }
    __syncthreads();  // D: VsT free
    // phase 11: commit next V (transposed scatter)
    if (hasn) {
#pragma unroll
      for (int it = 0; it < 2; ++it) {
        union { uint4 v; ushort_t us[8]; } vv; vv.v = vpf[it];
#pragma unroll
        for (int e = 0; e < 8; ++e) VsT[sseg + e][srow + it * 32] = (short)vv.us[e];
      }
    }
  }

  // epilogue
#pragma unroll
  for (int s = 0; s < 4; ++s)
#pragma unroll
    for (int rr = 0; rr < 4; ++rr) {
      const int il = w * 16 + g * 4 + rr;
      av[(size_t)(b * S_LEN + i0 + il) * DMODEL + n * 64 + s * 16 + r16] =
          (ushort_t)f2b(o[s][rr] / l_r[rr]);
    }
}

// ---------------------------------------------------------------------------
// Residual + LayerNorm
// ---------------------------------------------------------------------------
__global__ __launch_bounds__(256) void ln_kernel(
    const float* __restrict__ q, const float* __restrict__ ao,
    const float* __restrict__ ln_g, const float* __restrict__ ln_b,
    float* __restrict__ out) {
  int row = blockIdx.x;
  const float* xq = q + (size_t)row * 1024;
  const float* xa = ao + (size_t)row * 1024;
  float x[4], lsum = 0.f, lsq = 0.f;
#pragma unroll
  for (int e = 0; e < 4; ++e) {
    int d = threadIdx.x + e * 256;
    x[e] = xq[d] + xa[d];
    lsum += x[e]; lsq += x[e] * x[e];
  }
  for (int off = 1; off < 64; off <<= 1) {
    lsum += __shfl_xor(lsum, off);
    lsq += __shfl_xor(lsq, off);
  }
  __shared__ float red[8];
  int wv = threadIdx.x >> 6, ln = threadIdx.x & 63;
  if (ln == 0) { red[wv] = lsum; red[4 + wv] = lsq; }
  __syncthreads();
  lsum = red[0] + red[1] + red[2] + red[3];
  lsq = red[4] + red[5] + red[6] + red[7];
  float mu = lsum * (1.f / 1024.f);
  float var = lsq * (1.f / 1024.f) - mu * mu;
  float inv = rsqrtf(var + 1e-5f);
#pragma unroll
  for (int e = 0; e < 4; ++e) {
    int d = threadIdx.x + e * 256;
    out[(size_t)row * 1024 + d] = (x[e] - mu) * inv * ln_g[d] + ln_b[d];
  }
}

// ---------------------------------------------------------------------------
extern "C" void kernel_launch(void* const* d_in, const int* in_sizes, int n_in,
                              void* d_out, int out_size, void* d_ws, size_t ws_size,
                              hipStream_t stream) {
  const float* q   = (const float*)d_in[0];
  const float* k   = (const float*)d_in[1];
  const float* v   = (const float*)d_in[2];
  const float* pe  = (const float*)d_in[3];
  const void*  seg = d_in[4];
  const float* qW  = (const float*)d_in[6];
  const float* kW  = (const float*)d_in[7];
  const float* kb  = (const float*)d_in[8];
  const float* vW  = (const float*)d_in[9];
  const float* vb  = (const float*)d_in[10];
  const float* rwb = (const float*)d_in[11];
  const float* rrb = (const float*)d_in[12];
  const float* rK  = (const float*)d_in[13];
  const float* rsb = (const float*)d_in[14];
  const float* sem = (const float*)d_in[15];
  const float* pW  = (const float*)d_in[16];
  const float* pb  = (const float*)d_in[17];
  const float* lng = (const float*)d_in[18];
  const float* lnb = (const float*)d_in[19];
  float* out = (float*)d_out;

  const size_t MB = 1u << 20;
  char* W = (char*)d_ws;
  ushort_t* abq  = (ushort_t*)(W + 0 * MB);
  ushort_t* abk  = (ushort_t*)(W + 8 * MB);
  ushort_t* abv  = (ushort_t*)(W + 16 * MB);
  ushort_t* abpe = (ushort_t*)(W + 24 * MB);
  ushort_t* wtq  = (ushort_t*)(W + 32 * MB);
  ushort_t* wtk  = (ushort_t*)(W + 34 * MB);
  ushort_t* wtv  = (ushort_t*)(W + 36 * MB);
  ushort_t* wtr  = (ushort_t*)(W + 38 * MB);
  ushort_t* wtp  = (ushort_t*)(W + 40 * MB);
  ushort_t* qh   = (ushort_t*)(W + 42 * MB);
  ushort_t* kh   = (ushort_t*)(W + 50 * MB);
  ushort_t* vh   = (ushort_t*)(W + 58 * MB);
  ushort_t* rh   = (ushort_t*)(W + 66 * MB);
  ushort_t* av   = (ushort_t*)(W + 0 * MB);    // overlays abq (dead by then)
  float*    ao   = (float*)(W + 8 * MB);       // overlays abk/abv (dead by then)
  int* segbits   = (int*)(W + 74 * MB);

  seg_extract_kernel<<<dim3(1), dim3(256), 0, stream>>>((const unsigned int*)seg, segbits);
  conv4_kernel<<<dim3(2048, 4), dim3(256), 0, stream>>>(q, k, v, pe, abq, abk, abv, abpe);
  convT_kernel<<<dim3(16, 16, 5), dim3(256), 0, stream>>>(qW, kW, vW, rK, pW,
                                                          wtq, wtk, wtv, wtr, wtp);
  dim3 gg(32, 16), bb(256);
  gemm_bf_kernel<true><<<gg, bb, 0, stream>>>(abq,  wtq, (const float*)nullptr, qh, NORM_F);
  gemm_bf_kernel<true><<<gg, bb, 0, stream>>>(abk,  wtk, kb, kh, 1.0f);
  gemm_bf_kernel<true><<<gg, bb, 0, stream>>>(abv,  wtv, vb, vh, 1.0f);
  gemm_bf_kernel<true><<<gg, bb, 0, stream>>>(abpe, wtr, (const float*)nullptr, rh, 1.0f);

  attn_kernel<<<dim3(32, 16, 2), dim3(256), 0, stream>>>(qh, kh, vh, rh, rwb, rrb,
                                                         rsb, sem, segbits, av);

  gemm_bf_kernel<false><<<gg, bb, 0, stream>>>(av, wtp, pb, ao, 1.0f);
  ln_kernel<<<dim3(4096), dim3(256), 0, stream>>>(q, ao, lng, lnb, out);
}

// Round 3
// 414.887 us; speedup vs baseline: 2.2006x; 1.0821x over previous
//
#include <hip/hip_runtime.h>
#include <hip/hip_bf16.h>

typedef __attribute__((ext_vector_type(8))) short bf16x8;
typedef __attribute__((ext_vector_type(4))) float f32x4;
typedef unsigned short ushort_t;

#define S_LEN 2048
#define DMODEL 1024
#define NORM_F 0.125f

__device__ __forceinline__ short f2b(float x) {
  union { float f; unsigned u; } c; c.f = x;
  unsigned r = (c.u + 0x7FFFu + ((c.u >> 16) & 1u)) >> 16;
  return (short)r;
}
__device__ __forceinline__ float b2f(ushort_t u) {
  union { unsigned u; float f; } c; c.u = ((unsigned)u) << 16; return c.f;
}

// ---------------------------------------------------------------------------
// Segment-bit extraction with dtype detection (int32 / float32 / uint8 bool).
// ---------------------------------------------------------------------------
__global__ void seg_extract_kernel(const unsigned int* __restrict__ seg_raw,
                                   int* __restrict__ segbits) {
  __shared__ int bad_int, bad_flt;
  int tid = threadIdx.x;
  if (tid == 0) { bad_int = 0; bad_flt = 0; }
  __syncthreads();
  for (int i = tid; i < 2048; i += blockDim.x) {
    unsigned v = seg_raw[i];
    if (v > 1u) atomicOr(&bad_int, 1);
    if (v != 0u && v != 0x3F800000u) atomicOr(&bad_flt, 1);
  }
  __syncthreads();
  int mode = bad_int ? (bad_flt ? 2 : 1) : 0;
  const unsigned char* u8 = (const unsigned char*)seg_raw;
  for (int idx = tid; idx < 2 * S_LEN; idx += blockDim.x) {
    int b = idx / S_LEN, i = idx % S_LEN;
    size_t base = (size_t)b * S_LEN * S_LEN + i;
    int bit;
    if (mode == 0)      bit = (int)seg_raw[base];
    else if (mode == 1) bit = (seg_raw[base] != 0u) ? 1 : 0;
    else                bit = (int)u8[base];
    segbits[idx] = bit;
  }
}

// ---------------------------------------------------------------------------
// fp32 -> bf16 plane conversion (4 planes of 4096x1024)
// ---------------------------------------------------------------------------
__global__ __launch_bounds__(256) void conv4_kernel(
    const float* __restrict__ s0, const float* __restrict__ s1,
    const float* __restrict__ s2, const float* __restrict__ s3,
    ushort_t* __restrict__ d0, ushort_t* __restrict__ d1,
    ushort_t* __restrict__ d2, ushort_t* __restrict__ d3) {
  int z = blockIdx.y;
  const float* src = z == 0 ? s0 : z == 1 ? s1 : z == 2 ? s2 : s3;
  ushort_t* dst = z == 0 ? d0 : z == 1 ? d1 : z == 2 ? d2 : d3;
  size_t base = ((size_t)blockIdx.x * 256 + threadIdx.x) * 8;
  float4 a = *(const float4*)(src + base);
  float4 b = *(const float4*)(src + base + 4);
  union { ushort_t us[8]; uint4 v; } o;
  o.us[0] = (ushort_t)f2b(a.x); o.us[1] = (ushort_t)f2b(a.y);
  o.us[2] = (ushort_t)f2b(a.z); o.us[3] = (ushort_t)f2b(a.w);
  o.us[4] = (ushort_t)f2b(b.x); o.us[5] = (ushort_t)f2b(b.y);
  o.us[6] = (ushort_t)f2b(b.z); o.us[7] = (ushort_t)f2b(b.w);
  *(uint4*)(dst + base) = o.v;
}

// ---------------------------------------------------------------------------
// Weight transpose+convert: W fp32 [1024 k][1024 n] -> Wt bf16 [n][k]
// ---------------------------------------------------------------------------
__global__ __launch_bounds__(256) void convT_kernel(
    const float* __restrict__ s0, const float* __restrict__ s1,
    const float* __restrict__ s2, const float* __restrict__ s3,
    const float* __restrict__ s4,
    ushort_t* __restrict__ d0, ushort_t* __restrict__ d1,
    ushort_t* __restrict__ d2, ushort_t* __restrict__ d3,
    ushort_t* __restrict__ d4) {
  int z = blockIdx.z;
  const float* src = z == 0 ? s0 : z == 1 ? s1 : z == 2 ? s2 : z == 3 ? s3 : s4;
  ushort_t* dst = z == 0 ? d0 : z == 1 ? d1 : z == 2 ? d2 : z == 3 ? d3 : d4;
  __shared__ float Tl[64][68];
  int tid = threadIdx.x;
  int k0 = blockIdx.x * 64, n0 = blockIdx.y * 64;
#pragma unroll
  for (int it = 0; it < 4; ++it) {
    int idx = tid + it * 256;
    int r = idx >> 4, c4 = (idx & 15) * 4;
    *(float4*)&Tl[r][c4] = *(const float4*)(src + (size_t)(k0 + r) * 1024 + n0 + c4);
  }
  __syncthreads();
#pragma unroll
  for (int it = 0; it < 2; ++it) {
    int idx = tid + it * 256;
    int nn = idx >> 3, kc = idx & 7;
    union { ushort_t us[8]; uint4 v; } o;
#pragma unroll
    for (int e = 0; e < 8; ++e) o.us[e] = (ushort_t)f2b(Tl[kc * 8 + e][nn]);
    *(uint4*)(dst + (size_t)(n0 + nn) * 1024 + k0 + kc * 8) = o.v;
  }
}

// ---------------------------------------------------------------------------
// bf16 GEMM: C[4096][1024] = scale*(A x Wt^T) + bias. 128x128 tile, 4 waves.
// ---------------------------------------------------------------------------
template <bool OUTBF>
__global__ __launch_bounds__(256) void gemm_bf_kernel(
    const ushort_t* __restrict__ A, const ushort_t* __restrict__ Wt,
    const float* __restrict__ bias, void* __restrict__ Cv, float scale) {
  __shared__ short A_lds[128][40];
  __shared__ short B_lds[128][40];
  const int tid = threadIdx.x;
  const int wave = tid >> 6, lane = tid & 63;
  const int r16 = lane & 15, g = lane >> 4;
  const int wm = wave >> 1, wn = wave & 1;
  const int m0 = blockIdx.x * 128, n0 = blockIdx.y * 128;
  const int sr = tid >> 2, sseg = (tid & 3) * 8;
  f32x4 acc[4][4] = {};
  uint4 ra0 = *(const uint4*)(A + (size_t)(m0 + sr) * 1024 + sseg);
  uint4 ra1 = *(const uint4*)(A + (size_t)(m0 + 64 + sr) * 1024 + sseg);
  uint4 rb0 = *(const uint4*)(Wt + (size_t)(n0 + sr) * 1024 + sseg);
  uint4 rb1 = *(const uint4*)(Wt + (size_t)(n0 + 64 + sr) * 1024 + sseg);
  for (int k0 = 0; k0 < 1024; k0 += 32) {
    *(uint4*)&A_lds[sr][sseg] = ra0;
    *(uint4*)&A_lds[64 + sr][sseg] = ra1;
    *(uint4*)&B_lds[sr][sseg] = rb0;
    *(uint4*)&B_lds[64 + sr][sseg] = rb1;
    __syncthreads();
    if (k0 + 32 < 1024) {
      ra0 = *(const uint4*)(A + (size_t)(m0 + sr) * 1024 + k0 + 32 + sseg);
      ra1 = *(const uint4*)(A + (size_t)(m0 + 64 + sr) * 1024 + k0 + 32 + sseg);
      rb0 = *(const uint4*)(Wt + (size_t)(n0 + sr) * 1024 + k0 + 32 + sseg);
      rb1 = *(const uint4*)(Wt + (size_t)(n0 + 64 + sr) * 1024 + k0 + 32 + sseg);
    }
    bf16x8 af[4], bfr[4];
#pragma unroll
    for (int fm = 0; fm < 4; ++fm)
      af[fm] = *(const bf16x8*)&A_lds[wm * 64 + fm * 16 + r16][g * 8];
#pragma unroll
    for (int fn = 0; fn < 4; ++fn)
      bfr[fn] = *(const bf16x8*)&B_lds[wn * 64 + fn * 16 + r16][g * 8];
#pragma unroll
    for (int fm = 0; fm < 4; ++fm)
#pragma unroll
      for (int fn = 0; fn < 4; ++fn)
        acc[fm][fn] = __builtin_amdgcn_mfma_f32_16x16x32_bf16(af[fm], bfr[fn], acc[fm][fn], 0, 0, 0);
    __syncthreads();
  }
  float bv[4];
#pragma unroll
  for (int fn = 0; fn < 4; ++fn)
    bv[fn] = bias ? bias[n0 + wn * 64 + fn * 16 + r16] : 0.f;
#pragma unroll
  for (int fm = 0; fm < 4; ++fm)
#pragma unroll
    for (int fn = 0; fn < 4; ++fn)
#pragma unroll
      for (int rr = 0; rr < 4; ++rr) {
        float vv = acc[fm][fn][rr] * scale + bv[fn];
        size_t off = (size_t)(m0 + wm * 64 + fm * 16 + g * 4 + rr) * 1024 +
                     n0 + wn * 64 + fn * 16 + r16;
        if (OUTBF) ((ushort_t*)Cv)[off] = (ushort_t)f2b(vv);
        else       ((float*)Cv)[off] = vv;
      }
}

// ---------------------------------------------------------------------------
// Fused causal relative attention v3: K/R fragments direct from global (L2),
// per-wave R window (10 pos MFMAs), XOR-swizzled double-buffered VsT,
// 1 barrier/tile, split-j halves + merge for load balance.
// ---------------------------------------------------------------------------
__global__ __launch_bounds__(256, 4) void attn_kernel(
    const ushort_t* __restrict__ qhb, const ushort_t* __restrict__ khb,
    const ushort_t* __restrict__ vhb, const ushort_t* __restrict__ rhb,
    const float* __restrict__ rwb, const float* __restrict__ rrb,
    const float* __restrict__ rsb, const float* __restrict__ sem,
    const int* __restrict__ segbits, ushort_t* __restrict__ opart,
    float* __restrict__ ml) {
  __shared__ short VsT[2][64][72];
  __shared__ short Ps[64][72];
  __shared__ short PosL[64][81];
  __shared__ float sb_s[2][64];

  const int tid = threadIdx.x;
  const int w = tid >> 6, lane = tid & 63;
  const int r16 = lane & 15, g = lane >> 4;
  const int x = 31 - ((int)blockIdx.x >> 1);
  const int hx = blockIdx.x & 1;
  const int i0 = x * 64;
  const int nh = (x + 2) >> 1;
  const int tbeg = hx ? nh : 0;
  const int tend = hx ? (x + 1) : nh;
  const int n = blockIdx.y, b = blockIdx.z;
  const int BNS = 65536;
  const int rowbase = (b * 16 + n) * 2048 + i0;

  if (tbeg >= tend) {  // empty half (only hx==1, x==0)
    const int il0 = w * 16 + g * 4;
#pragma unroll
    for (int rr = 0; rr < 4; ++rr) {
#pragma unroll
      for (int s = 0; s < 4; ++s)
        opart[(size_t)(BNS + rowbase + il0 + rr) * 64 + s * 16 + r16] = 0;
      if (r16 == 0) {
        ml[2 * BNS + rowbase + il0 + rr] = -1e30f;
        ml[3 * BNS + rowbase + il0 + rr] = 0.f;
      }
    }
    return;
  }

  const int srow = tid >> 3, sg = (tid & 7) * 8;
  // issue V(tbeg) loads
  uint4 vpf[2];
#pragma unroll
  for (int it = 0; it < 2; ++it)
    vpf[it] = *(const uint4*)(vhb + (size_t)(b * 2048 + tbeg * 64 + srow + it * 32) * 1024 + n * 64 + sg);

  // Q prologue: fragments + segment projections
  const int qrow = i0 + w * 16 + r16;
  bf16x8 qw[2], qr[2];
  float p0 = 0.f, p1 = 0.f;
#pragma unroll
  for (int hg = 0; hg < 2; ++hg) {
    const ushort_t* qp = qhb + (size_t)(b * 2048 + qrow) * DMODEL + n * 64 + hg * 32 + g * 8;
    union { uint4 v; ushort_t us[8]; } qv; qv.v = *(const uint4*)qp;
#pragma unroll
    for (int e = 0; e < 8; ++e) {
      float qf = b2f(qv.us[e]);
      int hh = n * 64 + hg * 32 + g * 8 + e;
      qw[hg][e] = f2b(qf + rwb[hh] * NORM_F);
      qr[hg][e] = f2b(qf + rrb[hh] * NORM_F);
      float qs = qf + rsb[hh] * NORM_F;
      p0 += qs * sem[hh];
      p1 += qs * sem[DMODEL + hh];
    }
  }
  p0 += __shfl_xor(p0, 16); p0 += __shfl_xor(p0, 32);
  p1 += __shfl_xor(p1, 16); p1 += __shfl_xor(p1, 32);
  sb_s[0][w * 16 + r16] = p0;
  sb_s[1][w * 16 + r16] = p1;
  int ai_r[4];
#pragma unroll
  for (int rr = 0; rr < 4; ++rr)
    ai_r[rr] = segbits[b * 2048 + i0 + w * 16 + g * 4 + rr];

  // commit V(tbeg) into VsT[0] (swizzled)
#pragma unroll
  for (int it = 0; it < 2; ++it) {
    const int j = srow + it * 32;
    union { uint4 v; ushort_t us[8]; } vv; vv.v = vpf[it];
#pragma unroll
    for (int e = 0; e < 8; ++e) {
      const int hh = sg + e;
      VsT[0][hh][((j >> 3) ^ ((hh >> 3) & 3)) * 8 + (j & 7)] = (short)vv.us[e];
    }
  }
  __syncthreads();

  float sb0[4], sb1[4];
#pragma unroll
  for (int rr = 0; rr < 4; ++rr) {
    sb0[rr] = sb_s[0][w * 16 + g * 4 + rr];
    sb1[rr] = sb_s[1][w * 16 + g * 4 + rr];
  }
  float m_r[4], l_r[4];
#pragma unroll
  for (int rr = 0; rr < 4; ++rr) { m_r[rr] = -1e30f; l_r[rr] = 0.f; }
  f32x4 o[4] = {};

  for (int t = tbeg; t < tend; ++t) {
    const int j0 = t * 64;
    const int tt = t - tbeg;
    const bool hasn = (t + 1 < tend);
    // phase 1: prefetch next V + current aj
    uint4 vnx[2];
    if (hasn) {
#pragma unroll
      for (int it = 0; it < 2; ++it)
        vnx[it] = *(const uint4*)(vhb + (size_t)(b * 2048 + j0 + 64 + srow + it * 32) * 1024 + n * 64 + sg);
    }
    int ajv[4];
#pragma unroll
    for (int s = 0; s < 4; ++s) ajv[s] = segbits[b * 2048 + j0 + s * 16 + r16];

    __builtin_amdgcn_s_setprio(1);
    // phase 2a: pos MFMAs from global R (per-wave 80-col window)
    {
      const ushort_t* rbase = rhb + (size_t)(2048 + j0 - i0 - 15 - w * 16 + r16) * 1024 + n * 64 + g * 8;
#pragma unroll
      for (int s = 0; s < 5; ++s) {
        bf16x8 r0 = *(const bf16x8*)(rbase + (size_t)s * 16 * 1024);
        bf16x8 r1 = *(const bf16x8*)(rbase + (size_t)s * 16 * 1024 + 32);
        f32x4 pf = {};
        pf = __builtin_amdgcn_mfma_f32_16x16x32_bf16(qr[0], r0, pf, 0, 0, 0);
        pf = __builtin_amdgcn_mfma_f32_16x16x32_bf16(qr[1], r1, pf, 0, 0, 0);
#pragma unroll
        for (int rr = 0; rr < 4; ++rr)
          PosL[w * 16 + g * 4 + rr][s * 16 + r16] = f2b(pf[rr]);
      }
    }
    // phase 2b: content MFMAs from global K
    f32x4 cf[4] = {};
    {
      const ushort_t* kbase = khb + (size_t)(b * 2048 + j0 + r16) * 1024 + n * 64 + g * 8;
#pragma unroll
      for (int s = 0; s < 4; ++s) {
        bf16x8 k0 = *(const bf16x8*)(kbase + (size_t)s * 16 * 1024);
        bf16x8 k1 = *(const bf16x8*)(kbase + (size_t)s * 16 * 1024 + 32);
        cf[s] = __builtin_amdgcn_mfma_f32_16x16x32_bf16(qw[0], k0, cf[s], 0, 0, 0);
        cf[s] = __builtin_amdgcn_mfma_f32_16x16x32_bf16(qw[1], k1, cf[s], 0, 0, 0);
      }
    }
    __builtin_amdgcn_s_setprio(0);

    // phase 3: in-register online softmax
    float scl[4];
#pragma unroll
    for (int rr = 0; rr < 4; ++rr) {
      const int il = w * 16 + g * 4 + rr;
      const int c0 = r16 + 15 - g * 4 - rr;
      float vals[4];
      float vmax = -1e30f;
#pragma unroll
      for (int s = 0; s < 4; ++s) {
        float pos = b2f((ushort_t)PosL[il][c0 + s * 16]);
        float sv = cf[s][rr] + pos + ((ajv[s] == ai_r[rr]) ? sb1[rr] : sb0[rr]);
        if (j0 + s * 16 + r16 > i0 + il) sv -= 1e6f;
        vals[s] = sv;
        vmax = fmaxf(vmax, sv);
      }
      vmax = fmaxf(vmax, __shfl_xor(vmax, 1));
      vmax = fmaxf(vmax, __shfl_xor(vmax, 2));
      vmax = fmaxf(vmax, __shfl_xor(vmax, 4));
      vmax = fmaxf(vmax, __shfl_xor(vmax, 8));
      float mnew = fmaxf(m_r[rr], vmax);
      float sc_ = __expf(m_r[rr] - mnew);
      float psum = 0.f, pex[4];
#pragma unroll
      for (int s = 0; s < 4; ++s) {
        pex[s] = __expf(vals[s] - mnew);
        psum += pex[s];
      }
      psum += __shfl_xor(psum, 1);
      psum += __shfl_xor(psum, 2);
      psum += __shfl_xor(psum, 4);
      psum += __shfl_xor(psum, 8);
      l_r[rr] = l_r[rr] * sc_ + psum;
      m_r[rr] = mnew;
      scl[rr] = sc_;
#pragma unroll
      for (int s = 0; s < 4; ++s)
        Ps[il][s * 16 + r16] = f2b(pex[s]);
    }
    __syncthreads();

    // phase 5: commit next V (other buffer) + PV on current buffer
    if (hasn) {
      const int dst = (tt + 1) & 1;
#pragma unroll
      for (int it = 0; it < 2; ++it) {
        const int j = srow + it * 32;
        union { uint4 v; ushort_t us[8]; } vv; vv.v = vnx[it];
#pragma unroll
        for (int e = 0; e < 8; ++e) {
          const int hh = sg + e;
          VsT[dst][hh][((j >> 3) ^ ((hh >> 3) & 3)) * 8 + (j & 7)] = (short)vv.us[e];
        }
      }
    }
    const int src = tt & 1;
#pragma unroll
    for (int s = 0; s < 4; ++s)
#pragma unroll
      for (int rr = 0; rr < 4; ++rr) o[s][rr] *= scl[rr];
    __builtin_amdgcn_s_setprio(1);
#pragma unroll
    for (int jg = 0; jg < 2; ++jg) {
      bf16x8 pa = *(const bf16x8*)&Ps[w * 16 + r16][jg * 32 + g * 8];
#pragma unroll
      for (int s = 0; s < 4; ++s) {
        const int hh = s * 16 + r16;
        bf16x8 bv = *(const bf16x8*)&VsT[src][hh][((jg * 4 + g) ^ ((hh >> 3) & 3)) * 8];
        o[s] = __builtin_amdgcn_mfma_f32_16x16x32_bf16(pa, bv, o[s], 0, 0, 0);
      }
    }
    __builtin_amdgcn_s_setprio(0);
  }

  // epilogue: write partial o (unnormalized), m, l
#pragma unroll
  for (int s = 0; s < 4; ++s)
#pragma unroll
    for (int rr = 0; rr < 4; ++rr) {
      const int il = w * 16 + g * 4 + rr;
      opart[(size_t)(hx * BNS + rowbase + il) * 64 + s * 16 + r16] = (ushort_t)f2b(o[s][rr]);
    }
#pragma unroll
  for (int rr = 0; rr < 4; ++rr) {
    if (r16 == 0) {
      const int il = w * 16 + g * 4 + rr;
      ml[hx * 2 * BNS + rowbase + il] = m_r[rr];
      ml[(hx * 2 + 1) * BNS + rowbase + il] = l_r[rr];
    }
  }
}

// ---------------------------------------------------------------------------
// Merge the two j-halves: o = (o0*e^{m0-m} + o1*e^{m1-m}) / l
// ---------------------------------------------------------------------------
__global__ __launch_bounds__(256) void merge_kernel(
    const ushort_t* __restrict__ opart, const float* __restrict__ ml,
    ushort_t* __restrict__ av) {
  const int BNS = 65536;
  int row = blockIdx.x * 4 + (threadIdx.x >> 6);
  int lane = threadIdx.x & 63;
  float m0 = ml[row], l0 = ml[BNS + row];
  float m1 = ml[2 * BNS + row], l1 = ml[3 * BNS + row];
  float m = fmaxf(m0, m1);
  float a0 = __expf(m0 - m), a1 = __expf(m1 - m);
  float inv = 1.f / (l0 * a0 + l1 * a1);
  float o0 = b2f(opart[(size_t)row * 64 + lane]);
  float o1 = b2f(opart[(size_t)(BNS + row) * 64 + lane]);
  float ov = (o0 * a0 + o1 * a1) * inv;
  int bI = row >> 15, nI = (row >> 11) & 15, iI = row & 2047;
  av[(size_t)(bI * 2048 + iI) * 1024 + nI * 64 + lane] = (ushort_t)f2b(ov);
}

// ---------------------------------------------------------------------------
// Residual + LayerNorm
// ---------------------------------------------------------------------------
__global__ __launch_bounds__(256) void ln_kernel(
    const float* __restrict__ q, const float* __restrict__ ao,
    const float* __restrict__ ln_g, const float* __restrict__ ln_b,
    float* __restrict__ out) {
  int row = blockIdx.x;
  const float* xq = q + (size_t)row * 1024;
  const float* xa = ao + (size_t)row * 1024;
  float x[4], lsum = 0.f, lsq = 0.f;
#pragma unroll
  for (int e = 0; e < 4; ++e) {
    int d = threadIdx.x + e * 256;
    x[e] = xq[d] + xa[d];
    lsum += x[e]; lsq += x[e] * x[e];
  }
  for (int off = 1; off < 64; off <<= 1) {
    lsum += __shfl_xor(lsum, off);
    lsq += __shfl_xor(lsq, off);
  }
  __shared__ float red[8];
  int wv = threadIdx.x >> 6, ln = threadIdx.x & 63;
  if (ln == 0) { red[wv] = lsum; red[4 + wv] = lsq; }
  __syncthreads();
  lsum = red[0] + red[1] + red[2] + red[3];
  lsq = red[4] + red[5] + red[6] + red[7];
  float mu = lsum * (1.f / 1024.f);
  float var = lsq * (1.f / 1024.f) - mu * mu;
  float inv = rsqrtf(var + 1e-5f);
#pragma unroll
  for (int e = 0; e < 4; ++e) {
    int d = threadIdx.x + e * 256;
    out[(size_t)row * 1024 + d] = (x[e] - mu) * inv * ln_g[d] + ln_b[d];
  }
}

// ---------------------------------------------------------------------------
extern "C" void kernel_launch(void* const* d_in, const int* in_sizes, int n_in,
                              void* d_out, int out_size, void* d_ws, size_t ws_size,
                              hipStream_t stream) {
  const float* q   = (const float*)d_in[0];
  const float* k   = (const float*)d_in[1];
  const float* v   = (const float*)d_in[2];
  const float* pe  = (const float*)d_in[3];
  const void*  seg = d_in[4];
  const float* qW  = (const float*)d_in[6];
  const float* kW  = (const float*)d_in[7];
  const float* kb  = (const float*)d_in[8];
  const float* vW  = (const float*)d_in[9];
  const float* vb  = (const float*)d_in[10];
  const float* rwb = (const float*)d_in[11];
  const float* rrb = (const float*)d_in[12];
  const float* rK  = (const float*)d_in[13];
  const float* rsb = (const float*)d_in[14];
  const float* sem = (const float*)d_in[15];
  const float* pW  = (const float*)d_in[16];
  const float* pb  = (const float*)d_in[17];
  const float* lng = (const float*)d_in[18];
  const float* lnb = (const float*)d_in[19];
  float* out = (float*)d_out;

  const size_t MB = 1u << 20;
  char* W = (char*)d_ws;
  ushort_t* abq  = (ushort_t*)(W + 0 * MB);
  ushort_t* abk  = (ushort_t*)(W + 8 * MB);
  ushort_t* abv  = (ushort_t*)(W + 16 * MB);
  ushort_t* abpe = (ushort_t*)(W + 24 * MB);
  ushort_t* wtq  = (ushort_t*)(W + 32 * MB);
  ushort_t* wtk  = (ushort_t*)(W + 34 * MB);
  ushort_t* wtv  = (ushort_t*)(W + 36 * MB);
  ushort_t* wtr  = (ushort_t*)(W + 38 * MB);
  ushort_t* wtp  = (ushort_t*)(W + 40 * MB);
  ushort_t* qh   = (ushort_t*)(W + 42 * MB);
  ushort_t* kh   = (ushort_t*)(W + 50 * MB);
  ushort_t* vh   = (ushort_t*)(W + 58 * MB);
  ushort_t* rh   = (ushort_t*)(W + 66 * MB);
  int* segbits   = (int*)(W + 74 * MB);
  float* ml      = (float*)(W + 75 * MB);       // 1 MB
  ushort_t* opart = (ushort_t*)(W + 0 * MB);    // 32 MB, overlays conv bufs (dead)
  ushort_t* av   = (ushort_t*)(W + 66 * MB);    // overlays rh (dead post-attn)
  float*    ao   = (float*)(W + 0 * MB);        // overlays opart[0] (dead post-merge)

  seg_extract_kernel<<<dim3(1), dim3(256), 0, stream>>>((const unsigned int*)seg, segbits);
  conv4_kernel<<<dim3(2048, 4), dim3(256), 0, stream>>>(q, k, v, pe, abq, abk, abv, abpe);
  convT_kernel<<<dim3(16, 16, 5), dim3(256), 0, stream>>>(qW, kW, vW, rK, pW,
                                                          wtq, wtk, wtv, wtr, wtp);
  dim3 gg(32, 8), bb(256);
  gemm_bf_kernel<true><<<gg, bb, 0, stream>>>(abq,  wtq, (const float*)nullptr, qh, NORM_F);
  gemm_bf_kernel<true><<<gg, bb, 0, stream>>>(abk,  wtk, kb, kh, 1.0f);
  gemm_bf_kernel<true><<<gg, bb, 0, stream>>>(abv,  wtv, vb, vh, 1.0f);
  gemm_bf_kernel<true><<<gg, bb, 0, stream>>>(abpe, wtr, (const float*)nullptr, rh, 1.0f);

  attn_kernel<<<dim3(64, 16, 2), dim3(256), 0, stream>>>(qh, kh, vh, rh, rwb, rrb,
                                                         rsb, sem, segbits, opart, ml);
  merge_kernel<<<dim3(16384), dim3(256), 0, stream>>>(opart, ml, av);

  gemm_bf_kernel<false><<<gg, bb, 0, stream>>>(av, wtp, pb, ao, 1.0f);
  ln_kernel<<<dim3(4096), dim3(256), 0, stream>>>(q, ao, lng, lnb, out);
}

// Round 4
// 405.380 us; speedup vs baseline: 2.2522x; 1.0235x over previous
//
#include <hip/hip_runtime.h>
#include <hip/hip_bf16.h>

typedef __attribute__((ext_vector_type(8))) short bf16x8;
typedef __attribute__((ext_vector_type(4))) float f32x4;
typedef unsigned short ushort_t;

#define S_LEN 2048
#define DMODEL 1024
#define NORM_F 0.125f

__device__ __forceinline__ short f2b(float x) {
  union { float f; unsigned u; } c; c.f = x;
  unsigned r = (c.u + 0x7FFFu + ((c.u >> 16) & 1u)) >> 16;
  return (short)r;
}
__device__ __forceinline__ float b2f(ushort_t u) {
  union { unsigned u; float f; } c; c.u = ((unsigned)u) << 16; return c.f;
}
__device__ __forceinline__ unsigned cvtpk(float lo, float hi) {
  unsigned r;
  asm volatile("v_cvt_pk_bf16_f32 %0, %1, %2" : "=v"(r) : "v"(lo), "v"(hi));
  return r;
}

// ---------------------------------------------------------------------------
// Segment bits, packed: segw[b*64 + (i>>5)] bit (i&31) = seg id of (b, i).
// dtype detection (int32 / float32 / uint8 bool) as before.
// ---------------------------------------------------------------------------
__global__ void seg_extract_kernel(const unsigned int* __restrict__ seg_raw,
                                   unsigned* __restrict__ segw) {
  __shared__ int bad_int, bad_flt;
  int tid = threadIdx.x;
  if (tid == 0) { bad_int = 0; bad_flt = 0; }
  __syncthreads();
  for (int i = tid; i < 2048; i += 256) {
    unsigned v = seg_raw[i];
    if (v > 1u) atomicOr(&bad_int, 1);
    if (v != 0u && v != 0x3F800000u) atomicOr(&bad_flt, 1);
  }
  __syncthreads();
  int mode = bad_int ? (bad_flt ? 2 : 1) : 0;
  const unsigned char* u8 = (const unsigned char*)seg_raw;
  for (int it = 0; it < 16; ++it) {
    int P = it * 256 + tid;               // global position in [0, 4096)
    int b = P >> 11, i = P & 2047;
    size_t off = (size_t)b * S_LEN * S_LEN + i;
    int bit;
    if (mode == 0)      bit = (int)(seg_raw[off] & 1u);
    else if (mode == 1) bit = (seg_raw[off] != 0u) ? 1 : 0;
    else                bit = (int)(u8[off] & 1u);
    unsigned long long mk = __ballot(bit);
    if ((tid & 63) == 0) {
      segw[P >> 5] = (unsigned)mk;
      segw[(P >> 5) + 1] = (unsigned)(mk >> 32);
    }
  }
}

// ---------------------------------------------------------------------------
// fp32 -> bf16 plane conversion (4 planes of 4096x1024)
// ---------------------------------------------------------------------------
__global__ __launch_bounds__(256) void conv4_kernel(
    const float* __restrict__ s0, const float* __restrict__ s1,
    const float* __restrict__ s2, const float* __restrict__ s3,
    ushort_t* __restrict__ d0, ushort_t* __restrict__ d1,
    ushort_t* __restrict__ d2, ushort_t* __restrict__ d3) {
  int z = blockIdx.y;
  const float* src = z == 0 ? s0 : z == 1 ? s1 : z == 2 ? s2 : s3;
  ushort_t* dst = z == 0 ? d0 : z == 1 ? d1 : z == 2 ? d2 : d3;
  size_t base = ((size_t)blockIdx.x * 256 + threadIdx.x) * 8;
  float4 a = *(const float4*)(src + base);
  float4 b = *(const float4*)(src + base + 4);
  union { ushort_t us[8]; uint4 v; } o;
  o.us[0] = (ushort_t)f2b(a.x); o.us[1] = (ushort_t)f2b(a.y);
  o.us[2] = (ushort_t)f2b(a.z); o.us[3] = (ushort_t)f2b(a.w);
  o.us[4] = (ushort_t)f2b(b.x); o.us[5] = (ushort_t)f2b(b.y);
  o.us[6] = (ushort_t)f2b(b.z); o.us[7] = (ushort_t)f2b(b.w);
  *(uint4*)(dst + base) = o.v;
}

// ---------------------------------------------------------------------------
// Weight transpose+convert: W fp32 [1024 k][1024 n] -> Wt bf16 [n][k]
// ---------------------------------------------------------------------------
__global__ __launch_bounds__(256) void convT_kernel(
    const float* __restrict__ s0, const float* __restrict__ s1,
    const float* __restrict__ s2, const float* __restrict__ s3,
    const float* __restrict__ s4,
    ushort_t* __restrict__ d0, ushort_t* __restrict__ d1,
    ushort_t* __restrict__ d2, ushort_t* __restrict__ d3,
    ushort_t* __restrict__ d4) {
  int z = blockIdx.z;
  const float* src = z == 0 ? s0 : z == 1 ? s1 : z == 2 ? s2 : z == 3 ? s3 : s4;
  ushort_t* dst = z == 0 ? d0 : z == 1 ? d1 : z == 2 ? d2 : z == 3 ? d3 : d4;
  __shared__ float Tl[64][68];
  int tid = threadIdx.x;
  int k0 = blockIdx.x * 64, n0 = blockIdx.y * 64;
#pragma unroll
  for (int it = 0; it < 4; ++it) {
    int idx = tid + it * 256;
    int r = idx >> 4, c4 = (idx & 15) * 4;
    *(float4*)&Tl[r][c4] = *(const float4*)(src + (size_t)(k0 + r) * 1024 + n0 + c4);
  }
  __syncthreads();
#pragma unroll
  for (int it = 0; it < 2; ++it) {
    int idx = tid + it * 256;
    int nn = idx >> 3, kc = idx & 7;
    union { ushort_t us[8]; uint4 v; } o;
#pragma unroll
    for (int e = 0; e < 8; ++e) o.us[e] = (ushort_t)f2b(Tl[kc * 8 + e][nn]);
    *(uint4*)(dst + (size_t)(n0 + nn) * 1024 + k0 + kc * 8) = o.v;
  }
}

// ---------------------------------------------------------------------------
// bf16 GEMM: C[4096][1024] = scale*(A x Wt^T) + bias. 128x128 tile, 4 waves.
// ---------------------------------------------------------------------------
template <bool OUTBF>
__global__ __launch_bounds__(256) void gemm_bf_kernel(
    const ushort_t* __restrict__ A, const ushort_t* __restrict__ Wt,
    const float* __restrict__ bias, void* __restrict__ Cv, float scale) {
  __shared__ short A_lds[128][40];
  __shared__ short B_lds[128][40];
  const int tid = threadIdx.x;
  const int wave = tid >> 6, lane = tid & 63;
  const int r16 = lane & 15, g = lane >> 4;
  const int wm = wave >> 1, wn = wave & 1;
  const int m0 = blockIdx.x * 128, n0 = blockIdx.y * 128;
  const int sr = tid >> 2, sseg = (tid & 3) * 8;
  f32x4 acc[4][4] = {};
  uint4 ra0 = *(const uint4*)(A + (size_t)(m0 + sr) * 1024 + sseg);
  uint4 ra1 = *(const uint4*)(A + (size_t)(m0 + 64 + sr) * 1024 + sseg);
  uint4 rb0 = *(const uint4*)(Wt + (size_t)(n0 + sr) * 1024 + sseg);
  uint4 rb1 = *(const uint4*)(Wt + (size_t)(n0 + 64 + sr) * 1024 + sseg);
  for (int k0 = 0; k0 < 1024; k0 += 32) {
    *(uint4*)&A_lds[sr][sseg] = ra0;
    *(uint4*)&A_lds[64 + sr][sseg] = ra1;
    *(uint4*)&B_lds[sr][sseg] = rb0;
    *(uint4*)&B_lds[64 + sr][sseg] = rb1;
    __syncthreads();
    if (k0 + 32 < 1024) {
      ra0 = *(const uint4*)(A + (size_t)(m0 + sr) * 1024 + k0 + 32 + sseg);
      ra1 = *(const uint4*)(A + (size_t)(m0 + 64 + sr) * 1024 + k0 + 32 + sseg);
      rb0 = *(const uint4*)(Wt + (size_t)(n0 + sr) * 1024 + k0 + 32 + sseg);
      rb1 = *(const uint4*)(Wt + (size_t)(n0 + 64 + sr) * 1024 + k0 + 32 + sseg);
    }
    bf16x8 af[4], bfr[4];
#pragma unroll
    for (int fm = 0; fm < 4; ++fm)
      af[fm] = *(const bf16x8*)&A_lds[wm * 64 + fm * 16 + r16][g * 8];
#pragma unroll
    for (int fn = 0; fn < 4; ++fn)
      bfr[fn] = *(const bf16x8*)&B_lds[wn * 64 + fn * 16 + r16][g * 8];
#pragma unroll
    for (int fm = 0; fm < 4; ++fm)
#pragma unroll
      for (int fn = 0; fn < 4; ++fn)
        acc[fm][fn] = __builtin_amdgcn_mfma_f32_16x16x32_bf16(af[fm], bfr[fn], acc[fm][fn], 0, 0, 0);
    __syncthreads();
  }
  float bv[4];
#pragma unroll
  for (int fn = 0; fn < 4; ++fn)
    bv[fn] = bias ? bias[n0 + wn * 64 + fn * 16 + r16] : 0.f;
#pragma unroll
  for (int fm = 0; fm < 4; ++fm)
#pragma unroll
    for (int fn = 0; fn < 4; ++fn)
#pragma unroll
      for (int rr = 0; rr < 4; ++rr) {
        float vv = acc[fm][fn][rr] * scale + bv[fn];
        size_t off = (size_t)(m0 + wm * 64 + fm * 16 + g * 4 + rr) * 1024 +
                     n0 + wn * 64 + fn * 16 + r16;
        if (OUTBF) ((ushort_t*)Cv)[off] = (ushort_t)f2b(vv);
        else       ((float*)Cv)[off] = vv;
      }
}

// ---------------------------------------------------------------------------
// qprep: qwb = qh + rwb*N, qrb = qh + rrb*N (bf16); sbp[(b*16+n)*2048+i] =
// {dot(qh+rsb*N, sem0), dot(., sem1)} over the n-th 64-wide head slice.
// ---------------------------------------------------------------------------
__global__ __launch_bounds__(256) void qprep_kernel(
    const ushort_t* __restrict__ qh, const float* __restrict__ rwb,
    const float* __restrict__ rrb, const float* __restrict__ rsb,
    const float* __restrict__ sem, ushort_t* __restrict__ qwb,
    ushort_t* __restrict__ qrb, float2* __restrict__ sbp) {
  const int tid = threadIdx.x;
  const int w = tid >> 6, lane = tid & 63;
  const int c0 = lane * 16;
  float rwbN[16], rrbN[16], rsbN[16], s0v[16], s1v[16];
#pragma unroll
  for (int u = 0; u < 16; u += 4) {
    *(float4*)&rwbN[u] = *(const float4*)(rwb + c0 + u);
    *(float4*)&rrbN[u] = *(const float4*)(rrb + c0 + u);
    *(float4*)&rsbN[u] = *(const float4*)(rsb + c0 + u);
    *(float4*)&s0v[u]  = *(const float4*)(sem + c0 + u);
    *(float4*)&s1v[u]  = *(const float4*)(sem + 1024 + c0 + u);
  }
#pragma unroll
  for (int u = 0; u < 16; ++u) { rwbN[u] *= NORM_F; rrbN[u] *= NORM_F; rsbN[u] *= NORM_F; }
  for (int r = 0; r < 16; ++r) {
    int row = blockIdx.x * 64 + w * 16 + r;
    const ushort_t* qp = qh + (size_t)row * 1024 + c0;
    union { uint4 v; ushort_t us[8]; } qa, qb;
    qa.v = *(const uint4*)qp; qb.v = *(const uint4*)(qp + 8);
    float p0 = 0.f, p1 = 0.f;
    union { ushort_t us[8]; uint4 v; } w0, w1, r0, r1;
#pragma unroll
    for (int u = 0; u < 16; ++u) {
      float qv = b2f(u < 8 ? qa.us[u] : qb.us[u - 8]);
      ushort_t cw = (ushort_t)f2b(qv + rwbN[u]);
      ushort_t cr = (ushort_t)f2b(qv + rrbN[u]);
      if (u < 8) { w0.us[u] = cw; r0.us[u] = cr; }
      else       { w1.us[u - 8] = cw; r1.us[u - 8] = cr; }
      float qs = qv + rsbN[u];
      p0 += qs * s0v[u]; p1 += qs * s1v[u];
    }
    *(uint4*)(qwb + (size_t)row * 1024 + c0)     = w0.v;
    *(uint4*)(qwb + (size_t)row * 1024 + c0 + 8) = w1.v;
    *(uint4*)(qrb + (size_t)row * 1024 + c0)     = r0.v;
    *(uint4*)(qrb + (size_t)row * 1024 + c0 + 8) = r1.v;
    p0 += __shfl_xor(p0, 1); p0 += __shfl_xor(p0, 2);
    p1 += __shfl_xor(p1, 1); p1 += __shfl_xor(p1, 2);
    if ((lane & 3) == 0) {
      int bI = row >> 11, iI = row & 2047, nI = lane >> 2;
      sbp[((size_t)bI * 16 + nI) * 2048 + iI] = make_float2(p0, p1);
    }
  }
}

// ---------------------------------------------------------------------------
// Fused causal relative attention v4: swapped MFMA orientation (lane-local
// softmax rows), LDS-staged K/R (chunk-XOR swizzle), 2 barriers/tile with
// async staging, packed seg bits, diagonal-only masking, defer-max.
// ---------------------------------------------------------------------------
__global__ __launch_bounds__(256) void attn_kernel(
    const ushort_t* __restrict__ qwb, const ushort_t* __restrict__ qrb,
    const ushort_t* __restrict__ khb, const ushort_t* __restrict__ vhb,
    const ushort_t* __restrict__ rhb, const float2* __restrict__ sbp,
    const unsigned* __restrict__ segw, ushort_t* __restrict__ opart,
    float* __restrict__ ml) {
  __shared__ short Klds[64][64];
  __shared__ short Rlds[128][64];
  __shared__ short VsT[2][64][72];
  __shared__ short SP[4][1376];   // per-wave: Ps view stride 72, PosL view stride 84

  const int tid = threadIdx.x;
  const int w = tid >> 6, lane = tid & 63;
  const int r16 = lane & 15, g = lane >> 4;
  const int x = 31 - ((int)blockIdx.x >> 1);
  const int hx = blockIdx.x & 1;
  const int i0 = x * 64;
  const int nh = (x + 2) >> 1;
  const int tbeg = hx ? nh : 0;
  const int tend = hx ? (x + 1) : nh;
  const int n = blockIdx.y, b = blockIdx.z;
  const int BNS = 65536;
  const int rowbase = (b * 16 + n) * 2048 + i0;

  if (tbeg >= tend) {  // empty half (only hx==1, x==0)
    const int il0 = w * 16 + g * 4;
#pragma unroll
    for (int rr = 0; rr < 4; ++rr) {
#pragma unroll
      for (int s = 0; s < 4; ++s)
        opart[(size_t)(BNS + rowbase + il0 + rr) * 64 + s * 16 + r16] = 0;
      if (r16 == 0) {
        ml[2 * BNS + rowbase + il0 + rr] = -1e30f;
        ml[3 * BNS + rowbase + il0 + rr] = 0.f;
      }
    }
    return;
  }

  short* SPw = &SP[w][0];
  const int srow = tid >> 3, sg8 = (tid & 7) * 8;

  // per-lane persistent state (q-row = r16 within this wave's 16 rows)
  const int qrow = i0 + w * 16 + r16;
  const ushort_t* qwp = qwb + (size_t)(b * S_LEN + qrow) * DMODEL + n * 64 + g * 8;
  const ushort_t* qrp = qrb + (size_t)(b * S_LEN + qrow) * DMODEL + n * 64 + g * 8;
  bf16x8 qw[2], qr[2];
  qw[0] = *(const bf16x8*)qwp;  qw[1] = *(const bf16x8*)(qwp + 32);
  qr[0] = *(const bf16x8*)qrp;  qr[1] = *(const bf16x8*)(qrp + 32);
  float2 sbv = sbp[((size_t)b * 16 + n) * 2048 + qrow];
  const float sb0 = sbv.x, sb1 = sbv.y;
  const int ai = (segw[b * 64 + (qrow >> 5)] >> (qrow & 31)) & 1;

  // prologue: stage tile tbeg (K, R swizzled; V scattered)
  {
    const int j0 = tbeg * 64;
    const int W0 = 2048 + j0 - i0 - 63;
#pragma unroll
    for (int it = 0; it < 2; ++it) {
      int qk = tid + it * 256, row = qk >> 3, cl = qk & 7;
      uint4 kv = *(const uint4*)(khb + (size_t)(b * S_LEN + j0 + row) * DMODEL + n * 64 + cl * 8);
      *(uint4*)&Klds[row][(cl ^ (row & 7)) * 8] = kv;
    }
#pragma unroll
    for (int it = 0; it < 4; ++it) {
      int qk = tid + it * 256, row = qk >> 3, cl = qk & 7;
      uint4 rv = *(const uint4*)(rhb + (size_t)(W0 + row) * DMODEL + n * 64 + cl * 8);
      *(uint4*)&Rlds[row][(cl ^ (row & 7)) * 8] = rv;
    }
#pragma unroll
    for (int it = 0; it < 2; ++it) {
      int j = srow + it * 32;
      union { uint4 v; ushort_t us[8]; } vv;
      vv.v = *(const uint4*)(vhb + (size_t)(b * S_LEN + j0 + j) * DMODEL + n * 64 + sg8);
#pragma unroll
      for (int e = 0; e < 8; ++e) {
        int hh = sg8 + e;
        VsT[0][hh][((j >> 3) ^ ((hh >> 3) & 3)) * 8 + (j & 7)] = (short)vv.us[e];
      }
    }
  }

  float m_r = -1e30f, l_r = 0.f;
  f32x4 o[4] = {};

  for (int t = tbeg; t < tend; ++t) {
    const int j0 = t * 64;
    const int tt = (t - tbeg) & 1;
    const bool hasn = (t + 1 < tend);
    __syncthreads();  // barrier A: staged data for tile t visible

    uint4 kpf[2], rpf[4], vpf[2];
    if (hasn) {
      const int j0n = j0 + 64;
      const int W0n = 2048 + j0n - i0 - 63;
#pragma unroll
      for (int it = 0; it < 2; ++it) {
        int qk = tid + it * 256, row = qk >> 3, cl = qk & 7;
        kpf[it] = *(const uint4*)(khb + (size_t)(b * S_LEN + j0n + row) * DMODEL + n * 64 + cl * 8);
      }
#pragma unroll
      for (int it = 0; it < 4; ++it) {
        int qk = tid + it * 256, row = qk >> 3, cl = qk & 7;
        rpf[it] = *(const uint4*)(rhb + (size_t)(W0n + row) * DMODEL + n * 64 + cl * 8);
      }
#pragma unroll
      for (int it = 0; it < 2; ++it)
        vpf[it] = *(const uint4*)(vhb + (size_t)(b * S_LEN + j0n + srow + it * 32) * DMODEL + n * 64 + sg8);
    }
    unsigned wlo = segw[b * 64 + (j0 >> 5)];
    unsigned whi = segw[b * 64 + (j0 >> 5) + 1];

    // content MFMAs: cf[s][rr] = S[j = j0+s*16+g*4+rr][i = qrow]
    f32x4 cf[4] = {};
#pragma unroll
    for (int s = 0; s < 4; ++s) {
      int row = s * 16 + r16;
      bf16x8 k0 = *(const bf16x8*)&Klds[row][(g ^ (row & 7)) * 8];
      bf16x8 k1 = *(const bf16x8*)&Klds[row][((4 + g) ^ (row & 7)) * 8];
      cf[s] = __builtin_amdgcn_mfma_f32_16x16x32_bf16(k0, qw[0], cf[s], 0, 0, 0);
      cf[s] = __builtin_amdgcn_mfma_f32_16x16x32_bf16(k1, qw[1], cf[s], 0, 0, 0);
    }
    // pos MFMAs -> PosL (stride-84 view): value at (u' = sp*16+g*4+rr, qcol r16)
#pragma unroll
    for (int sp = 0; sp < 5; ++sp) {
      int row = 48 - w * 16 + sp * 16 + r16;
      bf16x8 r0 = *(const bf16x8*)&Rlds[row][(g ^ (row & 7)) * 8];
      bf16x8 r1 = *(const bf16x8*)&Rlds[row][((4 + g) ^ (row & 7)) * 8];
      f32x4 pf = {};
      pf = __builtin_amdgcn_mfma_f32_16x16x32_bf16(r0, qr[0], pf, 0, 0, 0);
      pf = __builtin_amdgcn_mfma_f32_16x16x32_bf16(r1, qr[1], pf, 0, 0, 0);
      uint2 pw;
      pw.x = cvtpk(pf[0], pf[1]);
      pw.y = cvtpk(pf[2], pf[3]);
      *(uint2*)&SPw[r16 * 84 + sp * 16 + g * 4] = pw;
    }
    // softmax (lane-local row = qrow). Read pos first (wave-lockstep => no race
    // with the Ps writes below into the same SP buffer).
    ushort_t pu[4][4];
#pragma unroll
    for (int s = 0; s < 4; ++s)
#pragma unroll
      for (int rr = 0; rr < 4; ++rr)
        pu[s][rr] = (ushort_t)SPw[r16 * 84 + (15 - r16) + s * 16 + g * 4 + rr];
    float vals[4][4];
    float vmax = -1e30f;
    const bool diag = (t == x);
#pragma unroll
    for (int s = 0; s < 4; ++s) {
      unsigned word = (s < 2) ? wlo : whi;
#pragma unroll
      for (int rr = 0; rr < 4; ++rr) {
        int p = s * 16 + g * 4 + rr;
        int bitv = (word >> (p & 31)) & 1;
        float sv = cf[s][rr] + b2f(pu[s][rr]) + ((bitv == ai) ? sb1 : sb0);
        if (diag && (p > w * 16 + r16)) sv -= 1e6f;
        vals[s][rr] = sv;
        vmax = fmaxf(vmax, sv);
      }
    }
    vmax = fmaxf(vmax, __shfl_xor(vmax, 16));
    vmax = fmaxf(vmax, __shfl_xor(vmax, 32));
    float scl = 1.f;
    bool resc = !__all(vmax <= m_r + 8.f);
    if (resc) {
      float mnew = fmaxf(m_r, vmax);
      scl = __expf(m_r - mnew);
      m_r = mnew;
    }
    float pex[4][4];
    float psum = 0.f;
#pragma unroll
    for (int s = 0; s < 4; ++s)
#pragma unroll
      for (int rr = 0; rr < 4; ++rr) {
        pex[s][rr] = __expf(vals[s][rr] - m_r);
        psum += pex[s][rr];
      }
    l_r = l_r * scl + psum;
#pragma unroll
    for (int s = 0; s < 4; ++s) {
      uint2 pw;
      pw.x = cvtpk(pex[s][0], pex[s][1]);
      pw.y = cvtpk(pex[s][2], pex[s][3]);
      *(uint2*)&SPw[r16 * 72 + s * 16 + g * 4] = pw;
    }
    __syncthreads();  // barrier B: K/R/V(t) LDS reads complete

    if (hasn) {
#pragma unroll
      for (int it = 0; it < 2; ++it) {
        int qk = tid + it * 256, row = qk >> 3, cl = qk & 7;
        *(uint4*)&Klds[row][(cl ^ (row & 7)) * 8] = kpf[it];
      }
#pragma unroll
      for (int it = 0; it < 4; ++it) {
        int qk = tid + it * 256, row = qk >> 3, cl = qk & 7;
        *(uint4*)&Rlds[row][(cl ^ (row & 7)) * 8] = rpf[it];
      }
      const int dst = tt ^ 1;
#pragma unroll
      for (int it = 0; it < 2; ++it) {
        int j = srow + it * 32;
        union { uint4 v; ushort_t us[8]; } vv; vv.v = vpf[it];
#pragma unroll
        for (int e = 0; e < 8; ++e) {
          int hh = sg8 + e;
          VsT[dst][hh][((j >> 3) ^ ((hh >> 3) & 3)) * 8 + (j & 7)] = (short)vv.us[e];
        }
      }
    }
    // PV: o[s][rr] at (i-row = g*4+rr, h = s*16+r16)
    if (resc) {
      float sclb[4];
#pragma unroll
      for (int rr = 0; rr < 4; ++rr) sclb[rr] = __shfl(scl, g * 4 + rr);
#pragma unroll
      for (int s = 0; s < 4; ++s)
#pragma unroll
        for (int rr = 0; rr < 4; ++rr) o[s][rr] *= sclb[rr];
    }
    bf16x8 pa0 = *(const bf16x8*)&SPw[r16 * 72 + g * 8];
    bf16x8 pa1 = *(const bf16x8*)&SPw[r16 * 72 + 32 + g * 8];
#pragma unroll
    for (int s = 0; s < 4; ++s) {
      int hh = s * 16 + r16;
      bf16x8 v0 = *(const bf16x8*)&VsT[tt][hh][(g ^ ((hh >> 3) & 3)) * 8];
      bf16x8 v1 = *(const bf16x8*)&VsT[tt][hh][((4 + g) ^ ((hh >> 3) & 3)) * 8];
      o[s] = __builtin_amdgcn_mfma_f32_16x16x32_bf16(pa0, v0, o[s], 0, 0, 0);
      o[s] = __builtin_amdgcn_mfma_f32_16x16x32_bf16(pa1, v1, o[s], 0, 0, 0);
    }
  }

  // epilogue
  float l_row = l_r;
  l_row += __shfl_xor(l_row, 16);
  l_row += __shfl_xor(l_row, 32);
  if (lane < 16) {
    ml[hx * 2 * BNS + rowbase + w * 16 + r16] = m_r;
    ml[(hx * 2 + 1) * BNS + rowbase + w * 16 + r16] = l_row;
  }
#pragma unroll
  for (int s = 0; s < 4; ++s)
#pragma unroll
    for (int rr = 0; rr < 4; ++rr) {
      const int il = w * 16 + g * 4 + rr;
      opart[(size_t)(hx * BNS + rowbase + il) * 64 + s * 16 + r16] = (ushort_t)f2b(o[s][rr]);
    }
}

// ---------------------------------------------------------------------------
// Merge the two j-halves: o = (o0*e^{m0-m} + o1*e^{m1-m}) / l
// ---------------------------------------------------------------------------
__global__ __launch_bounds__(256) void merge_kernel(
    const ushort_t* __restrict__ opart, const float* __restrict__ ml,
    ushort_t* __restrict__ av) {
  const int BNS = 65536;
  int row = blockIdx.x * 4 + (threadIdx.x >> 6);
  int lane = threadIdx.x & 63;
  float m0 = ml[row], l0 = ml[BNS + row];
  float m1 = ml[2 * BNS + row], l1 = ml[3 * BNS + row];
  float m = fmaxf(m0, m1);
  float a0 = __expf(m0 - m), a1 = __expf(m1 - m);
  float inv = 1.f / (l0 * a0 + l1 * a1);
  float o0 = b2f(opart[(size_t)row * 64 + lane]);
  float o1 = b2f(opart[(size_t)(BNS + row) * 64 + lane]);
  float ov = (o0 * a0 + o1 * a1) * inv;
  int bI = row >> 15, nI = (row >> 11) & 15, iI = row & 2047;
  av[(size_t)(bI * 2048 + iI) * 1024 + nI * 64 + lane] = (ushort_t)f2b(ov);
}

// ---------------------------------------------------------------------------
// Residual + LayerNorm
// ---------------------------------------------------------------------------
__global__ __launch_bounds__(256) void ln_kernel(
    const float* __restrict__ q, const float* __restrict__ ao,
    const float* __restrict__ ln_g, const float* __restrict__ ln_b,
    float* __restrict__ out) {
  int row = blockIdx.x;
  const float* xq = q + (size_t)row * 1024;
  const float* xa = ao + (size_t)row * 1024;
  float x[4], lsum = 0.f, lsq = 0.f;
#pragma unroll
  for (int e = 0; e < 4; ++e) {
    int d = threadIdx.x + e * 256;
    x[e] = xq[d] + xa[d];
    lsum += x[e]; lsq += x[e] * x[e];
  }
  for (int off = 1; off < 64; off <<= 1) {
    lsum += __shfl_xor(lsum, off);
    lsq += __shfl_xor(lsq, off);
  }
  __shared__ float red[8];
  int wv = threadIdx.x >> 6, ln = threadIdx.x & 63;
  if (ln == 0) { red[wv] = lsum; red[4 + wv] = lsq; }
  __syncthreads();
  lsum = red[0] + red[1] + red[2] + red[3];
  lsq = red[4] + red[5] + red[6] + red[7];
  float mu = lsum * (1.f / 1024.f);
  float var = lsq * (1.f / 1024.f) - mu * mu;
  float inv = rsqrtf(var + 1e-5f);
#pragma unroll
  for (int e = 0; e < 4; ++e) {
    int d = threadIdx.x + e * 256;
    out[(size_t)row * 1024 + d] = (x[e] - mu) * inv * ln_g[d] + ln_b[d];
  }
}

// ---------------------------------------------------------------------------
extern "C" void kernel_launch(void* const* d_in, const int* in_sizes, int n_in,
                              void* d_out, int out_size, void* d_ws, size_t ws_size,
                              hipStream_t stream) {
  const float* q   = (const float*)d_in[0];
  const float* k   = (const float*)d_in[1];
  const float* v   = (const float*)d_in[2];
  const float* pe  = (const float*)d_in[3];
  const void*  seg = d_in[4];
  const float* qW  = (const float*)d_in[6];
  const float* kW  = (const float*)d_in[7];
  const float* kb  = (const float*)d_in[8];
  const float* vW  = (const float*)d_in[9];
  const float* vb  = (const float*)d_in[10];
  const float* rwb = (const float*)d_in[11];
  const float* rrb = (const float*)d_in[12];
  const float* rK  = (const float*)d_in[13];
  const float* rsb = (const float*)d_in[14];
  const float* sem = (const float*)d_in[15];
  const float* pW  = (const float*)d_in[16];
  const float* pb  = (const float*)d_in[17];
  const float* lng = (const float*)d_in[18];
  const float* lnb = (const float*)d_in[19];
  float* out = (float*)d_out;

  const size_t MB = 1u << 20;
  char* W = (char*)d_ws;
  ushort_t* abq  = (ushort_t*)(W + 0 * MB);
  ushort_t* abk  = (ushort_t*)(W + 8 * MB);
  ushort_t* abv  = (ushort_t*)(W + 16 * MB);
  ushort_t* abpe = (ushort_t*)(W + 24 * MB);
  ushort_t* wtq  = (ushort_t*)(W + 32 * MB);
  ushort_t* wtk  = (ushort_t*)(W + 34 * MB);
  ushort_t* wtv  = (ushort_t*)(W + 36 * MB);
  ushort_t* wtr  = (ushort_t*)(W + 38 * MB);
  ushort_t* wtp  = (ushort_t*)(W + 40 * MB);
  ushort_t* qh   = (ushort_t*)(W + 42 * MB);
  ushort_t* kh   = (ushort_t*)(W + 50 * MB);
  ushort_t* vh   = (ushort_t*)(W + 58 * MB);
  ushort_t* rh   = (ushort_t*)(W + 66 * MB);
  unsigned* segw = (unsigned*)(W + 74 * MB);
  float2*   sbp  = (float2*)(W + 74 * MB + 65536);
  float*    ml   = (float*)(W + 75 * MB);
  // post-GEMM-phase overlays (sources are dead by the time these are written)
  ushort_t* qwb   = (ushort_t*)(W + 0 * MB);    // over abq
  ushort_t* qrb   = (ushort_t*)(W + 8 * MB);    // over abk
  ushort_t* opart = (ushort_t*)(W + 16 * MB);   // 16MB over abv+abpe
  ushort_t* av    = (ushort_t*)(W + 42 * MB);   // over qh (dead after qprep)
  float*    ao    = (float*)(W + 50 * MB);      // 16MB over kh+vh (dead post-attn)

  seg_extract_kernel<<<dim3(1), dim3(256), 0, stream>>>((const unsigned int*)seg, segw);
  conv4_kernel<<<dim3(2048, 4), dim3(256), 0, stream>>>(q, k, v, pe, abq, abk, abv, abpe);
  convT_kernel<<<dim3(16, 16, 5), dim3(256), 0, stream>>>(qW, kW, vW, rK, pW,
                                                          wtq, wtk, wtv, wtr, wtp);
  dim3 gg(32, 8), bb(256);
  gemm_bf_kernel<true><<<gg, bb, 0, stream>>>(abq,  wtq, (const float*)nullptr, qh, NORM_F);
  gemm_bf_kernel<true><<<gg, bb, 0, stream>>>(abk,  wtk, kb, kh, 1.0f);
  gemm_bf_kernel<true><<<gg, bb, 0, stream>>>(abv,  wtv, vb, vh, 1.0f);
  gemm_bf_kernel<true><<<gg, bb, 0, stream>>>(abpe, wtr, (const float*)nullptr, rh, 1.0f);

  qprep_kernel<<<dim3(64), dim3(256), 0, stream>>>(qh, rwb, rrb, rsb, sem, qwb, qrb, sbp);

  attn_kernel<<<dim3(64, 16, 2), dim3(256), 0, stream>>>(qwb, qrb, kh, vh, rh,
                                                         sbp, segw, opart, ml);
  merge_kernel<<<dim3(16384), dim3(256), 0, stream>>>(opart, ml, av);

  gemm_bf_kernel<false><<<gg, bb, 0, stream>>>(av, wtp, pb, ao, 1.0f);
  ln_kernel<<<dim3(4096), dim3(256), 0, stream>>>(q, ao, lng, lnb, out);
}

// Round 8
// 367.424 us; speedup vs baseline: 2.4849x; 1.1033x over previous
//
#include <hip/hip_runtime.h>
#include <hip/hip_bf16.h>

typedef __attribute__((ext_vector_type(8))) short bf16x8;
typedef __attribute__((ext_vector_type(4))) float f32x4;
typedef unsigned short ushort_t;

#define S_LEN 2048
#define DMODEL 1024
#define NORM_F 0.125f

__device__ __forceinline__ short f2b(float x) {
  union { float f; unsigned u; } c; c.f = x;
  unsigned r = (c.u + 0x7FFFu + ((c.u >> 16) & 1u)) >> 16;
  return (short)r;
}
__device__ __forceinline__ float b2f(ushort_t u) {
  union { unsigned u; float f; } c; c.u = ((unsigned)u) << 16; return c.f;
}
__device__ __forceinline__ unsigned cvtpk(float lo, float hi) {
  unsigned r;
  asm volatile("v_cvt_pk_bf16_f32 %0, %1, %2" : "=v"(r) : "v"(lo), "v"(hi));
  return r;
}

// ---------------------------------------------------------------------------
// Segment bits, packed: segw[b*64 + (i>>5)] bit (i&31) = seg id of (b, i).
// ---------------------------------------------------------------------------
__global__ void seg_extract_kernel(const unsigned int* __restrict__ seg_raw,
                                   unsigned* __restrict__ segw) {
  __shared__ int bad_int, bad_flt;
  int tid = threadIdx.x;
  if (tid == 0) { bad_int = 0; bad_flt = 0; }
  __syncthreads();
  for (int i = tid; i < 2048; i += 256) {
    unsigned v = seg_raw[i];
    if (v > 1u) atomicOr(&bad_int, 1);
    if (v != 0u && v != 0x3F800000u) atomicOr(&bad_flt, 1);
  }
  __syncthreads();
  int mode = bad_int ? (bad_flt ? 2 : 1) : 0;
  const unsigned char* u8 = (const unsigned char*)seg_raw;
  for (int it = 0; it < 16; ++it) {
    int P = it * 256 + tid;
    int b = P >> 11, i = P & 2047;
    size_t off = (size_t)b * S_LEN * S_LEN + i;
    int bit;
    if (mode == 0)      bit = (int)(seg_raw[off] & 1u);
    else if (mode == 1) bit = (seg_raw[off] != 0u) ? 1 : 0;
    else                bit = (int)(u8[off] & 1u);
    unsigned long long mk = __ballot(bit);
    if ((tid & 63) == 0) {
      segw[P >> 5] = (unsigned)mk;
      segw[(P >> 5) + 1] = (unsigned)(mk >> 32);
    }
  }
}

// ---------------------------------------------------------------------------
// fp32 -> bf16 plane conversion (4 planes of 4096x1024)
// ---------------------------------------------------------------------------
__global__ __launch_bounds__(256) void conv4_kernel(
    const float* __restrict__ s0, const float* __restrict__ s1,
    const float* __restrict__ s2, const float* __restrict__ s3,
    ushort_t* __restrict__ d0, ushort_t* __restrict__ d1,
    ushort_t* __restrict__ d2, ushort_t* __restrict__ d3) {
  int z = blockIdx.y;
  const float* src = z == 0 ? s0 : z == 1 ? s1 : z == 2 ? s2 : s3;
  ushort_t* dst = z == 0 ? d0 : z == 1 ? d1 : z == 2 ? d2 : d3;
  size_t base = ((size_t)blockIdx.x * 256 + threadIdx.x) * 8;
  float4 a = *(const float4*)(src + base);
  float4 b = *(const float4*)(src + base + 4);
  union { ushort_t us[8]; uint4 v; } o;
  o.us[0] = (ushort_t)f2b(a.x); o.us[1] = (ushort_t)f2b(a.y);
  o.us[2] = (ushort_t)f2b(a.z); o.us[3] = (ushort_t)f2b(a.w);
  o.us[4] = (ushort_t)f2b(b.x); o.us[5] = (ushort_t)f2b(b.y);
  o.us[6] = (ushort_t)f2b(b.z); o.us[7] = (ushort_t)f2b(b.w);
  *(uint4*)(dst + base) = o.v;
}

// ---------------------------------------------------------------------------
// Weight transpose+convert: W fp32 [1024 k][1024 n] -> Wt bf16 [n][k]
// ---------------------------------------------------------------------------
__global__ __launch_bounds__(256) void convT_kernel(
    const float* __restrict__ s0, const float* __restrict__ s1,
    const float* __restrict__ s2, const float* __restrict__ s3,
    const float* __restrict__ s4,
    ushort_t* __restrict__ d0, ushort_t* __restrict__ d1,
    ushort_t* __restrict__ d2, ushort_t* __restrict__ d3,
    ushort_t* __restrict__ d4) {
  int z = blockIdx.z;
  const float* src = z == 0 ? s0 : z == 1 ? s1 : z == 2 ? s2 : z == 3 ? s3 : s4;
  ushort_t* dst = z == 0 ? d0 : z == 1 ? d1 : z == 2 ? d2 : z == 3 ? d3 : d4;
  __shared__ float Tl[64][68];
  int tid = threadIdx.x;
  int k0 = blockIdx.x * 64, n0 = blockIdx.y * 64;
#pragma unroll
  for (int it = 0; it < 4; ++it) {
    int idx = tid + it * 256;
    int r = idx >> 4, c4 = (idx & 15) * 4;
    *(float4*)&Tl[r][c4] = *(const float4*)(src + (size_t)(k0 + r) * 1024 + n0 + c4);
  }
  __syncthreads();
#pragma unroll
  for (int it = 0; it < 2; ++it) {
    int idx = tid + it * 256;
    int nn = idx >> 3, kc = idx & 7;
    union { ushort_t us[8]; uint4 v; } o;
#pragma unroll
    for (int e = 0; e < 8; ++e) o.us[e] = (ushort_t)f2b(Tl[kc * 8 + e][nn]);
    *(uint4*)(dst + (size_t)(n0 + nn) * 1024 + k0 + kc * 8) = o.v;
  }
}

// ---------------------------------------------------------------------------
// bf16 GEMM: C[4096][1024] = scale*(A x Wt^T) + bias. 128x128 tile, 4 waves.
// ---------------------------------------------------------------------------
template <bool OUTBF>
__global__ __launch_bounds__(256) void gemm_bf_kernel(
    const ushort_t* __restrict__ A, const ushort_t* __restrict__ Wt,
    const float* __restrict__ bias, void* __restrict__ Cv, float scale) {
  __shared__ short A_lds[128][40];
  __shared__ short B_lds[128][40];
  const int tid = threadIdx.x;
  const int wave = tid >> 6, lane = tid & 63;
  const int r16 = lane & 15, g = lane >> 4;
  const int wm = wave >> 1, wn = wave & 1;
  const int m0 = blockIdx.x * 128, n0 = blockIdx.y * 128;
  const int sr = tid >> 2, sseg = (tid & 3) * 8;
  f32x4 acc[4][4] = {};
  uint4 ra0 = *(const uint4*)(A + (size_t)(m0 + sr) * 1024 + sseg);
  uint4 ra1 = *(const uint4*)(A + (size_t)(m0 + 64 + sr) * 1024 + sseg);
  uint4 rb0 = *(const uint4*)(Wt + (size_t)(n0 + sr) * 1024 + sseg);
  uint4 rb1 = *(const uint4*)(Wt + (size_t)(n0 + 64 + sr) * 1024 + sseg);
  for (int k0 = 0; k0 < 1024; k0 += 32) {
    *(uint4*)&A_lds[sr][sseg] = ra0;
    *(uint4*)&A_lds[64 + sr][sseg] = ra1;
    *(uint4*)&B_lds[sr][sseg] = rb0;
    *(uint4*)&B_lds[64 + sr][sseg] = rb1;
    __syncthreads();
    if (k0 + 32 < 1024) {
      ra0 = *(const uint4*)(A + (size_t)(m0 + sr) * 1024 + k0 + 32 + sseg);
      ra1 = *(const uint4*)(A + (size_t)(m0 + 64 + sr) * 1024 + k0 + 32 + sseg);
      rb0 = *(const uint4*)(Wt + (size_t)(n0 + sr) * 1024 + k0 + 32 + sseg);
      rb1 = *(const uint4*)(Wt + (size_t)(n0 + 64 + sr) * 1024 + k0 + 32 + sseg);
    }
    bf16x8 af[4], bfr[4];
#pragma unroll
    for (int fm = 0; fm < 4; ++fm)
      af[fm] = *(const bf16x8*)&A_lds[wm * 64 + fm * 16 + r16][g * 8];
#pragma unroll
    for (int fn = 0; fn < 4; ++fn)
      bfr[fn] = *(const bf16x8*)&B_lds[wn * 64 + fn * 16 + r16][g * 8];
#pragma unroll
    for (int fm = 0; fm < 4; ++fm)
#pragma unroll
      for (int fn = 0; fn < 4; ++fn)
        acc[fm][fn] = __builtin_amdgcn_mfma_f32_16x16x32_bf16(af[fm], bfr[fn], acc[fm][fn], 0, 0, 0);
    __syncthreads();
  }
  float bv[4];
#pragma unroll
  for (int fn = 0; fn < 4; ++fn)
    bv[fn] = bias ? bias[n0 + wn * 64 + fn * 16 + r16] : 0.f;
#pragma unroll
  for (int fm = 0; fm < 4; ++fm)
#pragma unroll
    for (int fn = 0; fn < 4; ++fn)
#pragma unroll
      for (int rr = 0; rr < 4; ++rr) {
        float vv = acc[fm][fn][rr] * scale + bv[fn];
        size_t off = (size_t)(m0 + wm * 64 + fm * 16 + g * 4 + rr) * 1024 +
                     n0 + wn * 64 + fn * 16 + r16;
        if (OUTBF) ((ushort_t*)Cv)[off] = (ushort_t)f2b(vv);
        else       ((float*)Cv)[off] = vv;
      }
}

// ---------------------------------------------------------------------------
// Batched projection GEMM: blockIdx.z selects {q,k,v,pe}. Body identical to
// gemm_bf_kernel<true>. 1024 blocks = 4 blocks/CU (vs 1 for a single GEMM).
// ---------------------------------------------------------------------------
__global__ __launch_bounds__(256) void gemm4_kernel(
    const ushort_t* __restrict__ a0, const ushort_t* __restrict__ a1,
    const ushort_t* __restrict__ a2, const ushort_t* __restrict__ a3,
    const ushort_t* __restrict__ w0, const ushort_t* __restrict__ w1,
    const ushort_t* __restrict__ w2, const ushort_t* __restrict__ w3,
    const float* __restrict__ kb, const float* __restrict__ vb,
    ushort_t* __restrict__ c0, ushort_t* __restrict__ c1,
    ushort_t* __restrict__ c2, ushort_t* __restrict__ c3) {
  const int z = blockIdx.z;
  const ushort_t* A  = z == 0 ? a0 : z == 1 ? a1 : z == 2 ? a2 : a3;
  const ushort_t* Wt = z == 0 ? w0 : z == 1 ? w1 : z == 2 ? w2 : w3;
  const float* bias  = z == 1 ? kb : z == 2 ? vb : (const float*)nullptr;
  ushort_t* C        = z == 0 ? c0 : z == 1 ? c1 : z == 2 ? c2 : c3;
  const float scale  = z == 0 ? NORM_F : 1.0f;

  __shared__ short A_lds[128][40];
  __shared__ short B_lds[128][40];
  const int tid = threadIdx.x;
  const int wave = tid >> 6, lane = tid & 63;
  const int r16 = lane & 15, g = lane >> 4;
  const int wm = wave >> 1, wn = wave & 1;
  const int m0 = blockIdx.x * 128, n0 = blockIdx.y * 128;
  const int sr = tid >> 2, sseg = (tid & 3) * 8;
  f32x4 acc[4][4] = {};
  uint4 ra0 = *(const uint4*)(A + (size_t)(m0 + sr) * 1024 + sseg);
  uint4 ra1 = *(const uint4*)(A + (size_t)(m0 + 64 + sr) * 1024 + sseg);
  uint4 rb0 = *(const uint4*)(Wt + (size_t)(n0 + sr) * 1024 + sseg);
  uint4 rb1 = *(const uint4*)(Wt + (size_t)(n0 + 64 + sr) * 1024 + sseg);
  for (int k0 = 0; k0 < 1024; k0 += 32) {
    *(uint4*)&A_lds[sr][sseg] = ra0;
    *(uint4*)&A_lds[64 + sr][sseg] = ra1;
    *(uint4*)&B_lds[sr][sseg] = rb0;
    *(uint4*)&B_lds[64 + sr][sseg] = rb1;
    __syncthreads();
    if (k0 + 32 < 1024) {
      ra0 = *(const uint4*)(A + (size_t)(m0 + sr) * 1024 + k0 + 32 + sseg);
      ra1 = *(const uint4*)(A + (size_t)(m0 + 64 + sr) * 1024 + k0 + 32 + sseg);
      rb0 = *(const uint4*)(Wt + (size_t)(n0 + sr) * 1024 + k0 + 32 + sseg);
      rb1 = *(const uint4*)(Wt + (size_t)(n0 + 64 + sr) * 1024 + k0 + 32 + sseg);
    }
    bf16x8 af[4], bfr[4];
#pragma unroll
    for (int fm = 0; fm < 4; ++fm)
      af[fm] = *(const bf16x8*)&A_lds[wm * 64 + fm * 16 + r16][g * 8];
#pragma unroll
    for (int fn = 0; fn < 4; ++fn)
      bfr[fn] = *(const bf16x8*)&B_lds[wn * 64 + fn * 16 + r16][g * 8];
#pragma unroll
    for (int fm = 0; fm < 4; ++fm)
#pragma unroll
      for (int fn = 0; fn < 4; ++fn)
        acc[fm][fn] = __builtin_amdgcn_mfma_f32_16x16x32_bf16(af[fm], bfr[fn], acc[fm][fn], 0, 0, 0);
    __syncthreads();
  }
  float bv[4];
#pragma unroll
  for (int fn = 0; fn < 4; ++fn)
    bv[fn] = bias ? bias[n0 + wn * 64 + fn * 16 + r16] : 0.f;
#pragma unroll
  for (int fm = 0; fm < 4; ++fm)
#pragma unroll
    for (int fn = 0; fn < 4; ++fn)
#pragma unroll
      for (int rr = 0; rr < 4; ++rr) {
        float vv = acc[fm][fn][rr] * scale + bv[fn];
        size_t off = (size_t)(m0 + wm * 64 + fm * 16 + g * 4 + rr) * 1024 +
                     n0 + wn * 64 + fn * 16 + r16;
        C[off] = (ushort_t)f2b(vv);
      }
}

// ---------------------------------------------------------------------------
// qprep: qwb = qh + rwb*N, qrb = qh + rrb*N (bf16); sbp = seg projections.
// ---------------------------------------------------------------------------
__global__ __launch_bounds__(256) void qprep_kernel(
    const ushort_t* __restrict__ qh, const float* __restrict__ rwb,
    const float* __restrict__ rrb, const float* __restrict__ rsb,
    const float* __restrict__ sem, ushort_t* __restrict__ qwb,
    ushort_t* __restrict__ qrb, float2* __restrict__ sbp) {
  const int tid = threadIdx.x;
  const int w = tid >> 6, lane = tid & 63;
  const int c0 = lane * 16;
  float rwbN[16], rrbN[16], rsbN[16], s0v[16], s1v[16];
#pragma unroll
  for (int u = 0; u < 16; u += 4) {
    *(float4*)&rwbN[u] = *(const float4*)(rwb + c0 + u);
    *(float4*)&rrbN[u] = *(const float4*)(rrb + c0 + u);
    *(float4*)&rsbN[u] = *(const float4*)(rsb + c0 + u);
    *(float4*)&s0v[u]  = *(const float4*)(sem + c0 + u);
    *(float4*)&s1v[u]  = *(const float4*)(sem + 1024 + c0 + u);
  }
#pragma unroll
  for (int u = 0; u < 16; ++u) { rwbN[u] *= NORM_F; rrbN[u] *= NORM_F; rsbN[u] *= NORM_F; }
  for (int r = 0; r < 16; ++r) {
    int row = blockIdx.x * 64 + w * 16 + r;
    const ushort_t* qp = qh + (size_t)row * 1024 + c0;
    union { uint4 v; ushort_t us[8]; } qa, qb;
    qa.v = *(const uint4*)qp; qb.v = *(const uint4*)(qp + 8);
    float p0 = 0.f, p1 = 0.f;
    union { ushort_t us[8]; uint4 v; } w0, w1, r0, r1;
#pragma unroll
    for (int u = 0; u < 16; ++u) {
      float qv = b2f(u < 8 ? qa.us[u] : qb.us[u - 8]);
      ushort_t cw = (ushort_t)f2b(qv + rwbN[u]);
      ushort_t cr = (ushort_t)f2b(qv + rrbN[u]);
      if (u < 8) { w0.us[u] = cw; r0.us[u] = cr; }
      else       { w1.us[u - 8] = cw; r1.us[u - 8] = cr; }
      float qs = qv + rsbN[u];
      p0 += qs * s0v[u]; p1 += qs * s1v[u];
    }
    *(uint4*)(qwb + (size_t)row * 1024 + c0)     = w0.v;
    *(uint4*)(qwb + (size_t)row * 1024 + c0 + 8) = w1.v;
    *(uint4*)(qrb + (size_t)row * 1024 + c0)     = r0.v;
    *(uint4*)(qrb + (size_t)row * 1024 + c0 + 8) = r1.v;
    p0 += __shfl_xor(p0, 1); p0 += __shfl_xor(p0, 2);
    p1 += __shfl_xor(p1, 1); p1 += __shfl_xor(p1, 2);
    if ((lane & 3) == 0) {
      int bI = row >> 11, iI = row & 2047, nI = lane >> 2;
      sbp[((size_t)bI * 16 + nI) * 2048 + iI] = make_float2(p0, p1);
    }
  }
}

// ---------------------------------------------------------------------------
// Fused causal relative attention v4 (byte-exact from R4, the last PASS):
// swapped MFMA orientation, LDS-staged K/R (chunk-XOR swizzle), 2 barriers/
// tile with async staging, packed seg bits, diagonal-only masking, defer-max.
// ---------------------------------------------------------------------------
__global__ __launch_bounds__(256) void attn_kernel(
    const ushort_t* __restrict__ qwb, const ushort_t* __restrict__ qrb,
    const ushort_t* __restrict__ khb, const ushort_t* __restrict__ vhb,
    const ushort_t* __restrict__ rhb, const float2* __restrict__ sbp,
    const unsigned* __restrict__ segw, ushort_t* __restrict__ opart,
    float* __restrict__ ml) {
  __shared__ short Klds[64][64];
  __shared__ short Rlds[128][64];
  __shared__ short VsT[2][64][72];
  __shared__ short SP[4][1376];

  const int tid = threadIdx.x;
  const int w = tid >> 6, lane = tid & 63;
  const int r16 = lane & 15, g = lane >> 4;
  const int x = 31 - ((int)blockIdx.x >> 1);
  const int hx = blockIdx.x & 1;
  const int i0 = x * 64;
  const int nh = (x + 2) >> 1;
  const int tbeg = hx ? nh : 0;
  const int tend = hx ? (x + 1) : nh;
  const int n = blockIdx.y, b = blockIdx.z;
  const int BNS = 65536;
  const int rowbase = (b * 16 + n) * 2048 + i0;

  if (tbeg >= tend) {  // empty half (only hx==1, x==0)
    const int il0 = w * 16 + g * 4;
#pragma unroll
    for (int rr = 0; rr < 4; ++rr) {
#pragma unroll
      for (int s = 0; s < 4; ++s)
        opart[(size_t)(BNS + rowbase + il0 + rr) * 64 + s * 16 + r16] = 0;
      if (r16 == 0) {
        ml[2 * BNS + rowbase + il0 + rr] = -1e30f;
        ml[3 * BNS + rowbase + il0 + rr] = 0.f;
      }
    }
    return;
  }

  short* SPw = &SP[w][0];
  const int srow = tid >> 3, sg8 = (tid & 7) * 8;

  // per-lane persistent state (q-row = r16 within this wave's 16 rows)
  const int qrow = i0 + w * 16 + r16;
  const ushort_t* qwp = qwb + (size_t)(b * S_LEN + qrow) * DMODEL + n * 64 + g * 8;
  const ushort_t* qrp = qrb + (size_t)(b * S_LEN + qrow) * DMODEL + n * 64 + g * 8;
  bf16x8 qw[2], qr[2];
  qw[0] = *(const bf16x8*)qwp;  qw[1] = *(const bf16x8*)(qwp + 32);
  qr[0] = *(const bf16x8*)qrp;  qr[1] = *(const bf16x8*)(qrp + 32);
  float2 sbv = sbp[((size_t)b * 16 + n) * 2048 + qrow];
  const float sb0 = sbv.x, sb1 = sbv.y;
  const int ai = (segw[b * 64 + (qrow >> 5)] >> (qrow & 31)) & 1;
  const int iw0 = i0 + w * 16;

  // prologue: stage tile tbeg (K, R swizzled; V scattered)
  {
    const int j0 = tbeg * 64;
    const int W0 = 2048 + j0 - i0 - 63;
#pragma unroll
    for (int it = 0; it < 2; ++it) {
      int qk = tid + it * 256, row = qk >> 3, cl = qk & 7;
      uint4 kv = *(const uint4*)(khb + (size_t)(b * S_LEN + j0 + row) * DMODEL + n * 64 + cl * 8);
      *(uint4*)&Klds[row][(cl ^ (row & 7)) * 8] = kv;
    }
#pragma unroll
    for (int it = 0; it < 4; ++it) {
      int qk = tid + it * 256, row = qk >> 3, cl = qk & 7;
      uint4 rv = *(const uint4*)(rhb + (size_t)(W0 + row) * DMODEL + n * 64 + cl * 8);
      *(uint4*)&Rlds[row][(cl ^ (row & 7)) * 8] = rv;
    }
#pragma unroll
    for (int it = 0; it < 2; ++it) {
      int j = srow + it * 32;
      union { uint4 v; ushort_t us[8]; } vv;
      vv.v = *(const uint4*)(vhb + (size_t)(b * S_LEN + j0 + j) * DMODEL + n * 64 + sg8);
#pragma unroll
      for (int e = 0; e < 8; ++e) {
        int hh = sg8 + e;
        VsT[0][hh][((j >> 3) ^ ((hh >> 3) & 3)) * 8 + (j & 7)] = (short)vv.us[e];
      }
    }
  }

  float m_r = -1e30f, l_r = 0.f;
  f32x4 o[4] = {};

  for (int t = tbeg; t < tend; ++t) {
    const int j0 = t * 64;
    const int tt = (t - tbeg) & 1;
    const bool hasn = (t + 1 < tend);
    __syncthreads();  // barrier A: staged data for tile t visible

    uint4 kpf[2], rpf[4], vpf[2];
    if (hasn) {
      const int j0n = j0 + 64;
      const int W0n = 2048 + j0n - i0 - 63;
#pragma unroll
      for (int it = 0; it < 2; ++it) {
        int qk = tid + it * 256, row = qk >> 3, cl = qk & 7;
        kpf[it] = *(const uint4*)(khb + (size_t)(b * S_LEN + j0n + row) * DMODEL + n * 64 + cl * 8);
      }
#pragma unroll
      for (int it = 0; it < 4; ++it) {
        int qk = tid + it * 256, row = qk >> 3, cl = qk & 7;
        rpf[it] = *(const uint4*)(rhb + (size_t)(W0n + row) * DMODEL + n * 64 + cl * 8);
      }
#pragma unroll
      for (int it = 0; it < 2; ++it)
        vpf[it] = *(const uint4*)(vhb + (size_t)(b * S_LEN + j0n + srow + it * 32) * DMODEL + n * 64 + sg8);
    }
    unsigned wlo = segw[b * 64 + (j0 >> 5)];
    unsigned whi = segw[b * 64 + (j0 >> 5) + 1];

    // content MFMAs: cf[s][rr] = S[j = j0+s*16+g*4+rr][i = qrow]
    f32x4 cf[4] = {};
#pragma unroll
    for (int s = 0; s < 4; ++s) {
      int row = s * 16 + r16;
      bf16x8 k0 = *(const bf16x8*)&Klds[row][(g ^ (row & 7)) * 8];
      bf16x8 k1 = *(const bf16x8*)&Klds[row][((4 + g) ^ (row & 7)) * 8];
      cf[s] = __builtin_amdgcn_mfma_f32_16x16x32_bf16(k0, qw[0], cf[s], 0, 0, 0);
      cf[s] = __builtin_amdgcn_mfma_f32_16x16x32_bf16(k1, qw[1], cf[s], 0, 0, 0);
    }
    // pos MFMAs -> PosL (stride-84 view): value at (u' = sp*16+g*4+rr, qcol r16)
#pragma unroll
    for (int sp = 0; sp < 5; ++sp) {
      int row = 48 - w * 16 + sp * 16 + r16;
      bf16x8 r0 = *(const bf16x8*)&Rlds[row][(g ^ (row & 7)) * 8];
      bf16x8 r1 = *(const bf16x8*)&Rlds[row][((4 + g) ^ (row & 7)) * 8];
      f32x4 pf = {};
      pf = __builtin_amdgcn_mfma_f32_16x16x32_bf16(r0, qr[0], pf, 0, 0, 0);
      pf = __builtin_amdgcn_mfma_f32_16x16x32_bf16(r1, qr[1], pf, 0, 0, 0);
      uint2 pw;
      pw.x = cvtpk(pf[0], pf[1]);
      pw.y = cvtpk(pf[2], pf[3]);
      *(uint2*)&SPw[r16 * 84 + sp * 16 + g * 4] = pw;
    }
    // softmax (lane-local row = qrow). Read pos first (wave-lockstep => no race
    // with the Ps writes below into the same SP buffer).
    ushort_t pu[4][4];
#pragma unroll
    for (int s = 0; s < 4; ++s)
#pragma unroll
      for (int rr = 0; rr < 4; ++rr)
        pu[s][rr] = (ushort_t)SPw[r16 * 84 + (15 - r16) + s * 16 + g * 4 + rr];
    float vals[4][4];
    float vmax = -1e30f;
    const bool diag = (t == x);
#pragma unroll
    for (int s = 0; s < 4; ++s) {
      unsigned word = (s < 2) ? wlo : whi;
#pragma unroll
      for (int rr = 0; rr < 4; ++rr) {
        int p = s * 16 + g * 4 + rr;
        int bitv = (word >> (p & 31)) & 1;
        float sv = cf[s][rr] + b2f(pu[s][rr]) + ((bitv == ai) ? sb1 : sb0);
        if (diag && (p > w * 16 + r16)) sv -= 1e6f;
        vals[s][rr] = sv;
        vmax = fmaxf(vmax, sv);
      }
    }
    vmax = fmaxf(vmax, __shfl_xor(vmax, 16));
    vmax = fmaxf(vmax, __shfl_xor(vmax, 32));
    float scl = 1.f;
    bool resc = !__all(vmax <= m_r + 8.f);
    if (resc) {
      float mnew = fmaxf(m_r, vmax);
      scl = __expf(m_r - mnew);
      m_r = mnew;
    }
    float pex[4][4];
    float psum = 0.f;
#pragma unroll
    for (int s = 0; s < 4; ++s)
#pragma unroll
      for (int rr = 0; rr < 4; ++rr) {
        pex[s][rr] = __expf(vals[s][rr] - m_r);
        psum += pex[s][rr];
      }
    l_r = l_r * scl + psum;
#pragma unroll
    for (int s = 0; s < 4; ++s) {
      uint2 pw;
      pw.x = cvtpk(pex[s][0], pex[s][1]);
      pw.y = cvtpk(pex[s][2], pex[s][3]);
      *(uint2*)&SPw[r16 * 72 + s * 16 + g * 4] = pw;
    }
    __syncthreads();  // barrier B: K/R/V(t) LDS reads complete

    if (hasn) {
#pragma unroll
      for (int it = 0; it < 2; ++it) {
        int qk = tid + it * 256, row = qk >> 3, cl = qk & 7;
        *(uint4*)&Klds[row][(cl ^ (row & 7)) * 8] = kpf[it];
      }
#pragma unroll
      for (int it = 0; it < 4; ++it) {
        int qk = tid + it * 256, row = qk >> 3, cl = qk & 7;
        *(uint4*)&Rlds[row][(cl ^ (row & 7)) * 8] = rpf[it];
      }
      const int dst = tt ^ 1;
#pragma unroll
      for (int it = 0; it < 2; ++it) {
        int j = srow + it * 32;
        union { uint4 v; ushort_t us[8]; } vv; vv.v = vpf[it];
#pragma unroll
        for (int e = 0; e < 8; ++e) {
          int hh = sg8 + e;
          VsT[dst][hh][((j >> 3) ^ ((hh >> 3) & 3)) * 8 + (j & 7)] = (short)vv.us[e];
        }
      }
    }
    // PV: o[s][rr] at (i-row = g*4+rr, h = s*16+r16)
    if (resc) {
      float sclb[4];
#pragma unroll
      for (int rr = 0; rr < 4; ++rr) sclb[rr] = __shfl(scl, g * 4 + rr);
#pragma unroll
      for (int s = 0; s < 4; ++s)
#pragma unroll
        for (int rr = 0; rr < 4; ++rr) o[s][rr] *= sclb[rr];
    }
    bf16x8 pa0 = *(const bf16x8*)&SPw[r16 * 72 + g * 8];
    bf16x8 pa1 = *(const bf16x8*)&SPw[r16 * 72 + 32 + g * 8];
#pragma unroll
    for (int s = 0; s < 4; ++s) {
      int hh = s * 16 + r16;
      bf16x8 v0 = *(const bf16x8*)&VsT[tt][hh][(g ^ ((hh >> 3) & 3)) * 8];
      bf16x8 v1 = *(const bf16x8*)&VsT[tt][hh][((4 + g) ^ ((hh >> 3) & 3)) * 8];
      o[s] = __builtin_amdgcn_mfma_f32_16x16x32_bf16(pa0, v0, o[s], 0, 0, 0);
      o[s] = __builtin_amdgcn_mfma_f32_16x16x32_bf16(pa1, v1, o[s], 0, 0, 0);
    }
  }

  // epilogue
  float l_row = l_r;
  l_row += __shfl_xor(l_row, 16);
  l_row += __shfl_xor(l_row, 32);
  if (lane < 16) {
    ml[hx * 2 * BNS + rowbase + w * 16 + r16] = m_r;
    ml[(hx * 2 + 1) * BNS + rowbase + w * 16 + r16] = l_row;
  }
#pragma unroll
  for (int s = 0; s < 4; ++s)
#pragma unroll
    for (int rr = 0; rr < 4; ++rr) {
      const int il = w * 16 + g * 4 + rr;
      opart[(size_t)(hx * BNS + rowbase + il) * 64 + s * 16 + r16] = (ushort_t)f2b(o[s][rr]);
    }
}

// ---------------------------------------------------------------------------
// Merge the two j-halves: o = (o0*e^{m0-m} + o1*e^{m1-m}) / l
// ---------------------------------------------------------------------------
__global__ __launch_bounds__(256) void merge_kernel(
    const ushort_t* __restrict__ opart, const float* __restrict__ ml,
    ushort_t* __restrict__ av) {
  const int BNS = 65536;
  int row = blockIdx.x * 4 + (threadIdx.x >> 6);
  int lane = threadIdx.x & 63;
  float m0 = ml[row], l0 = ml[BNS + row];
  float m1 = ml[2 * BNS + row], l1 = ml[3 * BNS + row];
  float m = fmaxf(m0, m1);
  float a0 = __expf(m0 - m), a1 = __expf(m1 - m);
  float inv = 1.f / (l0 * a0 + l1 * a1);
  float o0 = b2f(opart[(size_t)row * 64 + lane]);
  float o1 = b2f(opart[(size_t)(BNS + row) * 64 + lane]);
  float ov = (o0 * a0 + o1 * a1) * inv;
  int bI = row >> 15, nI = (row >> 11) & 15, iI = row & 2047;
  av[(size_t)(bI * 2048 + iI) * 1024 + nI * 64 + lane] = (ushort_t)f2b(ov);
}

// ---------------------------------------------------------------------------
// Residual + LayerNorm
// ---------------------------------------------------------------------------
__global__ __launch_bounds__(256) void ln_kernel(
    const float* __restrict__ q, const float* __restrict__ ao,
    const float* __restrict__ ln_g, const float* __restrict__ ln_b,
    float* __restrict__ out) {
  int row = blockIdx.x;
  const float* xq = q + (size_t)row * 1024;
  const float* xa = ao + (size_t)row * 1024;
  float x[4], lsum = 0.f, lsq = 0.f;
#pragma unroll
  for (int e = 0; e < 4; ++e) {
    int d = threadIdx.x + e * 256;
    x[e] = xq[d] + xa[d];
    lsum += x[e]; lsq += x[e] * x[e];
  }
  for (int off = 1; off < 64; off <<= 1) {
    lsum += __shfl_xor(lsum, off);
    lsq += __shfl_xor(lsq, off);
  }
  __shared__ float red[8];
  int wv = threadIdx.x >> 6, ln = threadIdx.x & 63;
  if (ln == 0) { red[wv] = lsum; red[4 + wv] = lsq; }
  __syncthreads();
  lsum = red[0] + red[1] + red[2] + red[3];
  lsq = red[4] + red[5] + red[6] + red[7];
  float mu = lsum * (1.f / 1024.f);
  float var = lsq * (1.f / 1024.f) - mu * mu;
  float inv = rsqrtf(var + 1e-5f);
#pragma unroll
  for (int e = 0; e < 4; ++e) {
    int d = threadIdx.x + e * 256;
    out[(size_t)row * 1024 + d] = (x[e] - mu) * inv * ln_g[d] + ln_b[d];
  }
}

// ---------------------------------------------------------------------------
extern "C" void kernel_launch(void* const* d_in, const int* in_sizes, int n_in,
                              void* d_out, int out_size, void* d_ws, size_t ws_size,
                              hipStream_t stream) {
  const float* q   = (const float*)d_in[0];
  const float* k   = (const float*)d_in[1];
  const float* v   = (const float*)d_in[2];
  const float* pe  = (const float*)d_in[3];
  const void*  seg = d_in[4];
  const float* qW  = (const float*)d_in[6];
  const float* kW  = (const float*)d_in[7];
  const float* kb  = (const float*)d_in[8];
  const float* vW  = (const float*)d_in[9];
  const float* vb  = (const float*)d_in[10];
  const float* rwb = (const float*)d_in[11];
  const float* rrb = (const float*)d_in[12];
  const float* rK  = (const float*)d_in[13];
  const float* rsb = (const float*)d_in[14];
  const float* sem = (const float*)d_in[15];
  const float* pW  = (const float*)d_in[16];
  const float* pb  = (const float*)d_in[17];
  const float* lng = (const float*)d_in[18];
  const float* lnb = (const float*)d_in[19];
  float* out = (float*)d_out;

  const size_t MB = 1u << 20;
  char* W = (char*)d_ws;
  ushort_t* abq  = (ushort_t*)(W + 0 * MB);
  ushort_t* abk  = (ushort_t*)(W + 8 * MB);
  ushort_t* abv  = (ushort_t*)(W + 16 * MB);
  ushort_t* abpe = (ushort_t*)(W + 24 * MB);
  ushort_t* wtq  = (ushort_t*)(W + 32 * MB);
  ushort_t* wtk  = (ushort_t*)(W + 34 * MB);
  ushort_t* wtv  = (ushort_t*)(W + 36 * MB);
  ushort_t* wtr  = (ushort_t*)(W + 38 * MB);
  ushort_t* wtp  = (ushort_t*)(W + 40 * MB);
  ushort_t* qh   = (ushort_t*)(W + 42 * MB);
  ushort_t* kh   = (ushort_t*)(W + 50 * MB);
  ushort_t* vh   = (ushort_t*)(W + 58 * MB);
  ushort_t* rh   = (ushort_t*)(W + 66 * MB);
  unsigned* segw = (unsigned*)(W + 74 * MB);
  float2*   sbp  = (float2*)(W + 74 * MB + 65536);
  float*    ml   = (float*)(W + 75 * MB);
  // post-GEMM-phase overlays (sources are dead by the time these are written)
  ushort_t* qwb   = (ushort_t*)(W + 0 * MB);    // over abq
  ushort_t* qrb   = (ushort_t*)(W + 8 * MB);    // over abk
  ushort_t* opart = (ushort_t*)(W + 16 * MB);   // 16MB over abv+abpe
  ushort_t* av    = (ushort_t*)(W + 42 * MB);   // over qh (dead after qprep)
  float*    ao    = (float*)(W + 50 * MB);      // 16MB over kh+vh (dead post-attn)

  seg_extract_kernel<<<dim3(1), dim3(256), 0, stream>>>((const unsigned int*)seg, segw);
  conv4_kernel<<<dim3(2048, 4), dim3(256), 0, stream>>>(q, k, v, pe, abq, abk, abv, abpe);
  convT_kernel<<<dim3(16, 16, 5), dim3(256), 0, stream>>>(qW, kW, vW, rK, pW,
                                                          wtq, wtk, wtv, wtr, wtp);
  // batched projection GEMMs: one dispatch, 4 blocks/CU
  gemm4_kernel<<<dim3(32, 8, 4), dim3(256), 0, stream>>>(
      abq, abk, abv, abpe, wtq, wtk, wtv, wtr, kb, vb, qh, kh, vh, rh);

  qprep_kernel<<<dim3(64), dim3(256), 0, stream>>>(qh, rwb, rrb, rsb, sem, qwb, qrb, sbp);

  attn_kernel<<<dim3(64, 16, 2), dim3(256), 0, stream>>>(qwb, qrb, kh, vh, rh,
                                                         sbp, segw, opart, ml);
  merge_kernel<<<dim3(16384), dim3(256), 0, stream>>>(opart, ml, av);

  gemm_bf_kernel<false><<<dim3(32, 8), dim3(256), 0, stream>>>(av, wtp, pb, ao, 1.0f);
  ln_kernel<<<dim3(4096), dim3(256), 0, stream>>>(q, ao, lng, lnb, out);
}

// Round 9
// 283.227 us; speedup vs baseline: 3.2236x; 1.2973x over previous
//
#include <hip/hip_runtime.h>
#include <hip/hip_bf16.h>

typedef __attribute__((ext_vector_type(8))) short bf16x8;
typedef __attribute__((ext_vector_type(4))) float f32x4;
typedef unsigned short ushort_t;

#define S_LEN 2048
#define DMODEL 1024
#define NORM_F 0.125f

__device__ __forceinline__ short f2b(float x) {
  union { float f; unsigned u; } c; c.f = x;
  unsigned r = (c.u + 0x7FFFu + ((c.u >> 16) & 1u)) >> 16;
  return (short)r;
}
__device__ __forceinline__ float b2f(ushort_t u) {
  union { unsigned u; float f; } c; c.u = ((unsigned)u) << 16; return c.f;
}
__device__ __forceinline__ unsigned cvtpk(float lo, float hi) {
  unsigned r;
  asm volatile("v_cvt_pk_bf16_f32 %0, %1, %2" : "=v"(r) : "v"(lo), "v"(hi));
  return r;
}

// ---------------------------------------------------------------------------
// Segment bits, packed: segw[b*64 + (i>>5)] bit (i&31) = seg id of (b, i).
// 16 blocks; each re-runs the cheap dtype detection and packs 256 positions.
// ---------------------------------------------------------------------------
__global__ void seg_extract_kernel(const unsigned int* __restrict__ seg_raw,
                                   unsigned* __restrict__ segw) {
  __shared__ int bad_int, bad_flt;
  int tid = threadIdx.x;
  if (tid == 0) { bad_int = 0; bad_flt = 0; }
  __syncthreads();
  for (int i = tid; i < 2048; i += 256) {
    unsigned v = seg_raw[i];
    if (v > 1u) atomicOr(&bad_int, 1);
    if (v != 0u && v != 0x3F800000u) atomicOr(&bad_flt, 1);
  }
  __syncthreads();
  int mode = bad_int ? (bad_flt ? 2 : 1) : 0;
  const unsigned char* u8 = (const unsigned char*)seg_raw;
  int P = blockIdx.x * 256 + tid;       // [0, 4096)
  int b = P >> 11, i = P & 2047;
  size_t off = (size_t)b * S_LEN * S_LEN + i;
  int bit;
  if (mode == 0)      bit = (int)(seg_raw[off] & 1u);
  else if (mode == 1) bit = (seg_raw[off] != 0u) ? 1 : 0;
  else                bit = (int)(u8[off] & 1u);
  unsigned long long mk = __ballot(bit);
  if ((tid & 63) == 0) {
    segw[P >> 5] = (unsigned)mk;
    segw[(P >> 5) + 1] = (unsigned)(mk >> 32);
  }
}

// ---------------------------------------------------------------------------
// fp32 -> bf16 plane conversion (4 planes of 4096x1024)
// ---------------------------------------------------------------------------
__global__ __launch_bounds__(256) void conv4_kernel(
    const float* __restrict__ s0, const float* __restrict__ s1,
    const float* __restrict__ s2, const float* __restrict__ s3,
    ushort_t* __restrict__ d0, ushort_t* __restrict__ d1,
    ushort_t* __restrict__ d2, ushort_t* __restrict__ d3) {
  int z = blockIdx.y;
  const float* src = z == 0 ? s0 : z == 1 ? s1 : z == 2 ? s2 : s3;
  ushort_t* dst = z == 0 ? d0 : z == 1 ? d1 : z == 2 ? d2 : d3;
  size_t base = ((size_t)blockIdx.x * 256 + threadIdx.x) * 8;
  float4 a = *(const float4*)(src + base);
  float4 b = *(const float4*)(src + base + 4);
  union { ushort_t us[8]; uint4 v; } o;
  o.us[0] = (ushort_t)f2b(a.x); o.us[1] = (ushort_t)f2b(a.y);
  o.us[2] = (ushort_t)f2b(a.z); o.us[3] = (ushort_t)f2b(a.w);
  o.us[4] = (ushort_t)f2b(b.x); o.us[5] = (ushort_t)f2b(b.y);
  o.us[6] = (ushort_t)f2b(b.z); o.us[7] = (ushort_t)f2b(b.w);
  *(uint4*)(dst + base) = o.v;
}

// ---------------------------------------------------------------------------
// Weight transpose+convert: W fp32 [1024 k][1024 n] -> Wt bf16 [n][k]
// ---------------------------------------------------------------------------
__global__ __launch_bounds__(256) void convT_kernel(
    const float* __restrict__ s0, const float* __restrict__ s1,
    const float* __restrict__ s2, const float* __restrict__ s3,
    const float* __restrict__ s4,
    ushort_t* __restrict__ d0, ushort_t* __restrict__ d1,
    ushort_t* __restrict__ d2, ushort_t* __restrict__ d3,
    ushort_t* __restrict__ d4) {
  int z = blockIdx.z;
  const float* src = z == 0 ? s0 : z == 1 ? s1 : z == 2 ? s2 : z == 3 ? s3 : s4;
  ushort_t* dst = z == 0 ? d0 : z == 1 ? d1 : z == 2 ? d2 : z == 3 ? d3 : d4;
  __shared__ float Tl[64][68];
  int tid = threadIdx.x;
  int k0 = blockIdx.x * 64, n0 = blockIdx.y * 64;
#pragma unroll
  for (int it = 0; it < 4; ++it) {
    int idx = tid + it * 256;
    int r = idx >> 4, c4 = (idx & 15) * 4;
    *(float4*)&Tl[r][c4] = *(const float4*)(src + (size_t)(k0 + r) * 1024 + n0 + c4);
  }
  __syncthreads();
#pragma unroll
  for (int it = 0; it < 2; ++it) {
    int idx = tid + it * 256;
    int nn = idx >> 3, kc = idx & 7;
    union { ushort_t us[8]; uint4 v; } o;
#pragma unroll
    for (int e = 0; e < 8; ++e) o.us[e] = (ushort_t)f2b(Tl[kc * 8 + e][nn]);
    *(uint4*)(dst + (size_t)(n0 + nn) * 1024 + k0 + kc * 8) = o.v;
  }
}

// ---------------------------------------------------------------------------
// bf16 GEMM: C[4096][1024] = scale*(A x Wt^T) + bias. 128x128 tile, 4 waves.
// ---------------------------------------------------------------------------
template <bool OUTBF>
__global__ __launch_bounds__(256) void gemm_bf_kernel(
    const ushort_t* __restrict__ A, const ushort_t* __restrict__ Wt,
    const float* __restrict__ bias, void* __restrict__ Cv, float scale) {
  __shared__ short A_lds[128][40];
  __shared__ short B_lds[128][40];
  const int tid = threadIdx.x;
  const int wave = tid >> 6, lane = tid & 63;
  const int r16 = lane & 15, g = lane >> 4;
  const int wm = wave >> 1, wn = wave & 1;
  const int m0 = blockIdx.x * 128, n0 = blockIdx.y * 128;
  const int sr = tid >> 2, sseg = (tid & 3) * 8;
  f32x4 acc[4][4] = {};
  uint4 ra0 = *(const uint4*)(A + (size_t)(m0 + sr) * 1024 + sseg);
  uint4 ra1 = *(const uint4*)(A + (size_t)(m0 + 64 + sr) * 1024 + sseg);
  uint4 rb0 = *(const uint4*)(Wt + (size_t)(n0 + sr) * 1024 + sseg);
  uint4 rb1 = *(const uint4*)(Wt + (size_t)(n0 + 64 + sr) * 1024 + sseg);
  for (int k0 = 0; k0 < 1024; k0 += 32) {
    *(uint4*)&A_lds[sr][sseg] = ra0;
    *(uint4*)&A_lds[64 + sr][sseg] = ra1;
    *(uint4*)&B_lds[sr][sseg] = rb0;
    *(uint4*)&B_lds[64 + sr][sseg] = rb1;
    __syncthreads();
    if (k0 + 32 < 1024) {
      ra0 = *(const uint4*)(A + (size_t)(m0 + sr) * 1024 + k0 + 32 + sseg);
      ra1 = *(const uint4*)(A + (size_t)(m0 + 64 + sr) * 1024 + k0 + 32 + sseg);
      rb0 = *(const uint4*)(Wt + (size_t)(n0 + sr) * 1024 + k0 + 32 + sseg);
      rb1 = *(const uint4*)(Wt + (size_t)(n0 + 64 + sr) * 1024 + k0 + 32 + sseg);
    }
    bf16x8 af[4], bfr[4];
#pragma unroll
    for (int fm = 0; fm < 4; ++fm)
      af[fm] = *(const bf16x8*)&A_lds[wm * 64 + fm * 16 + r16][g * 8];
#pragma unroll
    for (int fn = 0; fn < 4; ++fn)
      bfr[fn] = *(const bf16x8*)&B_lds[wn * 64 + fn * 16 + r16][g * 8];
#pragma unroll
    for (int fm = 0; fm < 4; ++fm)
#pragma unroll
      for (int fn = 0; fn < 4; ++fn)
        acc[fm][fn] = __builtin_amdgcn_mfma_f32_16x16x32_bf16(af[fm], bfr[fn], acc[fm][fn], 0, 0, 0);
    __syncthreads();
  }
  float bv[4];
#pragma unroll
  for (int fn = 0; fn < 4; ++fn)
    bv[fn] = bias ? bias[n0 + wn * 64 + fn * 16 + r16] : 0.f;
#pragma unroll
  for (int fm = 0; fm < 4; ++fm)
#pragma unroll
    for (int fn = 0; fn < 4; ++fn)
#pragma unroll
      for (int rr = 0; rr < 4; ++rr) {
        float vv = acc[fm][fn][rr] * scale + bv[fn];
        size_t off = (size_t)(m0 + wm * 64 + fm * 16 + g * 4 + rr) * 1024 +
                     n0 + wn * 64 + fn * 16 + r16;
        if (OUTBF) ((ushort_t*)Cv)[off] = (ushort_t)f2b(vv);
        else       ((float*)Cv)[off] = vv;
      }
}

// ---------------------------------------------------------------------------
// Batched projection GEMM: blockIdx.z selects {q,k,v,pe}.
// ---------------------------------------------------------------------------
__global__ __launch_bounds__(256) void gemm4_kernel(
    const ushort_t* __restrict__ a0, const ushort_t* __restrict__ a1,
    const ushort_t* __restrict__ a2, const ushort_t* __restrict__ a3,
    const ushort_t* __restrict__ w0, const ushort_t* __restrict__ w1,
    const ushort_t* __restrict__ w2, const ushort_t* __restrict__ w3,
    const float* __restrict__ kb, const float* __restrict__ vb,
    ushort_t* __restrict__ c0, ushort_t* __restrict__ c1,
    ushort_t* __restrict__ c2, ushort_t* __restrict__ c3) {
  const int z = blockIdx.z;
  const ushort_t* A  = z == 0 ? a0 : z == 1 ? a1 : z == 2 ? a2 : a3;
  const ushort_t* Wt = z == 0 ? w0 : z == 1 ? w1 : z == 2 ? w2 : w3;
  const float* bias  = z == 1 ? kb : z == 2 ? vb : (const float*)nullptr;
  ushort_t* C        = z == 0 ? c0 : z == 1 ? c1 : z == 2 ? c2 : c3;
  const float scale  = z == 0 ? NORM_F : 1.0f;

  __shared__ short A_lds[128][40];
  __shared__ short B_lds[128][40];
  const int tid = threadIdx.x;
  const int wave = tid >> 6, lane = tid & 63;
  const int r16 = lane & 15, g = lane >> 4;
  const int wm = wave >> 1, wn = wave & 1;
  const int m0 = blockIdx.x * 128, n0 = blockIdx.y * 128;
  const int sr = tid >> 2, sseg = (tid & 3) * 8;
  f32x4 acc[4][4] = {};
  uint4 ra0 = *(const uint4*)(A + (size_t)(m0 + sr) * 1024 + sseg);
  uint4 ra1 = *(const uint4*)(A + (size_t)(m0 + 64 + sr) * 1024 + sseg);
  uint4 rb0 = *(const uint4*)(Wt + (size_t)(n0 + sr) * 1024 + sseg);
  uint4 rb1 = *(const uint4*)(Wt + (size_t)(n0 + 64 + sr) * 1024 + sseg);
  for (int k0 = 0; k0 < 1024; k0 += 32) {
    *(uint4*)&A_lds[sr][sseg] = ra0;
    *(uint4*)&A_lds[64 + sr][sseg] = ra1;
    *(uint4*)&B_lds[sr][sseg] = rb0;
    *(uint4*)&B_lds[64 + sr][sseg] = rb1;
    __syncthreads();
    if (k0 + 32 < 1024) {
      ra0 = *(const uint4*)(A + (size_t)(m0 + sr) * 1024 + k0 + 32 + sseg);
      ra1 = *(const uint4*)(A + (size_t)(m0 + 64 + sr) * 1024 + k0 + 32 + sseg);
      rb0 = *(const uint4*)(Wt + (size_t)(n0 + sr) * 1024 + k0 + 32 + sseg);
      rb1 = *(const uint4*)(Wt + (size_t)(n0 + 64 + sr) * 1024 + k0 + 32 + sseg);
    }
    bf16x8 af[4], bfr[4];
#pragma unroll
    for (int fm = 0; fm < 4; ++fm)
      af[fm] = *(const bf16x8*)&A_lds[wm * 64 + fm * 16 + r16][g * 8];
#pragma unroll
    for (int fn = 0; fn < 4; ++fn)
      bfr[fn] = *(const bf16x8*)&B_lds[wn * 64 + fn * 16 + r16][g * 8];
#pragma unroll
    for (int fm = 0; fm < 4; ++fm)
#pragma unroll
      for (int fn = 0; fn < 4; ++fn)
        acc[fm][fn] = __builtin_amdgcn_mfma_f32_16x16x32_bf16(af[fm], bfr[fn], acc[fm][fn], 0, 0, 0);
    __syncthreads();
  }
  float bv[4];
#pragma unroll
  for (int fn = 0; fn < 4; ++fn)
    bv[fn] = bias ? bias[n0 + wn * 64 + fn * 16 + r16] : 0.f;
#pragma unroll
  for (int fm = 0; fm < 4; ++fm)
#pragma unroll
    for (int fn = 0; fn < 4; ++fn)
#pragma unroll
      for (int rr = 0; rr < 4; ++rr) {
        float vv = acc[fm][fn][rr] * scale + bv[fn];
        size_t off = (size_t)(m0 + wm * 64 + fm * 16 + g * 4 + rr) * 1024 +
                     n0 + wn * 64 + fn * 16 + r16;
        C[off] = (ushort_t)f2b(vv);
      }
}

// ---------------------------------------------------------------------------
// qprep: qwb = qh + rwb*N, qrb = qh + rrb*N (bf16); sbp = seg projections.
// ---------------------------------------------------------------------------
__global__ __launch_bounds__(256) void qprep_kernel(
    const ushort_t* __restrict__ qh, const float* __restrict__ rwb,
    const float* __restrict__ rrb, const float* __restrict__ rsb,
    const float* __restrict__ sem, ushort_t* __restrict__ qwb,
    ushort_t* __restrict__ qrb, float2* __restrict__ sbp) {
  const int tid = threadIdx.x;
  const int w = tid >> 6, lane = tid & 63;
  const int c0 = lane * 16;
  float rwbN[16], rrbN[16], rsbN[16], s0v[16], s1v[16];
#pragma unroll
  for (int u = 0; u < 16; u += 4) {
    *(float4*)&rwbN[u] = *(const float4*)(rwb + c0 + u);
    *(float4*)&rrbN[u] = *(const float4*)(rrb + c0 + u);
    *(float4*)&rsbN[u] = *(const float4*)(rsb + c0 + u);
    *(float4*)&s0v[u]  = *(const float4*)(sem + c0 + u);
    *(float4*)&s1v[u]  = *(const float4*)(sem + 1024 + c0 + u);
  }
#pragma unroll
  for (int u = 0; u < 16; ++u) { rwbN[u] *= NORM_F; rrbN[u] *= NORM_F; rsbN[u] *= NORM_F; }
  for (int r = 0; r < 16; ++r) {
    int row = blockIdx.x * 64 + w * 16 + r;
    const ushort_t* qp = qh + (size_t)row * 1024 + c0;
    union { uint4 v; ushort_t us[8]; } qa, qb;
    qa.v = *(const uint4*)qp; qb.v = *(const uint4*)(qp + 8);
    float p0 = 0.f, p1 = 0.f;
    union { ushort_t us[8]; uint4 v; } w0, w1, r0, r1;
#pragma unroll
    for (int u = 0; u < 16; ++u) {
      float qv = b2f(u < 8 ? qa.us[u] : qb.us[u - 8]);
      ushort_t cw = (ushort_t)f2b(qv + rwbN[u]);
      ushort_t cr = (ushort_t)f2b(qv + rrbN[u]);
      if (u < 8) { w0.us[u] = cw; r0.us[u] = cr; }
      else       { w1.us[u - 8] = cw; r1.us[u - 8] = cr; }
      float qs = qv + rsbN[u];
      p0 += qs * s0v[u]; p1 += qs * s1v[u];
    }
    *(uint4*)(qwb + (size_t)row * 1024 + c0)     = w0.v;
    *(uint4*)(qwb + (size_t)row * 1024 + c0 + 8) = w1.v;
    *(uint4*)(qrb + (size_t)row * 1024 + c0)     = r0.v;
    *(uint4*)(qrb + (size_t)row * 1024 + c0 + 8) = r1.v;
    p0 += __shfl_xor(p0, 1); p0 += __shfl_xor(p0, 2);
    p1 += __shfl_xor(p1, 1); p1 += __shfl_xor(p1, 2);
    if ((lane & 3) == 0) {
      int bI = row >> 11, iI = row & 2047, nI = lane >> 2;
      sbp[((size_t)bI * 16 + nI) * 2048 + iI] = make_float2(p0, p1);
    }
  }
}

// ---------------------------------------------------------------------------
// Fused causal relative attention v4 internals (byte-exact from R8 PASS) with
// a T1 XCD-aware 1D block swizzle: all 64 strip-blocks of one (n,b) group get
// linear IDs == g (mod 8) -> same XCD L2 caches that group's ~1MB K/V/R slice.
// ---------------------------------------------------------------------------
__global__ __launch_bounds__(256) void attn_kernel(
    const ushort_t* __restrict__ qwb, const ushort_t* __restrict__ qrb,
    const ushort_t* __restrict__ khb, const ushort_t* __restrict__ vhb,
    const ushort_t* __restrict__ rhb, const float2* __restrict__ sbp,
    const unsigned* __restrict__ segw, ushort_t* __restrict__ opart,
    float* __restrict__ ml) {
  __shared__ short Klds[64][64];
  __shared__ short Rlds[128][64];
  __shared__ short VsT[2][64][72];
  __shared__ short SP[4][1376];

  const int tid = threadIdx.x;
  const int w = tid >> 6, lane = tid & 63;
  const int r16 = lane & 15, g = lane >> 4;
  // XCD swizzle: lin -> (group g in [0,32), j in [0,64)); XCD = lin % 8 = g % 8
  const int lin = (int)blockIdx.x;
  const int grp = (lin & 7) + ((lin >> 9) << 3);
  const int j = (lin >> 3) & 63;
  const int x = 31 - (j >> 1);
  const int hx = j & 1;
  const int i0 = x * 64;
  const int nh = (x + 2) >> 1;
  const int tbeg = hx ? nh : 0;
  const int tend = hx ? (x + 1) : nh;
  const int n = grp & 15, b = grp >> 4;
  const int BNS = 65536;
  const int rowbase = (b * 16 + n) * 2048 + i0;

  if (tbeg >= tend) {  // empty half (only hx==1, x==0)
    const int il0 = w * 16 + g * 4;
#pragma unroll
    for (int rr = 0; rr < 4; ++rr) {
#pragma unroll
      for (int s = 0; s < 4; ++s)
        opart[(size_t)(BNS + rowbase + il0 + rr) * 64 + s * 16 + r16] = 0;
      if (r16 == 0) {
        ml[2 * BNS + rowbase + il0 + rr] = -1e30f;
        ml[3 * BNS + rowbase + il0 + rr] = 0.f;
      }
    }
    return;
  }

  short* SPw = &SP[w][0];
  const int srow = tid >> 3, sg8 = (tid & 7) * 8;

  // per-lane persistent state (q-row = r16 within this wave's 16 rows)
  const int qrow = i0 + w * 16 + r16;
  const ushort_t* qwp = qwb + (size_t)(b * S_LEN + qrow) * DMODEL + n * 64 + g * 8;
  const ushort_t* qrp = qrb + (size_t)(b * S_LEN + qrow) * DMODEL + n * 64 + g * 8;
  bf16x8 qw[2], qr[2];
  qw[0] = *(const bf16x8*)qwp;  qw[1] = *(const bf16x8*)(qwp + 32);
  qr[0] = *(const bf16x8*)qrp;  qr[1] = *(const bf16x8*)(qrp + 32);
  float2 sbv = sbp[((size_t)b * 16 + n) * 2048 + qrow];
  const float sb0 = sbv.x, sb1 = sbv.y;
  const int ai = (segw[b * 64 + (qrow >> 5)] >> (qrow & 31)) & 1;
  const int iw0 = i0 + w * 16;

  // prologue: stage tile tbeg (K, R swizzled; V scattered)
  {
    const int j0 = tbeg * 64;
    const int W0 = 2048 + j0 - i0 - 63;
#pragma unroll
    for (int it = 0; it < 2; ++it) {
      int qk = tid + it * 256, row = qk >> 3, cl = qk & 7;
      uint4 kv = *(const uint4*)(khb + (size_t)(b * S_LEN + j0 + row) * DMODEL + n * 64 + cl * 8);
      *(uint4*)&Klds[row][(cl ^ (row & 7)) * 8] = kv;
    }
#pragma unroll
    for (int it = 0; it < 4; ++it) {
      int qk = tid + it * 256, row = qk >> 3, cl = qk & 7;
      uint4 rv = *(const uint4*)(rhb + (size_t)(W0 + row) * DMODEL + n * 64 + cl * 8);
      *(uint4*)&Rlds[row][(cl ^ (row & 7)) * 8] = rv;
    }
#pragma unroll
    for (int it = 0; it < 2; ++it) {
      int jj = srow + it * 32;
      union { uint4 v; ushort_t us[8]; } vv;
      vv.v = *(const uint4*)(vhb + (size_t)(b * S_LEN + j0 + jj) * DMODEL + n * 64 + sg8);
#pragma unroll
      for (int e = 0; e < 8; ++e) {
        int hh = sg8 + e;
        VsT[0][hh][((jj >> 3) ^ ((hh >> 3) & 3)) * 8 + (jj & 7)] = (short)vv.us[e];
      }
    }
  }

  float m_r = -1e30f, l_r = 0.f;
  f32x4 o[4] = {};

  for (int t = tbeg; t < tend; ++t) {
    const int j0 = t * 64;
    const int tt = (t - tbeg) & 1;
    const bool hasn = (t + 1 < tend);
    __syncthreads();  // barrier A: staged data for tile t visible

    uint4 kpf[2], rpf[4], vpf[2];
    if (hasn) {
      const int j0n = j0 + 64;
      const int W0n = 2048 + j0n - i0 - 63;
#pragma unroll
      for (int it = 0; it < 2; ++it) {
        int qk = tid + it * 256, row = qk >> 3, cl = qk & 7;
        kpf[it] = *(const uint4*)(khb + (size_t)(b * S_LEN + j0n + row) * DMODEL + n * 64 + cl * 8);
      }
#pragma unroll
      for (int it = 0; it < 4; ++it) {
        int qk = tid + it * 256, row = qk >> 3, cl = qk & 7;
        rpf[it] = *(const uint4*)(rhb + (size_t)(W0n + row) * DMODEL + n * 64 + cl * 8);
      }
#pragma unroll
      for (int it = 0; it < 2; ++it)
        vpf[it] = *(const uint4*)(vhb + (size_t)(b * S_LEN + j0n + srow + it * 32) * DMODEL + n * 64 + sg8);
    }
    unsigned wlo = segw[b * 64 + (j0 >> 5)];
    unsigned whi = segw[b * 64 + (j0 >> 5) + 1];

    // content MFMAs: cf[s][rr] = S[j = j0+s*16+g*4+rr][i = qrow]
    f32x4 cf[4] = {};
#pragma unroll
    for (int s = 0; s < 4; ++s) {
      int row = s * 16 + r16;
      bf16x8 k0 = *(const bf16x8*)&Klds[row][(g ^ (row & 7)) * 8];
      bf16x8 k1 = *(const bf16x8*)&Klds[row][((4 + g) ^ (row & 7)) * 8];
      cf[s] = __builtin_amdgcn_mfma_f32_16x16x32_bf16(k0, qw[0], cf[s], 0, 0, 0);
      cf[s] = __builtin_amdgcn_mfma_f32_16x16x32_bf16(k1, qw[1], cf[s], 0, 0, 0);
    }
    // pos MFMAs -> PosL (stride-84 view): value at (u' = sp*16+g*4+rr, qcol r16)
#pragma unroll
    for (int sp = 0; sp < 5; ++sp) {
      int row = 48 - w * 16 + sp * 16 + r16;
      bf16x8 r0 = *(const bf16x8*)&Rlds[row][(g ^ (row & 7)) * 8];
      bf16x8 r1 = *(const bf16x8*)&Rlds[row][((4 + g) ^ (row & 7)) * 8];
      f32x4 pf = {};
      pf = __builtin_amdgcn_mfma_f32_16x16x32_bf16(r0, qr[0], pf, 0, 0, 0);
      pf = __builtin_amdgcn_mfma_f32_16x16x32_bf16(r1, qr[1], pf, 0, 0, 0);
      uint2 pw;
      pw.x = cvtpk(pf[0], pf[1]);
      pw.y = cvtpk(pf[2], pf[3]);
      *(uint2*)&SPw[r16 * 84 + sp * 16 + g * 4] = pw;
    }
    // softmax (lane-local row = qrow). Read pos first (wave-lockstep => no race
    // with the Ps writes below into the same SP buffer).
    ushort_t pu[4][4];
#pragma unroll
    for (int s = 0; s < 4; ++s)
#pragma unroll
      for (int rr = 0; rr < 4; ++rr)
        pu[s][rr] = (ushort_t)SPw[r16 * 84 + (15 - r16) + s * 16 + g * 4 + rr];
    float vals[4][4];
    float vmax = -1e30f;
    const bool diag = (t == x);
#pragma unroll
    for (int s = 0; s < 4; ++s) {
      unsigned word = (s < 2) ? wlo : whi;
#pragma unroll
      for (int rr = 0; rr < 4; ++rr) {
        int p = s * 16 + g * 4 + rr;
        int bitv = (word >> (p & 31)) & 1;
        float sv = cf[s][rr] + b2f(pu[s][rr]) + ((bitv == ai) ? sb1 : sb0);
        if (diag && (p > w * 16 + r16)) sv -= 1e6f;
        vals[s][rr] = sv;
        vmax = fmaxf(vmax, sv);
      }
    }
    vmax = fmaxf(vmax, __shfl_xor(vmax, 16));
    vmax = fmaxf(vmax, __shfl_xor(vmax, 32));
    float scl = 1.f;
    bool resc = !__all(vmax <= m_r + 8.f);
    if (resc) {
      float mnew = fmaxf(m_r, vmax);
      scl = __expf(m_r - mnew);
      m_r = mnew;
    }
    float pex[4][4];
    float psum = 0.f;
#pragma unroll
    for (int s = 0; s < 4; ++s)
#pragma unroll
      for (int rr = 0; rr < 4; ++rr) {
        pex[s][rr] = __expf(vals[s][rr] - m_r);
        psum += pex[s][rr];
      }
    l_r = l_r * scl + psum;
#pragma unroll
    for (int s = 0; s < 4; ++s) {
      uint2 pw;
      pw.x = cvtpk(pex[s][0], pex[s][1]);
      pw.y = cvtpk(pex[s][2], pex[s][3]);
      *(uint2*)&SPw[r16 * 72 + s * 16 + g * 4] = pw;
    }
    __syncthreads();  // barrier B: K/R/V(t) LDS reads complete

    if (hasn) {
#pragma unroll
      for (int it = 0; it < 2; ++it) {
        int qk = tid + it * 256, row = qk >> 3, cl = qk & 7;
        *(uint4*)&Klds[row][(cl ^ (row & 7)) * 8] = kpf[it];
      }
#pragma unroll
      for (int it = 0; it < 4; ++it) {
        int qk = tid + it * 256, row = qk >> 3, cl = qk & 7;
        *(uint4*)&Rlds[row][(cl ^ (row & 7)) * 8] = rpf[it];
      }
      const int dst = tt ^ 1;
#pragma unroll
      for (int it = 0; it < 2; ++it) {
        int jj = srow + it * 32;
        union { uint4 v; ushort_t us[8]; } vv; vv.v = vpf[it];
#pragma unroll
        for (int e = 0; e < 8; ++e) {
          int hh = sg8 + e;
          VsT[dst][hh][((jj >> 3) ^ ((hh >> 3) & 3)) * 8 + (jj & 7)] = (short)vv.us[e];
        }
      }
    }
    // PV: o[s][rr] at (i-row = g*4+rr, h = s*16+r16)
    if (resc) {
      float sclb[4];
#pragma unroll
      for (int rr = 0; rr < 4; ++rr) sclb[rr] = __shfl(scl, g * 4 + rr);
#pragma unroll
      for (int s = 0; s < 4; ++s)
#pragma unroll
        for (int rr = 0; rr < 4; ++rr) o[s][rr] *= sclb[rr];
    }
    bf16x8 pa0 = *(const bf16x8*)&SPw[r16 * 72 + g * 8];
    bf16x8 pa1 = *(const bf16x8*)&SPw[r16 * 72 + 32 + g * 8];
#pragma unroll
    for (int s = 0; s < 4; ++s) {
      int hh = s * 16 + r16;
      bf16x8 v0 = *(const bf16x8*)&VsT[tt][hh][(g ^ ((hh >> 3) & 3)) * 8];
      bf16x8 v1 = *(const bf16x8*)&VsT[tt][hh][((4 + g) ^ ((hh >> 3) & 3)) * 8];
      o[s] = __builtin_amdgcn_mfma_f32_16x16x32_bf16(pa0, v0, o[s], 0, 0, 0);
      o[s] = __builtin_amdgcn_mfma_f32_16x16x32_bf16(pa1, v1, o[s], 0, 0, 0);
    }
  }

  // epilogue
  float l_row = l_r;
  l_row += __shfl_xor(l_row, 16);
  l_row += __shfl_xor(l_row, 32);
  if (lane < 16) {
    ml[hx * 2 * BNS + rowbase + w * 16 + r16] = m_r;
    ml[(hx * 2 + 1) * BNS + rowbase + w * 16 + r16] = l_row;
  }
#pragma unroll
  for (int s = 0; s < 4; ++s)
#pragma unroll
    for (int rr = 0; rr < 4; ++rr) {
      const int il = w * 16 + g * 4 + rr;
      opart[(size_t)(hx * BNS + rowbase + il) * 64 + s * 16 + r16] = (ushort_t)f2b(o[s][rr]);
    }
}

// ---------------------------------------------------------------------------
// Merge the two j-halves: o = (o0*e^{m0-m} + o1*e^{m1-m}) / l
// ---------------------------------------------------------------------------
__global__ __launch_bounds__(256) void merge_kernel(
    const ushort_t* __restrict__ opart, const float* __restrict__ ml,
    ushort_t* __restrict__ av) {
  const int BNS = 65536;
  int row = blockIdx.x * 4 + (threadIdx.x >> 6);
  int lane = threadIdx.x & 63;
  float m0 = ml[row], l0 = ml[BNS + row];
  float m1 = ml[2 * BNS + row], l1 = ml[3 * BNS + row];
  float m = fmaxf(m0, m1);
  float a0 = __expf(m0 - m), a1 = __expf(m1 - m);
  float inv = 1.f / (l0 * a0 + l1 * a1);
  float o0 = b2f(opart[(size_t)row * 64 + lane]);
  float o1 = b2f(opart[(size_t)(BNS + row) * 64 + lane]);
  float ov = (o0 * a0 + o1 * a1) * inv;
  int bI = row >> 15, nI = (row >> 11) & 15, iI = row & 2047;
  av[(size_t)(bI * 2048 + iI) * 1024 + nI * 64 + lane] = (ushort_t)f2b(ov);
}

// ---------------------------------------------------------------------------
// Residual + LayerNorm
// ---------------------------------------------------------------------------
__global__ __launch_bounds__(256) void ln_kernel(
    const float* __restrict__ q, const float* __restrict__ ao,
    const float* __restrict__ ln_g, const float* __restrict__ ln_b,
    float* __restrict__ out) {
  int row = blockIdx.x;
  const float* xq = q + (size_t)row * 1024;
  const float* xa = ao + (size_t)row * 1024;
  float x[4], lsum = 0.f, lsq = 0.f;
#pragma unroll
  for (int e = 0; e < 4; ++e) {
    int d = threadIdx.x + e * 256;
    x[e] = xq[d] + xa[d];
    lsum += x[e]; lsq += x[e] * x[e];
  }
  for (int off = 1; off < 64; off <<= 1) {
    lsum += __shfl_xor(lsum, off);
    lsq += __shfl_xor(lsq, off);
  }
  __shared__ float red[8];
  int wv = threadIdx.x >> 6, ln = threadIdx.x & 63;
  if (ln == 0) { red[wv] = lsum; red[4 + wv] = lsq; }
  __syncthreads();
  lsum = red[0] + red[1] + red[2] + red[3];
  lsq = red[4] + red[5] + red[6] + red[7];
  float mu = lsum * (1.f / 1024.f);
  float var = lsq * (1.f / 1024.f) - mu * mu;
  float inv = rsqrtf(var + 1e-5f);
#pragma unroll
  for (int e = 0; e < 4; ++e) {
    int d = threadIdx.x + e * 256;
    out[(size_t)row * 1024 + d] = (x[e] - mu) * inv * ln_g[d] + ln_b[d];
  }
}

// ---------------------------------------------------------------------------
extern "C" void kernel_launch(void* const* d_in, const int* in_sizes, int n_in,
                              void* d_out, int out_size, void* d_ws, size_t ws_size,
                              hipStream_t stream) {
  const float* q   = (const float*)d_in[0];
  const float* k   = (const float*)d_in[1];
  const float* v   = (const float*)d_in[2];
  const float* pe  = (const float*)d_in[3];
  const void*  seg = d_in[4];
  const float* qW  = (const float*)d_in[6];
  const float* kW  = (const float*)d_in[7];
  const float* kb  = (const float*)d_in[8];
  const float* vW  = (const float*)d_in[9];
  const float* vb  = (const float*)d_in[10];
  const float* rwb = (const float*)d_in[11];
  const float* rrb = (const float*)d_in[12];
  const float* rK  = (const float*)d_in[13];
  const float* rsb = (const float*)d_in[14];
  const float* sem = (const float*)d_in[15];
  const float* pW  = (const float*)d_in[16];
  const float* pb  = (const float*)d_in[17];
  const float* lng = (const float*)d_in[18];
  const float* lnb = (const float*)d_in[19];
  float* out = (float*)d_out;

  const size_t MB = 1u << 20;
  char* W = (char*)d_ws;
  ushort_t* abq  = (ushort_t*)(W + 0 * MB);
  ushort_t* abk  = (ushort_t*)(W + 8 * MB);
  ushort_t* abv  = (ushort_t*)(W + 16 * MB);
  ushort_t* abpe = (ushort_t*)(W + 24 * MB);
  ushort_t* wtq  = (ushort_t*)(W + 32 * MB);
  ushort_t* wtk  = (ushort_t*)(W + 34 * MB);
  ushort_t* wtv  = (ushort_t*)(W + 36 * MB);
  ushort_t* wtr  = (ushort_t*)(W + 38 * MB);
  ushort_t* wtp  = (ushort_t*)(W + 40 * MB);
  ushort_t* qh   = (ushort_t*)(W + 42 * MB);
  ushort_t* kh   = (ushort_t*)(W + 50 * MB);
  ushort_t* vh   = (ushort_t*)(W + 58 * MB);
  ushort_t* rh   = (ushort_t*)(W + 66 * MB);
  unsigned* segw = (unsigned*)(W + 74 * MB);
  float2*   sbp  = (float2*)(W + 74 * MB + 65536);
  float*    ml   = (float*)(W + 75 * MB);
  // post-GEMM-phase overlays (sources are dead by the time these are written)
  ushort_t* qwb   = (ushort_t*)(W + 0 * MB);    // over abq
  ushort_t* qrb   = (ushort_t*)(W + 8 * MB);    // over abk
  ushort_t* opart = (ushort_t*)(W + 16 * MB);   // 16MB over abv+abpe
  ushort_t* av    = (ushort_t*)(W + 42 * MB);   // over qh (dead after qprep)
  float*    ao    = (float*)(W + 50 * MB);      // 16MB over kh+vh (dead post-attn)

  seg_extract_kernel<<<dim3(16), dim3(256), 0, stream>>>((const unsigned int*)seg, segw);
  conv4_kernel<<<dim3(2048, 4), dim3(256), 0, stream>>>(q, k, v, pe, abq, abk, abv, abpe);
  convT_kernel<<<dim3(16, 16, 5), dim3(256), 0, stream>>>(qW, kW, vW, rK, pW,
                                                          wtq, wtk, wtv, wtr, wtp);
  // batched projection GEMMs: one dispatch, 4 blocks/CU
  gemm4_kernel<<<dim3(32, 8, 4), dim3(256), 0, stream>>>(
      abq, abk, abv, abpe, wtq, wtk, wtv, wtr, kb, vb, qh, kh, vh, rh);

  qprep_kernel<<<dim3(64), dim3(256), 0, stream>>>(qh, rwb, rrb, rsb, sem, qwb, qrb, sbp);

  attn_kernel<<<dim3(2048), dim3(256), 0, stream>>>(qwb, qrb, kh, vh, rh,
                                                    sbp, segw, opart, ml);
  merge_kernel<<<dim3(16384), dim3(256), 0, stream>>>(opart, ml, av);

  gemm_bf_kernel<false><<<dim3(32, 8), dim3(256), 0, stream>>>(av, wtp, pb, ao, 1.0f);
  ln_kernel<<<dim3(4096), dim3(256), 0, stream>>>(q, ao, lng, lnb, out);
}

// Round 10
// 274.615 us; speedup vs baseline: 3.3247x; 1.0314x over previous
//
#include <hip/hip_runtime.h>
#include <hip/hip_bf16.h>

typedef __attribute__((ext_vector_type(8))) short bf16x8;
typedef __attribute__((ext_vector_type(4))) float f32x4;
typedef unsigned short ushort_t;

#define S_LEN 2048
#define DMODEL 1024
#define NORM_F 0.125f

__device__ __forceinline__ short f2b(float x) {
  union { float f; unsigned u; } c; c.f = x;
  unsigned r = (c.u + 0x7FFFu + ((c.u >> 16) & 1u)) >> 16;
  return (short)r;
}
__device__ __forceinline__ float b2f(ushort_t u) {
  union { unsigned u; float f; } c; c.u = ((unsigned)u) << 16; return c.f;
}
__device__ __forceinline__ unsigned cvtpk(float lo, float hi) {
  unsigned r;
  asm volatile("v_cvt_pk_bf16_f32 %0, %1, %2" : "=v"(r) : "v"(lo), "v"(hi));
  return r;
}

// ---------------------------------------------------------------------------
// Segment bits, packed: segw[b*64 + (i>>5)] bit (i&31) = seg id of (b, i).
// ---------------------------------------------------------------------------
__global__ void seg_extract_kernel(const unsigned int* __restrict__ seg_raw,
                                   unsigned* __restrict__ segw) {
  __shared__ int bad_int, bad_flt;
  int tid = threadIdx.x;
  if (tid == 0) { bad_int = 0; bad_flt = 0; }
  __syncthreads();
  for (int i = tid; i < 2048; i += 256) {
    unsigned v = seg_raw[i];
    if (v > 1u) atomicOr(&bad_int, 1);
    if (v != 0u && v != 0x3F800000u) atomicOr(&bad_flt, 1);
  }
  __syncthreads();
  int mode = bad_int ? (bad_flt ? 2 : 1) : 0;
  const unsigned char* u8 = (const unsigned char*)seg_raw;
  int P = blockIdx.x * 256 + tid;       // [0, 4096)
  int b = P >> 11, i = P & 2047;
  size_t off = (size_t)b * S_LEN * S_LEN + i;
  int bit;
  if (mode == 0)      bit = (int)(seg_raw[off] & 1u);
  else if (mode == 1) bit = (seg_raw[off] != 0u) ? 1 : 0;
  else                bit = (int)(u8[off] & 1u);
  unsigned long long mk = __ballot(bit);
  if ((tid & 63) == 0) {
    segw[P >> 5] = (unsigned)mk;
    segw[(P >> 5) + 1] = (unsigned)(mk >> 32);
  }
}

// ---------------------------------------------------------------------------
// fp32 -> bf16 plane conversion (4 planes of 4096x1024)
// ---------------------------------------------------------------------------
__global__ __launch_bounds__(256) void conv4_kernel(
    const float* __restrict__ s0, const float* __restrict__ s1,
    const float* __restrict__ s2, const float* __restrict__ s3,
    ushort_t* __restrict__ d0, ushort_t* __restrict__ d1,
    ushort_t* __restrict__ d2, ushort_t* __restrict__ d3) {
  int z = blockIdx.y;
  const float* src = z == 0 ? s0 : z == 1 ? s1 : z == 2 ? s2 : s3;
  ushort_t* dst = z == 0 ? d0 : z == 1 ? d1 : z == 2 ? d2 : d3;
  size_t base = ((size_t)blockIdx.x * 256 + threadIdx.x) * 8;
  float4 a = *(const float4*)(src + base);
  float4 b = *(const float4*)(src + base + 4);
  union { ushort_t us[8]; uint4 v; } o;
  o.us[0] = (ushort_t)f2b(a.x); o.us[1] = (ushort_t)f2b(a.y);
  o.us[2] = (ushort_t)f2b(a.z); o.us[3] = (ushort_t)f2b(a.w);
  o.us[4] = (ushort_t)f2b(b.x); o.us[5] = (ushort_t)f2b(b.y);
  o.us[6] = (ushort_t)f2b(b.z); o.us[7] = (ushort_t)f2b(b.w);
  *(uint4*)(dst + base) = o.v;
}

// ---------------------------------------------------------------------------
// Weight transpose+convert: W fp32 [1024 k][1024 n] -> Wt bf16 [n][k]
// ---------------------------------------------------------------------------
__global__ __launch_bounds__(256) void convT_kernel(
    const float* __restrict__ s0, const float* __restrict__ s1,
    const float* __restrict__ s2, const float* __restrict__ s3,
    const float* __restrict__ s4,
    ushort_t* __restrict__ d0, ushort_t* __restrict__ d1,
    ushort_t* __restrict__ d2, ushort_t* __restrict__ d3,
    ushort_t* __restrict__ d4) {
  int z = blockIdx.z;
  const float* src = z == 0 ? s0 : z == 1 ? s1 : z == 2 ? s2 : z == 3 ? s3 : s4;
  ushort_t* dst = z == 0 ? d0 : z == 1 ? d1 : z == 2 ? d2 : z == 3 ? d3 : d4;
  __shared__ float Tl[64][68];
  int tid = threadIdx.x;
  int k0 = blockIdx.x * 64, n0 = blockIdx.y * 64;
#pragma unroll
  for (int it = 0; it < 4; ++it) {
    int idx = tid + it * 256;
    int r = idx >> 4, c4 = (idx & 15) * 4;
    *(float4*)&Tl[r][c4] = *(const float4*)(src + (size_t)(k0 + r) * 1024 + n0 + c4);
  }
  __syncthreads();
#pragma unroll
  for (int it = 0; it < 2; ++it) {
    int idx = tid + it * 256;
    int nn = idx >> 3, kc = idx & 7;
    union { ushort_t us[8]; uint4 v; } o;
#pragma unroll
    for (int e = 0; e < 8; ++e) o.us[e] = (ushort_t)f2b(Tl[kc * 8 + e][nn]);
    *(uint4*)(dst + (size_t)(n0 + nn) * 1024 + k0 + kc * 8) = o.v;
  }
}

// ---------------------------------------------------------------------------
// Batched projection GEMM: blockIdx.z selects {q,k,v,pe}. 128x128 tile.
// ---------------------------------------------------------------------------
__global__ __launch_bounds__(256) void gemm4_kernel(
    const ushort_t* __restrict__ a0, const ushort_t* __restrict__ a1,
    const ushort_t* __restrict__ a2, const ushort_t* __restrict__ a3,
    const ushort_t* __restrict__ w0, const ushort_t* __restrict__ w1,
    const ushort_t* __restrict__ w2, const ushort_t* __restrict__ w3,
    const float* __restrict__ kb, const float* __restrict__ vb,
    ushort_t* __restrict__ c0, ushort_t* __restrict__ c1,
    ushort_t* __restrict__ c2, ushort_t* __restrict__ c3) {
  const int z = blockIdx.z;
  const ushort_t* A  = z == 0 ? a0 : z == 1 ? a1 : z == 2 ? a2 : a3;
  const ushort_t* Wt = z == 0 ? w0 : z == 1 ? w1 : z == 2 ? w2 : w3;
  const float* bias  = z == 1 ? kb : z == 2 ? vb : (const float*)nullptr;
  ushort_t* C        = z == 0 ? c0 : z == 1 ? c1 : z == 2 ? c2 : c3;
  const float scale  = z == 0 ? NORM_F : 1.0f;

  __shared__ short A_lds[128][40];
  __shared__ short B_lds[128][40];
  const int tid = threadIdx.x;
  const int wave = tid >> 6, lane = tid & 63;
  const int r16 = lane & 15, g = lane >> 4;
  const int wm = wave >> 1, wn = wave & 1;
  const int m0 = blockIdx.x * 128, n0 = blockIdx.y * 128;
  const int sr = tid >> 2, sseg = (tid & 3) * 8;
  f32x4 acc[4][4] = {};
  uint4 ra0 = *(const uint4*)(A + (size_t)(m0 + sr) * 1024 + sseg);
  uint4 ra1 = *(const uint4*)(A + (size_t)(m0 + 64 + sr) * 1024 + sseg);
  uint4 rb0 = *(const uint4*)(Wt + (size_t)(n0 + sr) * 1024 + sseg);
  uint4 rb1 = *(const uint4*)(Wt + (size_t)(n0 + 64 + sr) * 1024 + sseg);
  for (int k0 = 0; k0 < 1024; k0 += 32) {
    *(uint4*)&A_lds[sr][sseg] = ra0;
    *(uint4*)&A_lds[64 + sr][sseg] = ra1;
    *(uint4*)&B_lds[sr][sseg] = rb0;
    *(uint4*)&B_lds[64 + sr][sseg] = rb1;
    __syncthreads();
    if (k0 + 32 < 1024) {
      ra0 = *(const uint4*)(A + (size_t)(m0 + sr) * 1024 + k0 + 32 + sseg);
      ra1 = *(const uint4*)(A + (size_t)(m0 + 64 + sr) * 1024 + k0 + 32 + sseg);
      rb0 = *(const uint4*)(Wt + (size_t)(n0 + sr) * 1024 + k0 + 32 + sseg);
      rb1 = *(const uint4*)(Wt + (size_t)(n0 + 64 + sr) * 1024 + k0 + 32 + sseg);
    }
    bf16x8 af[4], bfr[4];
#pragma unroll
    for (int fm = 0; fm < 4; ++fm)
      af[fm] = *(const bf16x8*)&A_lds[wm * 64 + fm * 16 + r16][g * 8];
#pragma unroll
    for (int fn = 0; fn < 4; ++fn)
      bfr[fn] = *(const bf16x8*)&B_lds[wn * 64 + fn * 16 + r16][g * 8];
#pragma unroll
    for (int fm = 0; fm < 4; ++fm)
#pragma unroll
      for (int fn = 0; fn < 4; ++fn)
        acc[fm][fn] = __builtin_amdgcn_mfma_f32_16x16x32_bf16(af[fm], bfr[fn], acc[fm][fn], 0, 0, 0);
    __syncthreads();
  }
  float bv[4];
#pragma unroll
  for (int fn = 0; fn < 4; ++fn)
    bv[fn] = bias ? bias[n0 + wn * 64 + fn * 16 + r16] : 0.f;
#pragma unroll
  for (int fm = 0; fm < 4; ++fm)
#pragma unroll
    for (int fn = 0; fn < 4; ++fn)
#pragma unroll
      for (int rr = 0; rr < 4; ++rr) {
        float vv = acc[fm][fn][rr] * scale + bv[fn];
        size_t off = (size_t)(m0 + wm * 64 + fm * 16 + g * 4 + rr) * 1024 +
                     n0 + wn * 64 + fn * 16 + r16;
        C[off] = (ushort_t)f2b(vv);
      }
}

// ---------------------------------------------------------------------------
// Post-projection GEMM, 64x128 tile (512 blocks = 2/CU), fp32 out.
// 4 waves as 2x2 of 32x64 each.
// ---------------------------------------------------------------------------
__global__ __launch_bounds__(256) void gemm_post_kernel(
    const ushort_t* __restrict__ A, const ushort_t* __restrict__ Wt,
    const float* __restrict__ bias, float* __restrict__ C) {
  __shared__ short A_lds[64][40];
  __shared__ short B_lds[128][40];
  const int tid = threadIdx.x;
  const int wave = tid >> 6, lane = tid & 63;
  const int r16 = lane & 15, g = lane >> 4;
  const int wm = wave >> 1, wn = wave & 1;
  const int m0 = blockIdx.x * 64, n0 = blockIdx.y * 128;
  const int sr = tid >> 2, sseg = (tid & 3) * 8;
  f32x4 acc[2][4] = {};
  uint4 ra0 = *(const uint4*)(A + (size_t)(m0 + sr) * 1024 + sseg);
  uint4 rb0 = *(const uint4*)(Wt + (size_t)(n0 + sr) * 1024 + sseg);
  uint4 rb1 = *(const uint4*)(Wt + (size_t)(n0 + 64 + sr) * 1024 + sseg);
  for (int k0 = 0; k0 < 1024; k0 += 32) {
    *(uint4*)&A_lds[sr][sseg] = ra0;
    *(uint4*)&B_lds[sr][sseg] = rb0;
    *(uint4*)&B_lds[64 + sr][sseg] = rb1;
    __syncthreads();
    if (k0 + 32 < 1024) {
      ra0 = *(const uint4*)(A + (size_t)(m0 + sr) * 1024 + k0 + 32 + sseg);
      rb0 = *(const uint4*)(Wt + (size_t)(n0 + sr) * 1024 + k0 + 32 + sseg);
      rb1 = *(const uint4*)(Wt + (size_t)(n0 + 64 + sr) * 1024 + k0 + 32 + sseg);
    }
    bf16x8 af[2], bfr[4];
#pragma unroll
    for (int fm = 0; fm < 2; ++fm)
      af[fm] = *(const bf16x8*)&A_lds[wm * 32 + fm * 16 + r16][g * 8];
#pragma unroll
    for (int fn = 0; fn < 4; ++fn)
      bfr[fn] = *(const bf16x8*)&B_lds[wn * 64 + fn * 16 + r16][g * 8];
#pragma unroll
    for (int fm = 0; fm < 2; ++fm)
#pragma unroll
      for (int fn = 0; fn < 4; ++fn)
        acc[fm][fn] = __builtin_amdgcn_mfma_f32_16x16x32_bf16(af[fm], bfr[fn], acc[fm][fn], 0, 0, 0);
    __syncthreads();
  }
  float bv[4];
#pragma unroll
  for (int fn = 0; fn < 4; ++fn)
    bv[fn] = bias ? bias[n0 + wn * 64 + fn * 16 + r16] : 0.f;
#pragma unroll
  for (int fm = 0; fm < 2; ++fm)
#pragma unroll
    for (int fn = 0; fn < 4; ++fn)
#pragma unroll
      for (int rr = 0; rr < 4; ++rr) {
        size_t off = (size_t)(m0 + wm * 32 + fm * 16 + g * 4 + rr) * 1024 +
                     n0 + wn * 64 + fn * 16 + r16;
        C[off] = acc[fm][fn][rr] + bv[fn];
      }
}

// ---------------------------------------------------------------------------
// qprep: qwb = qh + rwb*N, qrb = qh + rrb*N (bf16); sbp = seg projections.
// 256 blocks x 1 wave; each does 16 rows.
// ---------------------------------------------------------------------------
__global__ __launch_bounds__(64) void qprep_kernel(
    const ushort_t* __restrict__ qh, const float* __restrict__ rwb,
    const float* __restrict__ rrb, const float* __restrict__ rsb,
    const float* __restrict__ sem, ushort_t* __restrict__ qwb,
    ushort_t* __restrict__ qrb, float2* __restrict__ sbp) {
  const int lane = threadIdx.x & 63;
  const int c0 = lane * 16;
  float rwbN[16], rrbN[16], rsbN[16], s0v[16], s1v[16];
#pragma unroll
  for (int u = 0; u < 16; u += 4) {
    *(float4*)&rwbN[u] = *(const float4*)(rwb + c0 + u);
    *(float4*)&rrbN[u] = *(const float4*)(rrb + c0 + u);
    *(float4*)&rsbN[u] = *(const float4*)(rsb + c0 + u);
    *(float4*)&s0v[u]  = *(const float4*)(sem + c0 + u);
    *(float4*)&s1v[u]  = *(const float4*)(sem + 1024 + c0 + u);
  }
#pragma unroll
  for (int u = 0; u < 16; ++u) { rwbN[u] *= NORM_F; rrbN[u] *= NORM_F; rsbN[u] *= NORM_F; }
  for (int r = 0; r < 16; ++r) {
    int row = blockIdx.x * 16 + r;
    const ushort_t* qp = qh + (size_t)row * 1024 + c0;
    union { uint4 v; ushort_t us[8]; } qa, qb;
    qa.v = *(const uint4*)qp; qb.v = *(const uint4*)(qp + 8);
    float p0 = 0.f, p1 = 0.f;
    union { ushort_t us[8]; uint4 v; } w0, w1, r0, r1;
#pragma unroll
    for (int u = 0; u < 16; ++u) {
      float qv = b2f(u < 8 ? qa.us[u] : qb.us[u - 8]);
      ushort_t cw = (ushort_t)f2b(qv + rwbN[u]);
      ushort_t cr = (ushort_t)f2b(qv + rrbN[u]);
      if (u < 8) { w0.us[u] = cw; r0.us[u] = cr; }
      else       { w1.us[u - 8] = cw; r1.us[u - 8] = cr; }
      float qs = qv + rsbN[u];
      p0 += qs * s0v[u]; p1 += qs * s1v[u];
    }
    *(uint4*)(qwb + (size_t)row * 1024 + c0)     = w0.v;
    *(uint4*)(qwb + (size_t)row * 1024 + c0 + 8) = w1.v;
    *(uint4*)(qrb + (size_t)row * 1024 + c0)     = r0.v;
    *(uint4*)(qrb + (size_t)row * 1024 + c0 + 8) = r1.v;
    p0 += __shfl_xor(p0, 1); p0 += __shfl_xor(p0, 2);
    p1 += __shfl_xor(p1, 1); p1 += __shfl_xor(p1, 2);
    if ((lane & 3) == 0) {
      int bI = row >> 11, iI = row & 2047, nI = lane >> 2;
      sbp[((size_t)bI * 16 + nI) * 2048 + iI] = make_float2(p0, p1);
    }
  }
}

// ---------------------------------------------------------------------------
// Fused causal relative attention (R9 internals) with: full 3-bit V-swizzle
// XOR (conflict-free scatter writes) and s_setprio around MFMA clusters.
// ---------------------------------------------------------------------------
__global__ __launch_bounds__(256) void attn_kernel(
    const ushort_t* __restrict__ qwb, const ushort_t* __restrict__ qrb,
    const ushort_t* __restrict__ khb, const ushort_t* __restrict__ vhb,
    const ushort_t* __restrict__ rhb, const float2* __restrict__ sbp,
    const unsigned* __restrict__ segw, ushort_t* __restrict__ opart,
    float* __restrict__ ml) {
  __shared__ short Klds[64][64];
  __shared__ short Rlds[128][64];
  __shared__ short VsT[2][64][72];
  __shared__ short SP[4][1376];

  const int tid = threadIdx.x;
  const int w = tid >> 6, lane = tid & 63;
  const int r16 = lane & 15, g = lane >> 4;
  // XCD swizzle: lin -> (group g in [0,32), j in [0,64)); XCD = lin % 8 = g % 8
  const int lin = (int)blockIdx.x;
  const int grp = (lin & 7) + ((lin >> 9) << 3);
  const int j = (lin >> 3) & 63;
  const int x = 31 - (j >> 1);
  const int hx = j & 1;
  const int i0 = x * 64;
  const int nh = (x + 2) >> 1;
  const int tbeg = hx ? nh : 0;
  const int tend = hx ? (x + 1) : nh;
  const int n = grp & 15, b = grp >> 4;
  const int BNS = 65536;
  const int rowbase = (b * 16 + n) * 2048 + i0;

  if (tbeg >= tend) {  // empty half (only hx==1, x==0)
    const int il0 = w * 16 + g * 4;
#pragma unroll
    for (int rr = 0; rr < 4; ++rr) {
#pragma unroll
      for (int s = 0; s < 4; ++s)
        opart[(size_t)(BNS + rowbase + il0 + rr) * 64 + s * 16 + r16] = 0;
      if (r16 == 0) {
        ml[2 * BNS + rowbase + il0 + rr] = -1e30f;
        ml[3 * BNS + rowbase + il0 + rr] = 0.f;
      }
    }
    return;
  }

  short* SPw = &SP[w][0];
  const int srow = tid >> 3, sg8 = (tid & 7) * 8;

  // per-lane persistent state (q-row = r16 within this wave's 16 rows)
  const int qrow = i0 + w * 16 + r16;
  const ushort_t* qwp = qwb + (size_t)(b * S_LEN + qrow) * DMODEL + n * 64 + g * 8;
  const ushort_t* qrp = qrb + (size_t)(b * S_LEN + qrow) * DMODEL + n * 64 + g * 8;
  bf16x8 qw[2], qr[2];
  qw[0] = *(const bf16x8*)qwp;  qw[1] = *(const bf16x8*)(qwp + 32);
  qr[0] = *(const bf16x8*)qrp;  qr[1] = *(const bf16x8*)(qrp + 32);
  float2 sbv = sbp[((size_t)b * 16 + n) * 2048 + qrow];
  const float sb0 = sbv.x, sb1 = sbv.y;
  const int ai = (segw[b * 64 + (qrow >> 5)] >> (qrow & 31)) & 1;
  const int iw0 = i0 + w * 16;

  // prologue: stage tile tbeg (K, R swizzled; V scattered, 3-bit chunk XOR)
  {
    const int j0 = tbeg * 64;
    const int W0 = 2048 + j0 - i0 - 63;
#pragma unroll
    for (int it = 0; it < 2; ++it) {
      int qk = tid + it * 256, row = qk >> 3, cl = qk & 7;
      uint4 kv = *(const uint4*)(khb + (size_t)(b * S_LEN + j0 + row) * DMODEL + n * 64 + cl * 8);
      *(uint4*)&Klds[row][(cl ^ (row & 7)) * 8] = kv;
    }
#pragma unroll
    for (int it = 0; it < 4; ++it) {
      int qk = tid + it * 256, row = qk >> 3, cl = qk & 7;
      uint4 rv = *(const uint4*)(rhb + (size_t)(W0 + row) * DMODEL + n * 64 + cl * 8);
      *(uint4*)&Rlds[row][(cl ^ (row & 7)) * 8] = rv;
    }
#pragma unroll
    for (int it = 0; it < 2; ++it) {
      int jj = srow + it * 32;
      union { uint4 v; ushort_t us[8]; } vv;
      vv.v = *(const uint4*)(vhb + (size_t)(b * S_LEN + j0 + jj) * DMODEL + n * 64 + sg8);
#pragma unroll
      for (int e = 0; e < 8; ++e) {
        int hh = sg8 + e;
        VsT[0][hh][((jj >> 3) ^ (hh >> 3)) * 8 + (jj & 7)] = (short)vv.us[e];
      }
    }
  }

  float m_r = -1e30f, l_r = 0.f;
  f32x4 o[4] = {};

  for (int t = tbeg; t < tend; ++t) {
    const int j0 = t * 64;
    const int tt = (t - tbeg) & 1;
    const bool hasn = (t + 1 < tend);
    __syncthreads();  // barrier A: staged data for tile t visible

    uint4 kpf[2], rpf[4], vpf[2];
    if (hasn) {
      const int j0n = j0 + 64;
      const int W0n = 2048 + j0n - i0 - 63;
#pragma unroll
      for (int it = 0; it < 2; ++it) {
        int qk = tid + it * 256, row = qk >> 3, cl = qk & 7;
        kpf[it] = *(const uint4*)(khb + (size_t)(b * S_LEN + j0n + row) * DMODEL + n * 64 + cl * 8);
      }
#pragma unroll
      for (int it = 0; it < 4; ++it) {
        int qk = tid + it * 256, row = qk >> 3, cl = qk & 7;
        rpf[it] = *(const uint4*)(rhb + (size_t)(W0n + row) * DMODEL + n * 64 + cl * 8);
      }
#pragma unroll
      for (int it = 0; it < 2; ++it)
        vpf[it] = *(const uint4*)(vhb + (size_t)(b * S_LEN + j0n + srow + it * 32) * DMODEL + n * 64 + sg8);
    }
    unsigned wlo = segw[b * 64 + (j0 >> 5)];
    unsigned whi = segw[b * 64 + (j0 >> 5) + 1];

    // content MFMAs: cf[s][rr] = S[j = j0+s*16+g*4+rr][i = qrow]
    __builtin_amdgcn_s_setprio(1);
    f32x4 cf[4] = {};
#pragma unroll
    for (int s = 0; s < 4; ++s) {
      int row = s * 16 + r16;
      bf16x8 k0 = *(const bf16x8*)&Klds[row][(g ^ (row & 7)) * 8];
      bf16x8 k1 = *(const bf16x8*)&Klds[row][((4 + g) ^ (row & 7)) * 8];
      cf[s] = __builtin_amdgcn_mfma_f32_16x16x32_bf16(k0, qw[0], cf[s], 0, 0, 0);
      cf[s] = __builtin_amdgcn_mfma_f32_16x16x32_bf16(k1, qw[1], cf[s], 0, 0, 0);
    }
    // pos MFMAs -> PosL (stride-84 view): value at (u' = sp*16+g*4+rr, qcol r16)
#pragma unroll
    for (int sp = 0; sp < 5; ++sp) {
      int row = 48 - w * 16 + sp * 16 + r16;
      bf16x8 r0 = *(const bf16x8*)&Rlds[row][(g ^ (row & 7)) * 8];
      bf16x8 r1 = *(const bf16x8*)&Rlds[row][((4 + g) ^ (row & 7)) * 8];
      f32x4 pf = {};
      pf = __builtin_amdgcn_mfma_f32_16x16x32_bf16(r0, qr[0], pf, 0, 0, 0);
      pf = __builtin_amdgcn_mfma_f32_16x16x32_bf16(r1, qr[1], pf, 0, 0, 0);
      uint2 pw;
      pw.x = cvtpk(pf[0], pf[1]);
      pw.y = cvtpk(pf[2], pf[3]);
      *(uint2*)&SPw[r16 * 84 + sp * 16 + g * 4] = pw;
    }
    __builtin_amdgcn_s_setprio(0);
    // softmax (lane-local row = qrow). Read pos first (wave-lockstep => no race
    // with the Ps writes below into the same SP buffer).
    ushort_t pu[4][4];
#pragma unroll
    for (int s = 0; s < 4; ++s)
#pragma unroll
      for (int rr = 0; rr < 4; ++rr)
        pu[s][rr] = (ushort_t)SPw[r16 * 84 + (15 - r16) + s * 16 + g * 4 + rr];
    float vals[4][4];
    float vmax = -1e30f;
    const bool diag = (t == x);
#pragma unroll
    for (int s = 0; s < 4; ++s) {
      unsigned word = (s < 2) ? wlo : whi;
#pragma unroll
      for (int rr = 0; rr < 4; ++rr) {
        int p = s * 16 + g * 4 + rr;
        int bitv = (word >> (p & 31)) & 1;
        float sv = cf[s][rr] + b2f(pu[s][rr]) + ((bitv == ai) ? sb1 : sb0);
        if (diag && (p > w * 16 + r16)) sv -= 1e6f;
        vals[s][rr] = sv;
        vmax = fmaxf(vmax, sv);
      }
    }
    vmax = fmaxf(vmax, __shfl_xor(vmax, 16));
    vmax = fmaxf(vmax, __shfl_xor(vmax, 32));
    float scl = 1.f;
    bool resc = !__all(vmax <= m_r + 8.f);
    if (resc) {
      float mnew = fmaxf(m_r, vmax);
      scl = __expf(m_r - mnew);
      m_r = mnew;
    }
    float pex[4][4];
    float psum = 0.f;
#pragma unroll
    for (int s = 0; s < 4; ++s)
#pragma unroll
      for (int rr = 0; rr < 4; ++rr) {
        pex[s][rr] = __expf(vals[s][rr] - m_r);
        psum += pex[s][rr];
      }
    l_r = l_r * scl + psum;
#pragma unroll
    for (int s = 0; s < 4; ++s) {
      uint2 pw;
      pw.x = cvtpk(pex[s][0], pex[s][1]);
      pw.y = cvtpk(pex[s][2], pex[s][3]);
      *(uint2*)&SPw[r16 * 72 + s * 16 + g * 4] = pw;
    }
    __syncthreads();  // barrier B: K/R/V(t) LDS reads complete

    if (hasn) {
#pragma unroll
      for (int it = 0; it < 2; ++it) {
        int qk = tid + it * 256, row = qk >> 3, cl = qk & 7;
        *(uint4*)&Klds[row][(cl ^ (row & 7)) * 8] = kpf[it];
      }
#pragma unroll
      for (int it = 0; it < 4; ++it) {
        int qk = tid + it * 256, row = qk >> 3, cl = qk & 7;
        *(uint4*)&Rlds[row][(cl ^ (row & 7)) * 8] = rpf[it];
      }
      const int dst = tt ^ 1;
#pragma unroll
      for (int it = 0; it < 2; ++it) {
        int jj = srow + it * 32;
        union { uint4 v; ushort_t us[8]; } vv; vv.v = vpf[it];
#pragma unroll
        for (int e = 0; e < 8; ++e) {
          int hh = sg8 + e;
          VsT[dst][hh][((jj >> 3) ^ (hh >> 3)) * 8 + (jj & 7)] = (short)vv.us[e];
        }
      }
    }
    // PV: o[s][rr] at (i-row = g*4+rr, h = s*16+r16)
    if (resc) {
      float sclb[4];
#pragma unroll
      for (int rr = 0; rr < 4; ++rr) sclb[rr] = __shfl(scl, g * 4 + rr);
#pragma unroll
      for (int s = 0; s < 4; ++s)
#pragma unroll
        for (int rr = 0; rr < 4; ++rr) o[s][rr] *= sclb[rr];
    }
    bf16x8 pa0 = *(const bf16x8*)&SPw[r16 * 72 + g * 8];
    bf16x8 pa1 = *(const bf16x8*)&SPw[r16 * 72 + 32 + g * 8];
    __builtin_amdgcn_s_setprio(1);
#pragma unroll
    for (int s = 0; s < 4; ++s) {
      int hh = s * 16 + r16;
      bf16x8 v0 = *(const bf16x8*)&VsT[tt][hh][(g ^ (hh >> 3)) * 8];
      bf16x8 v1 = *(const bf16x8*)&VsT[tt][hh][((4 + g) ^ (hh >> 3)) * 8];
      o[s] = __builtin_amdgcn_mfma_f32_16x16x32_bf16(pa0, v0, o[s], 0, 0, 0);
      o[s] = __builtin_amdgcn_mfma_f32_16x16x32_bf16(pa1, v1, o[s], 0, 0, 0);
    }
    __builtin_amdgcn_s_setprio(0);
  }

  // epilogue
  float l_row = l_r;
  l_row += __shfl_xor(l_row, 16);
  l_row += __shfl_xor(l_row, 32);
  if (lane < 16) {
    ml[hx * 2 * BNS + rowbase + w * 16 + r16] = m_r;
    ml[(hx * 2 + 1) * BNS + rowbase + w * 16 + r16] = l_row;
  }
#pragma unroll
  for (int s = 0; s < 4; ++s)
#pragma unroll
    for (int rr = 0; rr < 4; ++rr) {
      const int il = w * 16 + g * 4 + rr;
      opart[(size_t)(hx * BNS + rowbase + il) * 64 + s * 16 + r16] = (ushort_t)f2b(o[s][rr]);
    }
}

// ---------------------------------------------------------------------------
// Merge the two j-halves: o = (o0*e^{m0-m} + o1*e^{m1-m}) / l
// ---------------------------------------------------------------------------
__global__ __launch_bounds__(256) void merge_kernel(
    const ushort_t* __restrict__ opart, const float* __restrict__ ml,
    ushort_t* __restrict__ av) {
  const int BNS = 65536;
  int row = blockIdx.x * 4 + (threadIdx.x >> 6);
  int lane = threadIdx.x & 63;
  float m0 = ml[row], l0 = ml[BNS + row];
  float m1 = ml[2 * BNS + row], l1 = ml[3 * BNS + row];
  float m = fmaxf(m0, m1);
  float a0 = __expf(m0 - m), a1 = __expf(m1 - m);
  float inv = 1.f / (l0 * a0 + l1 * a1);
  float o0 = b2f(opart[(size_t)row * 64 + lane]);
  float o1 = b2f(opart[(size_t)(BNS + row) * 64 + lane]);
  float ov = (o0 * a0 + o1 * a1) * inv;
  int bI = row >> 15, nI = (row >> 11) & 15, iI = row & 2047;
  av[(size_t)(bI * 2048 + iI) * 1024 + nI * 64 + lane] = (ushort_t)f2b(ov);
}

// ---------------------------------------------------------------------------
// Residual + LayerNorm
// ---------------------------------------------------------------------------
__global__ __launch_bounds__(256) void ln_kernel(
    const float* __restrict__ q, const float* __restrict__ ao,
    const float* __restrict__ ln_g, const float* __restrict__ ln_b,
    float* __restrict__ out) {
  int row = blockIdx.x;
  const float* xq = q + (size_t)row * 1024;
  const float* xa = ao + (size_t)row * 1024;
  float x[4], lsum = 0.f, lsq = 0.f;
#pragma unroll
  for (int e = 0; e < 4; ++e) {
    int d = threadIdx.x + e * 256;
    x[e] = xq[d] + xa[d];
    lsum += x[e]; lsq += x[e] * x[e];
  }
  for (int off = 1; off < 64; off <<= 1) {
    lsum += __shfl_xor(lsum, off);
    lsq += __shfl_xor(lsq, off);
  }
  __shared__ float red[8];
  int wv = threadIdx.x >> 6, ln = threadIdx.x & 63;
  if (ln == 0) { red[wv] = lsum; red[4 + wv] = lsq; }
  __syncthreads();
  lsum = red[0] + red[1] + red[2] + red[3];
  lsq = red[4] + red[5] + red[6] + red[7];
  float mu = lsum * (1.f / 1024.f);
  float var = lsq * (1.f / 1024.f) - mu * mu;
  float inv = rsqrtf(var + 1e-5f);
#pragma unroll
  for (int e = 0; e < 4; ++e) {
    int d = threadIdx.x + e * 256;
    out[(size_t)row * 1024 + d] = (x[e] - mu) * inv * ln_g[d] + ln_b[d];
  }
}

// ---------------------------------------------------------------------------
extern "C" void kernel_launch(void* const* d_in, const int* in_sizes, int n_in,
                              void* d_out, int out_size, void* d_ws, size_t ws_size,
                              hipStream_t stream) {
  const float* q   = (const float*)d_in[0];
  const float* k   = (const float*)d_in[1];
  const float* v   = (const float*)d_in[2];
  const float* pe  = (const float*)d_in[3];
  const void*  seg = d_in[4];
  const float* qW  = (const float*)d_in[6];
  const float* kW  = (const float*)d_in[7];
  const float* kb  = (const float*)d_in[8];
  const float* vW  = (const float*)d_in[9];
  const float* vb  = (const float*)d_in[10];
  const float* rwb = (const float*)d_in[11];
  const float* rrb = (const float*)d_in[12];
  const float* rK  = (const float*)d_in[13];
  const float* rsb = (const float*)d_in[14];
  const float* sem = (const float*)d_in[15];
  const float* pW  = (const float*)d_in[16];
  const float* pb  = (const float*)d_in[17];
  const float* lng = (const float*)d_in[18];
  const float* lnb = (const float*)d_in[19];
  float* out = (float*)d_out;

  const size_t MB = 1u << 20;
  char* W = (char*)d_ws;
  ushort_t* abq  = (ushort_t*)(W + 0 * MB);
  ushort_t* abk  = (ushort_t*)(W + 8 * MB);
  ushort_t* abv  = (ushort_t*)(W + 16 * MB);
  ushort_t* abpe = (ushort_t*)(W + 24 * MB);
  ushort_t* wtq  = (ushort_t*)(W + 32 * MB);
  ushort_t* wtk  = (ushort_t*)(W + 34 * MB);
  ushort_t* wtv  = (ushort_t*)(W + 36 * MB);
  ushort_t* wtr  = (ushort_t*)(W + 38 * MB);
  ushort_t* wtp  = (ushort_t*)(W + 40 * MB);
  ushort_t* qh   = (ushort_t*)(W + 42 * MB);
  ushort_t* kh   = (ushort_t*)(W + 50 * MB);
  ushort_t* vh   = (ushort_t*)(W + 58 * MB);
  ushort_t* rh   = (ushort_t*)(W + 66 * MB);
  unsigned* segw = (unsigned*)(W + 74 * MB);
  float2*   sbp  = (float2*)(W + 74 * MB + 65536);
  float*    ml   = (float*)(W + 75 * MB);
  // post-GEMM-phase overlays (sources are dead by the time these are written)
  ushort_t* qwb   = (ushort_t*)(W + 0 * MB);    // over abq
  ushort_t* qrb   = (ushort_t*)(W + 8 * MB);    // over abk
  ushort_t* opart = (ushort_t*)(W + 16 * MB);   // 16MB over abv+abpe
  ushort_t* av    = (ushort_t*)(W + 42 * MB);   // over qh (dead after qprep)
  float*    ao    = (float*)(W + 50 * MB);      // 16MB over kh+vh (dead post-attn)

  seg_extract_kernel<<<dim3(16), dim3(256), 0, stream>>>((const unsigned int*)seg, segw);
  conv4_kernel<<<dim3(2048, 4), dim3(256), 0, stream>>>(q, k, v, pe, abq, abk, abv, abpe);
  convT_kernel<<<dim3(16, 16, 5), dim3(256), 0, stream>>>(qW, kW, vW, rK, pW,
                                                          wtq, wtk, wtv, wtr, wtp);
  // batched projection GEMMs: one dispatch, 4 blocks/CU
  gemm4_kernel<<<dim3(32, 8, 4), dim3(256), 0, stream>>>(
      abq, abk, abv, abpe, wtq, wtk, wtv, wtr, kb, vb, qh, kh, vh, rh);

  qprep_kernel<<<dim3(256), dim3(64), 0, stream>>>(qh, rwb, rrb, rsb, sem, qwb, qrb, sbp);

  attn_kernel<<<dim3(2048), dim3(256), 0, stream>>>(qwb, qrb, kh, vh, rh,
                                                    sbp, segw, opart, ml);
  merge_kernel<<<dim3(16384), dim3(256), 0, stream>>>(opart, ml, av);

  gemm_post_kernel<<<dim3(64, 8), dim3(256), 0, stream>>>(av, wtp, pb, ao);
  ln_kernel<<<dim3(4096), dim3(256), 0, stream>>>(q, ao, lng, lnb, out);
}

// Round 11
// 252.428 us; speedup vs baseline: 3.6169x; 1.0879x over previous
//
#include <hip/hip_runtime.h>
#include <hip/hip_bf16.h>

typedef __attribute__((ext_vector_type(8))) short bf16x8;
typedef __attribute__((ext_vector_type(4))) float f32x4;
typedef unsigned short ushort_t;

#define S_LEN 2048
#define DMODEL 1024
#define NORM_F 0.125f

__device__ __forceinline__ short f2b(float x) {
  union { float f; unsigned u; } c; c.f = x;
  unsigned r = (c.u + 0x7FFFu + ((c.u >> 16) & 1u)) >> 16;
  return (short)r;
}
__device__ __forceinline__ float b2f(ushort_t u) {
  union { unsigned u; float f; } c; c.u = ((unsigned)u) << 16; return c.f;
}
__device__ __forceinline__ unsigned cvtpk(float lo, float hi) {
  unsigned r;
  asm volatile("v_cvt_pk_bf16_f32 %0, %1, %2" : "=v"(r) : "v"(lo), "v"(hi));
  return r;
}
__device__ __forceinline__ uint4 pack8(float4 a, float4 b) {
  union { ushort_t us[8]; uint4 v; } o;
  o.us[0] = (ushort_t)f2b(a.x); o.us[1] = (ushort_t)f2b(a.y);
  o.us[2] = (ushort_t)f2b(a.z); o.us[3] = (ushort_t)f2b(a.w);
  o.us[4] = (ushort_t)f2b(b.x); o.us[5] = (ushort_t)f2b(b.y);
  o.us[6] = (ushort_t)f2b(b.z); o.us[7] = (ushort_t)f2b(b.w);
  return o.v;
}

// ---------------------------------------------------------------------------
// Segment bits, packed: segw[b*64 + (i>>5)] bit (i&31) = seg id of (b, i).
// ---------------------------------------------------------------------------
__global__ void seg_extract_kernel(const unsigned int* __restrict__ seg_raw,
                                   unsigned* __restrict__ segw) {
  __shared__ int bad_int, bad_flt;
  int tid = threadIdx.x;
  if (tid == 0) { bad_int = 0; bad_flt = 0; }
  __syncthreads();
  for (int i = tid; i < 2048; i += 256) {
    unsigned v = seg_raw[i];
    if (v > 1u) atomicOr(&bad_int, 1);
    if (v != 0u && v != 0x3F800000u) atomicOr(&bad_flt, 1);
  }
  __syncthreads();
  int mode = bad_int ? (bad_flt ? 2 : 1) : 0;
  const unsigned char* u8 = (const unsigned char*)seg_raw;
  int P = blockIdx.x * 256 + tid;       // [0, 4096)
  int b = P >> 11, i = P & 2047;
  size_t off = (size_t)b * S_LEN * S_LEN + i;
  int bit;
  if (mode == 0)      bit = (int)(seg_raw[off] & 1u);
  else if (mode == 1) bit = (seg_raw[off] != 0u) ? 1 : 0;
  else                bit = (int)(u8[off] & 1u);
  unsigned long long mk = __ballot(bit);
  if ((tid & 63) == 0) {
    segw[P >> 5] = (unsigned)mk;
    segw[(P >> 5) + 1] = (unsigned)(mk >> 32);
  }
}

// ---------------------------------------------------------------------------
// Weight transpose+convert: W fp32 [1024 k][1024 n] -> Wt bf16 [n][k]
// ---------------------------------------------------------------------------
__global__ __launch_bounds__(256) void convT_kernel(
    const float* __restrict__ s0, const float* __restrict__ s1,
    const float* __restrict__ s2, const float* __restrict__ s3,
    const float* __restrict__ s4,
    ushort_t* __restrict__ d0, ushort_t* __restrict__ d1,
    ushort_t* __restrict__ d2, ushort_t* __restrict__ d3,
    ushort_t* __restrict__ d4) {
  int z = blockIdx.z;
  const float* src = z == 0 ? s0 : z == 1 ? s1 : z == 2 ? s2 : z == 3 ? s3 : s4;
  ushort_t* dst = z == 0 ? d0 : z == 1 ? d1 : z == 2 ? d2 : z == 3 ? d3 : d4;
  __shared__ float Tl[64][68];
  int tid = threadIdx.x;
  int k0 = blockIdx.x * 64, n0 = blockIdx.y * 64;
#pragma unroll
  for (int it = 0; it < 4; ++it) {
    int idx = tid + it * 256;
    int r = idx >> 4, c4 = (idx & 15) * 4;
    *(float4*)&Tl[r][c4] = *(const float4*)(src + (size_t)(k0 + r) * 1024 + n0 + c4);
  }
  __syncthreads();
#pragma unroll
  for (int it = 0; it < 2; ++it) {
    int idx = tid + it * 256;
    int nn = idx >> 3, kc = idx & 7;
    union { ushort_t us[8]; uint4 v; } o;
#pragma unroll
    for (int e = 0; e < 8; ++e) o.us[e] = (ushort_t)f2b(Tl[kc * 8 + e][nn]);
    *(uint4*)(dst + (size_t)(n0 + nn) * 1024 + k0 + kc * 8) = o.v;
  }
}

// ---------------------------------------------------------------------------
// Batched projection GEMM over fp32 activations (in-register bf16 convert):
// blockIdx.z selects {q,k,v,pe}. 128x128 tile, 4 waves.
// z==0 epilogue fuses qprep: writes qwb (= +rwb*N), qrb (= +rrb*N) and the
// per-(row,head) segment projections sbp; z>0 writes bias-added bf16 C.
// ---------------------------------------------------------------------------
__global__ __launch_bounds__(256) void gemm4_kernel(
    const float* __restrict__ a0, const float* __restrict__ a1,
    const float* __restrict__ a2, const float* __restrict__ a3,
    const ushort_t* __restrict__ w0, const ushort_t* __restrict__ w1,
    const ushort_t* __restrict__ w2, const ushort_t* __restrict__ w3,
    const float* __restrict__ kb, const float* __restrict__ vb,
    const float* __restrict__ rwb, const float* __restrict__ rrb,
    const float* __restrict__ rsb, const float* __restrict__ sem,
    ushort_t* __restrict__ qwb, ushort_t* __restrict__ qrb,
    float2* __restrict__ sbp,
    ushort_t* __restrict__ c1, ushort_t* __restrict__ c2,
    ushort_t* __restrict__ c3) {
  const int z = blockIdx.z;
  const float* A     = z == 0 ? a0 : z == 1 ? a1 : z == 2 ? a2 : a3;
  const ushort_t* Wt = z == 0 ? w0 : z == 1 ? w1 : z == 2 ? w2 : w3;

  __shared__ short A_lds[128][40];
  __shared__ short B_lds[128][40];
  const int tid = threadIdx.x;
  const int wave = tid >> 6, lane = tid & 63;
  const int r16 = lane & 15, g = lane >> 4;
  const int wm = wave >> 1, wn = wave & 1;
  const int m0 = blockIdx.x * 128, n0 = blockIdx.y * 128;
  const int sr = tid >> 2, sseg = (tid & 3) * 8;
  f32x4 acc[4][4] = {};
  float4 fa0a = *(const float4*)(A + (size_t)(m0 + sr) * 1024 + sseg);
  float4 fa0b = *(const float4*)(A + (size_t)(m0 + sr) * 1024 + sseg + 4);
  float4 fa1a = *(const float4*)(A + (size_t)(m0 + 64 + sr) * 1024 + sseg);
  float4 fa1b = *(const float4*)(A + (size_t)(m0 + 64 + sr) * 1024 + sseg + 4);
  uint4 rb0 = *(const uint4*)(Wt + (size_t)(n0 + sr) * 1024 + sseg);
  uint4 rb1 = *(const uint4*)(Wt + (size_t)(n0 + 64 + sr) * 1024 + sseg);
  for (int k0 = 0; k0 < 1024; k0 += 32) {
    *(uint4*)&A_lds[sr][sseg] = pack8(fa0a, fa0b);
    *(uint4*)&A_lds[64 + sr][sseg] = pack8(fa1a, fa1b);
    *(uint4*)&B_lds[sr][sseg] = rb0;
    *(uint4*)&B_lds[64 + sr][sseg] = rb1;
    __syncthreads();
    if (k0 + 32 < 1024) {
      fa0a = *(const float4*)(A + (size_t)(m0 + sr) * 1024 + k0 + 32 + sseg);
      fa0b = *(const float4*)(A + (size_t)(m0 + sr) * 1024 + k0 + 32 + sseg + 4);
      fa1a = *(const float4*)(A + (size_t)(m0 + 64 + sr) * 1024 + k0 + 32 + sseg);
      fa1b = *(const float4*)(A + (size_t)(m0 + 64 + sr) * 1024 + k0 + 32 + sseg + 4);
      rb0 = *(const uint4*)(Wt + (size_t)(n0 + sr) * 1024 + k0 + 32 + sseg);
      rb1 = *(const uint4*)(Wt + (size_t)(n0 + 64 + sr) * 1024 + k0 + 32 + sseg);
    }
    bf16x8 af[4], bfr[4];
#pragma unroll
    for (int fm = 0; fm < 4; ++fm)
      af[fm] = *(const bf16x8*)&A_lds[wm * 64 + fm * 16 + r16][g * 8];
#pragma unroll
    for (int fn = 0; fn < 4; ++fn)
      bfr[fn] = *(const bf16x8*)&B_lds[wn * 64 + fn * 16 + r16][g * 8];
#pragma unroll
    for (int fm = 0; fm < 4; ++fm)
#pragma unroll
      for (int fn = 0; fn < 4; ++fn)
        acc[fm][fn] = __builtin_amdgcn_mfma_f32_16x16x32_bf16(af[fm], bfr[fn], acc[fm][fn], 0, 0, 0);
    __syncthreads();
  }

  if (z == 0) {
    // fused qprep epilogue: this wave's 64-col half is one full head.
    float rwbN[4], rrbN[4], rsbN[4], s0c[4], s1c[4];
#pragma unroll
    for (int fn = 0; fn < 4; ++fn) {
      int col = n0 + wn * 64 + fn * 16 + r16;
      rwbN[fn] = rwb[col] * NORM_F;
      rrbN[fn] = rrb[col] * NORM_F;
      rsbN[fn] = rsb[col] * NORM_F;
      s0c[fn] = sem[col];
      s1c[fn] = sem[1024 + col];
    }
    const int nI = (n0 >> 6) + wn;   // head index 0..15
#pragma unroll
    for (int fm = 0; fm < 4; ++fm)
#pragma unroll
      for (int rr = 0; rr < 4; ++rr) {
        int row = m0 + wm * 64 + fm * 16 + g * 4 + rr;
        float p0 = 0.f, p1 = 0.f;
#pragma unroll
        for (int fn = 0; fn < 4; ++fn) {
          float vv = acc[fm][fn][rr] * NORM_F;
          size_t off = (size_t)row * 1024 + n0 + wn * 64 + fn * 16 + r16;
          qwb[off] = (ushort_t)f2b(vv + rwbN[fn]);
          qrb[off] = (ushort_t)f2b(vv + rrbN[fn]);
          float qs = vv + rsbN[fn];
          p0 += qs * s0c[fn];
          p1 += qs * s1c[fn];
        }
        p0 += __shfl_xor(p0, 1); p0 += __shfl_xor(p0, 2);
        p0 += __shfl_xor(p0, 4); p0 += __shfl_xor(p0, 8);
        p1 += __shfl_xor(p1, 1); p1 += __shfl_xor(p1, 2);
        p1 += __shfl_xor(p1, 4); p1 += __shfl_xor(p1, 8);
        if (r16 == 0) {
          int bI = row >> 11, iI = row & 2047;
          sbp[((size_t)bI * 16 + nI) * 2048 + iI] = make_float2(p0, p1);
        }
      }
  } else {
    const float* bias = z == 1 ? kb : z == 2 ? vb : (const float*)nullptr;
    ushort_t* C = z == 1 ? c1 : z == 2 ? c2 : c3;
    float bv[4];
#pragma unroll
    for (int fn = 0; fn < 4; ++fn)
      bv[fn] = bias ? bias[n0 + wn * 64 + fn * 16 + r16] : 0.f;
#pragma unroll
    for (int fm = 0; fm < 4; ++fm)
#pragma unroll
      for (int fn = 0; fn < 4; ++fn)
#pragma unroll
        for (int rr = 0; rr < 4; ++rr) {
          float vv = acc[fm][fn][rr] + bv[fn];
          size_t off = (size_t)(m0 + wm * 64 + fm * 16 + g * 4 + rr) * 1024 +
                       n0 + wn * 64 + fn * 16 + r16;
          C[off] = (ushort_t)f2b(vv);
        }
  }
}

// ---------------------------------------------------------------------------
// Post-projection GEMM, 64x128 tile (512 blocks = 2/CU), fp32 out.
// ---------------------------------------------------------------------------
__global__ __launch_bounds__(256) void gemm_post_kernel(
    const ushort_t* __restrict__ A, const ushort_t* __restrict__ Wt,
    const float* __restrict__ bias, float* __restrict__ C) {
  __shared__ short A_lds[64][40];
  __shared__ short B_lds[128][40];
  const int tid = threadIdx.x;
  const int wave = tid >> 6, lane = tid & 63;
  const int r16 = lane & 15, g = lane >> 4;
  const int wm = wave >> 1, wn = wave & 1;
  const int m0 = blockIdx.x * 64, n0 = blockIdx.y * 128;
  const int sr = tid >> 2, sseg = (tid & 3) * 8;
  f32x4 acc[2][4] = {};
  uint4 ra0 = *(const uint4*)(A + (size_t)(m0 + sr) * 1024 + sseg);
  uint4 rb0 = *(const uint4*)(Wt + (size_t)(n0 + sr) * 1024 + sseg);
  uint4 rb1 = *(const uint4*)(Wt + (size_t)(n0 + 64 + sr) * 1024 + sseg);
  for (int k0 = 0; k0 < 1024; k0 += 32) {
    *(uint4*)&A_lds[sr][sseg] = ra0;
    *(uint4*)&B_lds[sr][sseg] = rb0;
    *(uint4*)&B_lds[64 + sr][sseg] = rb1;
    __syncthreads();
    if (k0 + 32 < 1024) {
      ra0 = *(const uint4*)(A + (size_t)(m0 + sr) * 1024 + k0 + 32 + sseg);
      rb0 = *(const uint4*)(Wt + (size_t)(n0 + sr) * 1024 + k0 + 32 + sseg);
      rb1 = *(const uint4*)(Wt + (size_t)(n0 + 64 + sr) * 1024 + k0 + 32 + sseg);
    }
    bf16x8 af[2], bfr[4];
#pragma unroll
    for (int fm = 0; fm < 2; ++fm)
      af[fm] = *(const bf16x8*)&A_lds[wm * 32 + fm * 16 + r16][g * 8];
#pragma unroll
    for (int fn = 0; fn < 4; ++fn)
      bfr[fn] = *(const bf16x8*)&B_lds[wn * 64 + fn * 16 + r16][g * 8];
#pragma unroll
    for (int fm = 0; fm < 2; ++fm)
#pragma unroll
      for (int fn = 0; fn < 4; ++fn)
        acc[fm][fn] = __builtin_amdgcn_mfma_f32_16x16x32_bf16(af[fm], bfr[fn], acc[fm][fn], 0, 0, 0);
    __syncthreads();
  }
  float bv[4];
#pragma unroll
  for (int fn = 0; fn < 4; ++fn)
    bv[fn] = bias ? bias[n0 + wn * 64 + fn * 16 + r16] : 0.f;
#pragma unroll
  for (int fm = 0; fm < 2; ++fm)
#pragma unroll
    for (int fn = 0; fn < 4; ++fn)
#pragma unroll
      for (int rr = 0; rr < 4; ++rr) {
        size_t off = (size_t)(m0 + wm * 32 + fm * 16 + g * 4 + rr) * 1024 +
                     n0 + wn * 64 + fn * 16 + r16;
        C[off] = acc[fm][fn][rr] + bv[fn];
      }
}

// ---------------------------------------------------------------------------
// Fused causal relative attention (byte-exact from R10 PASS).
// ---------------------------------------------------------------------------
__global__ __launch_bounds__(256) void attn_kernel(
    const ushort_t* __restrict__ qwb, const ushort_t* __restrict__ qrb,
    const ushort_t* __restrict__ khb, const ushort_t* __restrict__ vhb,
    const ushort_t* __restrict__ rhb, const float2* __restrict__ sbp,
    const unsigned* __restrict__ segw, ushort_t* __restrict__ opart,
    float* __restrict__ ml) {
  __shared__ short Klds[64][64];
  __shared__ short Rlds[128][64];
  __shared__ short VsT[2][64][72];
  __shared__ short SP[4][1376];

  const int tid = threadIdx.x;
  const int w = tid >> 6, lane = tid & 63;
  const int r16 = lane & 15, g = lane >> 4;
  // XCD swizzle: lin -> (group g in [0,32), j in [0,64)); XCD = lin % 8 = g % 8
  const int lin = (int)blockIdx.x;
  const int grp = (lin & 7) + ((lin >> 9) << 3);
  const int j = (lin >> 3) & 63;
  const int x = 31 - (j >> 1);
  const int hx = j & 1;
  const int i0 = x * 64;
  const int nh = (x + 2) >> 1;
  const int tbeg = hx ? nh : 0;
  const int tend = hx ? (x + 1) : nh;
  const int n = grp & 15, b = grp >> 4;
  const int BNS = 65536;
  const int rowbase = (b * 16 + n) * 2048 + i0;

  if (tbeg >= tend) {  // empty half (only hx==1, x==0)
    const int il0 = w * 16 + g * 4;
#pragma unroll
    for (int rr = 0; rr < 4; ++rr) {
#pragma unroll
      for (int s = 0; s < 4; ++s)
        opart[(size_t)(BNS + rowbase + il0 + rr) * 64 + s * 16 + r16] = 0;
      if (r16 == 0) {
        ml[2 * BNS + rowbase + il0 + rr] = -1e30f;
        ml[3 * BNS + rowbase + il0 + rr] = 0.f;
      }
    }
    return;
  }

  short* SPw = &SP[w][0];
  const int srow = tid >> 3, sg8 = (tid & 7) * 8;

  // per-lane persistent state (q-row = r16 within this wave's 16 rows)
  const int qrow = i0 + w * 16 + r16;
  const ushort_t* qwp = qwb + (size_t)(b * S_LEN + qrow) * DMODEL + n * 64 + g * 8;
  const ushort_t* qrp = qrb + (size_t)(b * S_LEN + qrow) * DMODEL + n * 64 + g * 8;
  bf16x8 qw[2], qr[2];
  qw[0] = *(const bf16x8*)qwp;  qw[1] = *(const bf16x8*)(qwp + 32);
  qr[0] = *(const bf16x8*)qrp;  qr[1] = *(const bf16x8*)(qrp + 32);
  float2 sbv = sbp[((size_t)b * 16 + n) * 2048 + qrow];
  const float sb0 = sbv.x, sb1 = sbv.y;
  const int ai = (segw[b * 64 + (qrow >> 5)] >> (qrow & 31)) & 1;
  const int iw0 = i0 + w * 16;

  // prologue: stage tile tbeg (K, R swizzled; V scattered, 3-bit chunk XOR)
  {
    const int j0 = tbeg * 64;
    const int W0 = 2048 + j0 - i0 - 63;
#pragma unroll
    for (int it = 0; it < 2; ++it) {
      int qk = tid + it * 256, row = qk >> 3, cl = qk & 7;
      uint4 kv = *(const uint4*)(khb + (size_t)(b * S_LEN + j0 + row) * DMODEL + n * 64 + cl * 8);
      *(uint4*)&Klds[row][(cl ^ (row & 7)) * 8] = kv;
    }
#pragma unroll
    for (int it = 0; it < 4; ++it) {
      int qk = tid + it * 256, row = qk >> 3, cl = qk & 7;
      uint4 rv = *(const uint4*)(rhb + (size_t)(W0 + row) * DMODEL + n * 64 + cl * 8);
      *(uint4*)&Rlds[row][(cl ^ (row & 7)) * 8] = rv;
    }
#pragma unroll
    for (int it = 0; it < 2; ++it) {
      int jj = srow + it * 32;
      union { uint4 v; ushort_t us[8]; } vv;
      vv.v = *(const uint4*)(vhb + (size_t)(b * S_LEN + j0 + jj) * DMODEL + n * 64 + sg8);
#pragma unroll
      for (int e = 0; e < 8; ++e) {
        int hh = sg8 + e;
        VsT[0][hh][((jj >> 3) ^ (hh >> 3)) * 8 + (jj & 7)] = (short)vv.us[e];
      }
    }
  }

  float m_r = -1e30f, l_r = 0.f;
  f32x4 o[4] = {};

  for (int t = tbeg; t < tend; ++t) {
    const int j0 = t * 64;
    const int tt = (t - tbeg) & 1;
    const bool hasn = (t + 1 < tend);
    __syncthreads();  // barrier A: staged data for tile t visible

    uint4 kpf[2], rpf[4], vpf[2];
    if (hasn) {
      const int j0n = j0 + 64;
      const int W0n = 2048 + j0n - i0 - 63;
#pragma unroll
      for (int it = 0; it < 2; ++it) {
        int qk = tid + it * 256, row = qk >> 3, cl = qk & 7;
        kpf[it] = *(const uint4*)(khb + (size_t)(b * S_LEN + j0n + row) * DMODEL + n * 64 + cl * 8);
      }
#pragma unroll
      for (int it = 0; it < 4; ++it) {
        int qk = tid + it * 256, row = qk >> 3, cl = qk & 7;
        rpf[it] = *(const uint4*)(rhb + (size_t)(W0n + row) * DMODEL + n * 64 + cl * 8);
      }
#pragma unroll
      for (int it = 0; it < 2; ++it)
        vpf[it] = *(const uint4*)(vhb + (size_t)(b * S_LEN + j0n + srow + it * 32) * DMODEL + n * 64 + sg8);
    }
    unsigned wlo = segw[b * 64 + (j0 >> 5)];
    unsigned whi = segw[b * 64 + (j0 >> 5) + 1];

    // content MFMAs: cf[s][rr] = S[j = j0+s*16+g*4+rr][i = qrow]
    __builtin_amdgcn_s_setprio(1);
    f32x4 cf[4] = {};
#pragma unroll
    for (int s = 0; s < 4; ++s) {
      int row = s * 16 + r16;
      bf16x8 k0 = *(const bf16x8*)&Klds[row][(g ^ (row & 7)) * 8];
      bf16x8 k1 = *(const bf16x8*)&Klds[row][((4 + g) ^ (row & 7)) * 8];
      cf[s] = __builtin_amdgcn_mfma_f32_16x16x32_bf16(k0, qw[0], cf[s], 0, 0, 0);
      cf[s] = __builtin_amdgcn_mfma_f32_16x16x32_bf16(k1, qw[1], cf[s], 0, 0, 0);
    }
    // pos MFMAs -> PosL (stride-84 view): value at (u' = sp*16+g*4+rr, qcol r16)
#pragma unroll
    for (int sp = 0; sp < 5; ++sp) {
      int row = 48 - w * 16 + sp * 16 + r16;
      bf16x8 r0 = *(const bf16x8*)&Rlds[row][(g ^ (row & 7)) * 8];
      bf16x8 r1 = *(const bf16x8*)&Rlds[row][((4 + g) ^ (row & 7)) * 8];
      f32x4 pf = {};
      pf = __builtin_amdgcn_mfma_f32_16x16x32_bf16(r0, qr[0], pf, 0, 0, 0);
      pf = __builtin_amdgcn_mfma_f32_16x16x32_bf16(r1, qr[1], pf, 0, 0, 0);
      uint2 pw;
      pw.x = cvtpk(pf[0], pf[1]);
      pw.y = cvtpk(pf[2], pf[3]);
      *(uint2*)&SPw[r16 * 84 + sp * 16 + g * 4] = pw;
    }
    __builtin_amdgcn_s_setprio(0);
    // softmax (lane-local row = qrow). Read pos first (wave-lockstep => no race
    // with the Ps writes below into the same SP buffer).
    ushort_t pu[4][4];
#pragma unroll
    for (int s = 0; s < 4; ++s)
#pragma unroll
      for (int rr = 0; rr < 4; ++rr)
        pu[s][rr] = (ushort_t)SPw[r16 * 84 + (15 - r16) + s * 16 + g * 4 + rr];
    float vals[4][4];
    float vmax = -1e30f;
    const bool diag = (t == x);
#pragma unroll
    for (int s = 0; s < 4; ++s) {
      unsigned word = (s < 2) ? wlo : whi;
#pragma unroll
      for (int rr = 0; rr < 4; ++rr) {
        int p = s * 16 + g * 4 + rr;
        int bitv = (word >> (p & 31)) & 1;
        float sv = cf[s][rr] + b2f(pu[s][rr]) + ((bitv == ai) ? sb1 : sb0);
        if (diag && (p > w * 16 + r16)) sv -= 1e6f;
        vals[s][rr] = sv;
        vmax = fmaxf(vmax, sv);
      }
    }
    vmax = fmaxf(vmax, __shfl_xor(vmax, 16));
    vmax = fmaxf(vmax, __shfl_xor(vmax, 32));
    float scl = 1.f;
    bool resc = !__all(vmax <= m_r + 8.f);
    if (resc) {
      float mnew = fmaxf(m_r, vmax);
      scl = __expf(m_r - mnew);
      m_r = mnew;
    }
    float pex[4][4];
    float psum = 0.f;
#pragma unroll
    for (int s = 0; s < 4; ++s)
#pragma unroll
      for (int rr = 0; rr < 4; ++rr) {
        pex[s][rr] = __expf(vals[s][rr] - m_r);
        psum += pex[s][rr];
      }
    l_r = l_r * scl + psum;
#pragma unroll
    for (int s = 0; s < 4; ++s) {
      uint2 pw;
      pw.x = cvtpk(pex[s][0], pex[s][1]);
      pw.y = cvtpk(pex[s][2], pex[s][3]);
      *(uint2*)&SPw[r16 * 72 + s * 16 + g * 4] = pw;
    }
    __syncthreads();  // barrier B: K/R/V(t) LDS reads complete

    if (hasn) {
#pragma unroll
      for (int it = 0; it < 2; ++it) {
        int qk = tid + it * 256, row = qk >> 3, cl = qk & 7;
        *(uint4*)&Klds[row][(cl ^ (row & 7)) * 8] = kpf[it];
      }
#pragma unroll
      for (int it = 0; it < 4; ++it) {
        int qk = tid + it * 256, row = qk >> 3, cl = qk & 7;
        *(uint4*)&Rlds[row][(cl ^ (row & 7)) * 8] = rpf[it];
      }
      const int dst = tt ^ 1;
#pragma unroll
      for (int it = 0; it < 2; ++it) {
        int jj = srow + it * 32;
        union { uint4 v; ushort_t us[8]; } vv; vv.v = vpf[it];
#pragma unroll
        for (int e = 0; e < 8; ++e) {
          int hh = sg8 + e;
          VsT[dst][hh][((jj >> 3) ^ (hh >> 3)) * 8 + (jj & 7)] = (short)vv.us[e];
        }
      }
    }
    // PV: o[s][rr] at (i-row = g*4+rr, h = s*16+r16)
    if (resc) {
      float sclb[4];
#pragma unroll
      for (int rr = 0; rr < 4; ++rr) sclb[rr] = __shfl(scl, g * 4 + rr);
#pragma unroll
      for (int s = 0; s < 4; ++s)
#pragma unroll
        for (int rr = 0; rr < 4; ++rr) o[s][rr] *= sclb[rr];
    }
    bf16x8 pa0 = *(const bf16x8*)&SPw[r16 * 72 + g * 8];
    bf16x8 pa1 = *(const bf16x8*)&SPw[r16 * 72 + 32 + g * 8];
    __builtin_amdgcn_s_setprio(1);
#pragma unroll
    for (int s = 0; s < 4; ++s) {
      int hh = s * 16 + r16;
      bf16x8 v0 = *(const bf16x8*)&VsT[tt][hh][(g ^ (hh >> 3)) * 8];
      bf16x8 v1 = *(const bf16x8*)&VsT[tt][hh][((4 + g) ^ (hh >> 3)) * 8];
      o[s] = __builtin_amdgcn_mfma_f32_16x16x32_bf16(pa0, v0, o[s], 0, 0, 0);
      o[s] = __builtin_amdgcn_mfma_f32_16x16x32_bf16(pa1, v1, o[s], 0, 0, 0);
    }
    __builtin_amdgcn_s_setprio(0);
  }

  // epilogue
  float l_row = l_r;
  l_row += __shfl_xor(l_row, 16);
  l_row += __shfl_xor(l_row, 32);
  if (lane < 16) {
    ml[hx * 2 * BNS + rowbase + w * 16 + r16] = m_r;
    ml[(hx * 2 + 1) * BNS + rowbase + w * 16 + r16] = l_row;
  }
#pragma unroll
  for (int s = 0; s < 4; ++s)
#pragma unroll
    for (int rr = 0; rr < 4; ++rr) {
      const int il = w * 16 + g * 4 + rr;
      opart[(size_t)(hx * BNS + rowbase + il) * 64 + s * 16 + r16] = (ushort_t)f2b(o[s][rr]);
    }
}

// ---------------------------------------------------------------------------
// Merge the two j-halves: o = (o0*e^{m0-m} + o1*e^{m1-m}) / l
// ---------------------------------------------------------------------------
__global__ __launch_bounds__(256) void merge_kernel(
    const ushort_t* __restrict__ opart, const float* __restrict__ ml,
    ushort_t* __restrict__ av) {
  const int BNS = 65536;
  int row = blockIdx.x * 4 + (threadIdx.x >> 6);
  int lane = threadIdx.x & 63;
  float m0 = ml[row], l0 = ml[BNS + row];
  float m1 = ml[2 * BNS + row], l1 = ml[3 * BNS + row];
  float m = fmaxf(m0, m1);
  float a0 = __expf(m0 - m), a1 = __expf(m1 - m);
  float inv = 1.f / (l0 * a0 + l1 * a1);
  float o0 = b2f(opart[(size_t)row * 64 + lane]);
  float o1 = b2f(opart[(size_t)(BNS + row) * 64 + lane]);
  float ov = (o0 * a0 + o1 * a1) * inv;
  int bI = row >> 15, nI = (row >> 11) & 15, iI = row & 2047;
  av[(size_t)(bI * 2048 + iI) * 1024 + nI * 64 + lane] = (ushort_t)f2b(ov);
}

// ---------------------------------------------------------------------------
// Residual + LayerNorm
// ---------------------------------------------------------------------------
__global__ __launch_bounds__(256) void ln_kernel(
    const float* __restrict__ q, const float* __restrict__ ao,
    const float* __restrict__ ln_g, const float* __restrict__ ln_b,
    float* __restrict__ out) {
  int row = blockIdx.x;
  const float* xq = q + (size_t)row * 1024;
  const float* xa = ao + (size_t)row * 1024;
  float x[4], lsum = 0.f, lsq = 0.f;
#pragma unroll
  for (int e = 0; e < 4; ++e) {
    int d = threadIdx.x + e * 256;
    x[e] = xq[d] + xa[d];
    lsum += x[e]; lsq += x[e] * x[e];
  }
  for (int off = 1; off < 64; off <<= 1) {
    lsum += __shfl_xor(lsum, off);
    lsq += __shfl_xor(lsq, off);
  }
  __shared__ float red[8];
  int wv = threadIdx.x >> 6, ln = threadIdx.x & 63;
  if (ln == 0) { red[wv] = lsum; red[4 + wv] = lsq; }
  __syncthreads();
  lsum = red[0] + red[1] + red[2] + red[3];
  lsq = red[4] + red[5] + red[6] + red[7];
  float mu = lsum * (1.f / 1024.f);
  float var = lsq * (1.f / 1024.f) - mu * mu;
  float inv = rsqrtf(var + 1e-5f);
#pragma unroll
  for (int e = 0; e < 4; ++e) {
    int d = threadIdx.x + e * 256;
    out[(size_t)row * 1024 + d] = (x[e] - mu) * inv * ln_g[d] + ln_b[d];
  }
}

// ---------------------------------------------------------------------------
extern "C" void kernel_launch(void* const* d_in, const int* in_sizes, int n_in,
                              void* d_out, int out_size, void* d_ws, size_t ws_size,
                              hipStream_t stream) {
  const float* q   = (const float*)d_in[0];
  const float* k   = (const float*)d_in[1];
  const float* v   = (const float*)d_in[2];
  const float* pe  = (const float*)d_in[3];
  const void*  seg = d_in[4];
  const float* qW  = (const float*)d_in[6];
  const float* kW  = (const float*)d_in[7];
  const float* kb  = (const float*)d_in[8];
  const float* vW  = (const float*)d_in[9];
  const float* vb  = (const float*)d_in[10];
  const float* rwb = (const float*)d_in[11];
  const float* rrb = (const float*)d_in[12];
  const float* rK  = (const float*)d_in[13];
  const float* rsb = (const float*)d_in[14];
  const float* sem = (const float*)d_in[15];
  const float* pW  = (const float*)d_in[16];
  const float* pb  = (const float*)d_in[17];
  const float* lng = (const float*)d_in[18];
  const float* lnb = (const float*)d_in[19];
  float* out = (float*)d_out;

  const size_t MB = 1u << 20;
  char* W = (char*)d_ws;
  ushort_t* qwb  = (ushort_t*)(W + 0 * MB);     // 8 MB
  ushort_t* qrb  = (ushort_t*)(W + 8 * MB);     // 8 MB
  ushort_t* opart = (ushort_t*)(W + 16 * MB);   // 16 MB
  ushort_t* wtq  = (ushort_t*)(W + 32 * MB);
  ushort_t* wtk  = (ushort_t*)(W + 34 * MB);
  ushort_t* wtv  = (ushort_t*)(W + 36 * MB);
  ushort_t* wtr  = (ushort_t*)(W + 38 * MB);
  ushort_t* wtp  = (ushort_t*)(W + 40 * MB);
  ushort_t* av   = (ushort_t*)(W + 42 * MB);    // 8 MB
  ushort_t* kh   = (ushort_t*)(W + 50 * MB);
  ushort_t* vh   = (ushort_t*)(W + 58 * MB);
  ushort_t* rh   = (ushort_t*)(W + 66 * MB);
  unsigned* segw = (unsigned*)(W + 74 * MB);
  float2*   sbp  = (float2*)(W + 74 * MB + 65536);
  float*    ml   = (float*)(W + 75 * MB);
  float*    ao   = (float*)(W + 50 * MB);       // 16MB over kh+vh (dead post-attn)

  seg_extract_kernel<<<dim3(16), dim3(256), 0, stream>>>((const unsigned int*)seg, segw);
  convT_kernel<<<dim3(16, 16, 5), dim3(256), 0, stream>>>(qW, kW, vW, rK, pW,
                                                          wtq, wtk, wtv, wtr, wtp);
  // batched projection GEMMs over fp32 inputs; z==0 fuses qprep
  gemm4_kernel<<<dim3(32, 8, 4), dim3(256), 0, stream>>>(
      q, k, v, pe, wtq, wtk, wtv, wtr, kb, vb, rwb, rrb, rsb, sem,
      qwb, qrb, sbp, kh, vh, rh);

  attn_kernel<<<dim3(2048), dim3(256), 0, stream>>>(qwb, qrb, kh, vh, rh,
                                                    sbp, segw, opart, ml);
  merge_kernel<<<dim3(16384), dim3(256), 0, stream>>>(opart, ml, av);

  gemm_post_kernel<<<dim3(64, 8), dim3(256), 0, stream>>>(av, wtp, pb, ao);
  ln_kernel<<<dim3(4096), dim3(256), 0, stream>>>(q, ao, lng, lnb, out);
}